// Round 2
// baseline (2154.892 us; speedup 1.0000x reference)
//
#include <hip/hip_runtime.h>

#define NN 10000
#define NE 256000
#define H 128
#define H2 256
#define H3 384
#define NRBF 20

__device__ __forceinline__ void FMA4(float4& a, float s, const float4& v) {
    a.x = fmaf(s, v.x, a.x); a.y = fmaf(s, v.y, a.y);
    a.z = fmaf(s, v.z, a.z); a.w = fmaf(s, v.w, a.w);
}

__device__ __forceinline__ float silu_f(float v) { return v / (1.f + __expf(-v)); }

// fp32 -> bf16 bits (RNE)
__device__ __forceinline__ unsigned short f2b(float f) {
    union { float f; unsigned u; } x; x.f = f;
    unsigned r = (x.u + 0x7FFFu + ((x.u >> 16) & 1u)) >> 16;
    return (unsigned short)r;
}
__device__ __forceinline__ float b2f(unsigned short b) {
    union { unsigned u; float f; } x; x.u = ((unsigned)b) << 16;
    return x.f;
}

// ---------------------------------------------------------------------------
// x = silu(q @ W1 + b1) @ W2 + b2      [NN, 384]
// block = 384 threads, 16 nodes per block. micro-tile: 4 nodes x 4 cols.
// ---------------------------------------------------------------------------
__global__ __launch_bounds__(384) void node_x_kernel(
    const float* __restrict__ q,
    const float* __restrict__ W1, const float* __restrict__ b1,
    const float* __restrict__ W2, const float* __restrict__ b2,
    float* __restrict__ x) {
    __shared__ __align__(16) float q_s[16][H];
    __shared__ __align__(16) float h_s[16][H3];
    const int t = threadIdx.x;
    const int n0 = blockIdx.x * 16;

    for (int w = t; w < 16 * H / 4; w += 384) {
        int n = w / 32, c4 = (w % 32) * 4;
        *(float4*)&q_s[n][c4] = *(const float4*)&q[(size_t)(n0 + n) * H + c4];
    }
    __syncthreads();

    const int cg = t % 96, ng = t / 96;   // c0 in [0,384), 4 nodes per group
    const int c0 = cg * 4;

    float4 acc[4];
    {
        float4 bv = *(const float4*)&b1[c0];
        #pragma unroll
        for (int i = 0; i < 4; i++) acc[i] = bv;
    }
    for (int k = 0; k < H; k += 4) {
        float4 w0 = *(const float4*)&W1[(size_t)(k + 0) * H3 + c0];
        float4 w1 = *(const float4*)&W1[(size_t)(k + 1) * H3 + c0];
        float4 w2 = *(const float4*)&W1[(size_t)(k + 2) * H3 + c0];
        float4 w3 = *(const float4*)&W1[(size_t)(k + 3) * H3 + c0];
        #pragma unroll
        for (int i = 0; i < 4; i++) {
            float4 qv = *(const float4*)&q_s[ng * 4 + i][k];
            FMA4(acc[i], qv.x, w0); FMA4(acc[i], qv.y, w1);
            FMA4(acc[i], qv.z, w2); FMA4(acc[i], qv.w, w3);
        }
    }
    #pragma unroll
    for (int i = 0; i < 4; i++) {
        float4 v = acc[i];
        v.x = silu_f(v.x); v.y = silu_f(v.y); v.z = silu_f(v.z); v.w = silu_f(v.w);
        *(float4*)&h_s[ng * 4 + i][c0] = v;
    }
    __syncthreads();

    {
        float4 bv = *(const float4*)&b2[c0];
        #pragma unroll
        for (int i = 0; i < 4; i++) acc[i] = bv;
    }
    for (int k = 0; k < H3; k += 4) {
        float4 w0 = *(const float4*)&W2[(size_t)(k + 0) * H3 + c0];
        float4 w1 = *(const float4*)&W2[(size_t)(k + 1) * H3 + c0];
        float4 w2 = *(const float4*)&W2[(size_t)(k + 2) * H3 + c0];
        float4 w3 = *(const float4*)&W2[(size_t)(k + 3) * H3 + c0];
        #pragma unroll
        for (int i = 0; i < 4; i++) {
            float4 hv = *(const float4*)&h_s[ng * 4 + i][k];
            FMA4(acc[i], hv.x, w0); FMA4(acc[i], hv.y, w1);
            FMA4(acc[i], hv.z, w2); FMA4(acc[i], hv.w, w3);
        }
    }
    #pragma unroll
    for (int i = 0; i < 4; i++)
        *(float4*)&x[(size_t)(n0 + ng * 4 + i) * H3 + c0] = acc[i];
}

// ---------------------------------------------------------------------------
// Per-edge: filters = (silu(rbf@Wf1+bf1)@Wf2+bf2)*cutoff, then scatter
// messages into acc_q / acc_mu with atomics. 32 edges per block, 384 threads.
// ---------------------------------------------------------------------------
__global__ __launch_bounds__(384) void edge_kernel(
    const int* __restrict__ eidx, const float* __restrict__ rbf,
    const float* __restrict__ unitv, const float* __restrict__ cutoff,
    const float* __restrict__ Wf1, const float* __restrict__ bf1,
    const float* __restrict__ Wf2, const float* __restrict__ bf2,
    const float* __restrict__ x, const float* __restrict__ mu,
    float* __restrict__ acc_q, float* __restrict__ acc_mu) {
    __shared__ __align__(16) float rbf_s[32][NRBF];
    __shared__ __align__(16) float h1_s[32][H];
    __shared__ __align__(16) unsigned short filt_s[32][H3];   // bf16 bits
    __shared__ int src_s[32], tgt_s[32];
    __shared__ float cut_s[32];
    __shared__ float unit_s[32][3];
    const int t = threadIdx.x;
    const int e0 = blockIdx.x * 32;

    if (t < 32) {
        tgt_s[t] = eidx[e0 + t];
        src_s[t] = eidx[NE + e0 + t];
        cut_s[t] = cutoff[e0 + t];
    } else if (t >= 64 && t < 160) {
        int i = t - 64, e = i / 3, d = i % 3;
        unit_s[e][d] = unitv[(size_t)(e0 + e) * 3 + d];
    }
    for (int w = t; w < 32 * NRBF; w += 384) {
        int e = w / NRBF, k = w % NRBF;
        rbf_s[e][k] = rbf[(size_t)(e0 + e) * NRBF + k];
    }
    __syncthreads();

    // filter layer 1: 32 edges x 128 hidden
    for (int w = t; w < 32 * H; w += 384) {
        int e = w >> 7, c = w & 127;
        float a = bf1[c];
        #pragma unroll
        for (int k = 0; k < NRBF; k++) a = fmaf(rbf_s[e][k], Wf1[k * H + c], a);
        h1_s[e][c] = silu_f(a);
    }
    __syncthreads();

    // filter layer 2: micro-tile 8 edges x 4 cols per thread
    {
        const int cg = t % 96, eg = t / 96;
        const int c0 = cg * 4;
        float4 acc[8];
        {
            float4 bv = *(const float4*)&bf2[c0];
            #pragma unroll
            for (int i = 0; i < 8; i++) acc[i] = bv;
        }
        for (int k = 0; k < H; k += 4) {
            float4 w0 = *(const float4*)&Wf2[(size_t)(k + 0) * H3 + c0];
            float4 w1 = *(const float4*)&Wf2[(size_t)(k + 1) * H3 + c0];
            float4 w2 = *(const float4*)&Wf2[(size_t)(k + 2) * H3 + c0];
            float4 w3 = *(const float4*)&Wf2[(size_t)(k + 3) * H3 + c0];
            #pragma unroll
            for (int i = 0; i < 8; i++) {
                float4 hv = *(const float4*)&h1_s[eg * 8 + i][k];
                FMA4(acc[i], hv.x, w0); FMA4(acc[i], hv.y, w1);
                FMA4(acc[i], hv.z, w2); FMA4(acc[i], hv.w, w3);
            }
        }
        #pragma unroll
        for (int i = 0; i < 8; i++) {
            int e = eg * 8 + i;
            float cu = cut_s[e];
            filt_s[e][c0 + 0] = f2b(acc[i].x * cu);
            filt_s[e][c0 + 1] = f2b(acc[i].y * cu);
            filt_s[e][c0 + 2] = f2b(acc[i].z * cu);
            filt_s[e][c0 + 3] = f2b(acc[i].w * cu);
        }
    }
    __syncthreads();

    // message + scatter: 32 edges x 32 float4-col groups
    for (int w = t; w < 32 * 32; w += 384) {
        int e = w >> 5, c4 = (w & 31) * 4;
        int s = src_s[e], g = tgt_s[e];
        ushort4 uq = *(const ushort4*)&filt_s[e][c4];
        ushort4 ur = *(const ushort4*)&filt_s[e][c4 + H];
        ushort4 um = *(const ushort4*)&filt_s[e][c4 + 2 * H];
        const float* xrow = x + (size_t)s * H3;
        float4 xq = *(const float4*)&xrow[c4];
        float4 xr = *(const float4*)&xrow[c4 + H];
        float4 xm = *(const float4*)&xrow[c4 + 2 * H];
        float* aq = acc_q + (size_t)g * H + c4;
        atomicAdd(aq + 0, xq.x * b2f(uq.x));
        atomicAdd(aq + 1, xq.y * b2f(uq.y));
        atomicAdd(aq + 2, xq.z * b2f(uq.z));
        atomicAdd(aq + 3, xq.w * b2f(uq.w));
        float4 xrs, xms;
        xrs.x = xr.x * b2f(ur.x); xrs.y = xr.y * b2f(ur.y);
        xrs.z = xr.z * b2f(ur.z); xrs.w = xr.w * b2f(ur.w);
        xms.x = xm.x * b2f(um.x); xms.y = xm.y * b2f(um.y);
        xms.z = xm.z * b2f(um.z); xms.w = xm.w * b2f(um.w);
        #pragma unroll
        for (int d = 0; d < 3; d++) {
            float u = unit_s[e][d];
            float4 mv = *(const float4*)&mu[((size_t)s * 3 + d) * H + c4];
            float* am = acc_mu + ((size_t)g * 3 + d) * H + c4;
            atomicAdd(am + 0, u * xrs.x + mv.x * xms.x);
            atomicAdd(am + 1, u * xrs.y + mv.y * xms.y);
            atomicAdd(am + 2, u * xrs.z + mv.z * xms.z);
            atomicAdd(am + 3, u * xrs.w + mv.w * xms.w);
        }
    }
}

// ---------------------------------------------------------------------------
// Mixing: per node. 8 nodes per block, 384 threads.
// ---------------------------------------------------------------------------
__global__ __launch_bounds__(384) void mix_kernel(
    const float* __restrict__ q, const float* __restrict__ mu,
    const float* __restrict__ acc_q, const float* __restrict__ acc_mu,
    const float* __restrict__ W_vec,
    const float* __restrict__ W_mix1, const float* __restrict__ b_mix1,
    const float* __restrict__ W_mix2, const float* __restrict__ b_mix2,
    float* __restrict__ q_out, float* __restrict__ mu_out) {
    __shared__ __align__(16) float qn_s[8 * H];        // q + scalar_msg
    __shared__ __align__(16) float mun_s[8 * H3];      // mu + vector_msg
    __shared__ __align__(16) float muw_s[8 * H3];      // mu_w
    __shared__ __align__(16) float norm_s[8 * H];      // ||mu_v||
    __shared__ __align__(16) float inner_s[8 * H];     // <mu_v, mu_w>
    __shared__ __align__(16) float delta_s[8 * H3];
    __shared__ __align__(16) float muvh_s[8 * H3];     // mu_v, later h (mix1 out)
    const int t = threadIdx.x;
    const int n0 = blockIdx.x * 8;

    for (int w = t; w < 8 * H / 4; w += 384) {
        int idx = w * 4;
        float4 a = *(const float4*)&q[(size_t)n0 * H + idx];
        float4 b = *(const float4*)&acc_q[(size_t)n0 * H + idx];
        a.x += b.x; a.y += b.y; a.z += b.z; a.w += b.w;
        *(float4*)&qn_s[idx] = a;
    }
    for (int w = t; w < 8 * H3 / 4; w += 384) {
        int idx = w * 4;
        float4 a = *(const float4*)&mu[(size_t)n0 * H3 + idx];
        float4 b = *(const float4*)&acc_mu[(size_t)n0 * H3 + idx];
        a.x += b.x; a.y += b.y; a.z += b.z; a.w += b.w;
        *(float4*)&mun_s[idx] = a;
    }
    __syncthreads();

    // mu_cat = einsum('ndf,fo->ndo'): 24 nd-rows x 256 cols, K=128
    {
        const int cg = t % 64, g = t / 64;   // c0 in [0,256), 4 nd-rows per group
        const int c0 = cg * 4;
        float4 acc[4];
        float4 z; z.x = z.y = z.z = z.w = 0.f;
        #pragma unroll
        for (int i = 0; i < 4; i++) acc[i] = z;
        for (int k = 0; k < H; k += 4) {
            float4 w0 = *(const float4*)&W_vec[(size_t)(k + 0) * H2 + c0];
            float4 w1 = *(const float4*)&W_vec[(size_t)(k + 1) * H2 + c0];
            float4 w2 = *(const float4*)&W_vec[(size_t)(k + 2) * H2 + c0];
            float4 w3 = *(const float4*)&W_vec[(size_t)(k + 3) * H2 + c0];
            #pragma unroll
            for (int i = 0; i < 4; i++) {
                float4 m = *(const float4*)&mun_s[(g * 4 + i) * H + k];
                FMA4(acc[i], m.x, w0); FMA4(acc[i], m.y, w1);
                FMA4(acc[i], m.z, w2); FMA4(acc[i], m.w, w3);
            }
        }
        #pragma unroll
        for (int i = 0; i < 4; i++) {
            int nd = g * 4 + i;
            if (c0 < H) *(float4*)&muvh_s[nd * H + c0] = acc[i];
            else        *(float4*)&muw_s[nd * H + (c0 - H)] = acc[i];
        }
    }
    __syncthreads();

    // norms + inner products
    for (int w = t; w < 8 * H / 4; w += 384) {
        int n = w / 32, c4 = (w % 32) * 4;
        float4 v0 = *(const float4*)&muvh_s[(n * 3 + 0) * H + c4];
        float4 v1 = *(const float4*)&muvh_s[(n * 3 + 1) * H + c4];
        float4 v2 = *(const float4*)&muvh_s[(n * 3 + 2) * H + c4];
        float4 w0 = *(const float4*)&muw_s[(n * 3 + 0) * H + c4];
        float4 w1 = *(const float4*)&muw_s[(n * 3 + 1) * H + c4];
        float4 w2 = *(const float4*)&muw_s[(n * 3 + 2) * H + c4];
        float4 nr, in_;
        nr.x = sqrtf(v0.x * v0.x + v1.x * v1.x + v2.x * v2.x + 1e-8f);
        nr.y = sqrtf(v0.y * v0.y + v1.y * v1.y + v2.y * v2.y + 1e-8f);
        nr.z = sqrtf(v0.z * v0.z + v1.z * v1.z + v2.z * v2.z + 1e-8f);
        nr.w = sqrtf(v0.w * v0.w + v1.w * v1.w + v2.w * v2.w + 1e-8f);
        in_.x = v0.x * w0.x + v1.x * w1.x + v2.x * w2.x;
        in_.y = v0.y * w0.y + v1.y * w1.y + v2.y * w2.y;
        in_.z = v0.z * w0.z + v1.z * w1.z + v2.z * w2.z;
        in_.w = v0.w * w0.w + v1.w * w1.w + v2.w * w2.w;
        *(float4*)&norm_s[n * H + c4] = nr;
        *(float4*)&inner_s[n * H + c4] = in_;
    }
    __syncthreads();

    const int cg = t % 96, ng = t / 96;   // c0 in [0,384), 2 nodes per group
    const int c0 = cg * 4;

    // mix1: K = 256 (first half qn_s, second half norm_s), silu
    {
        float4 acc[2];
        float4 bv = *(const float4*)&b_mix1[c0];
        acc[0] = bv; acc[1] = bv;
        for (int k = 0; k < H; k += 4) {
            float4 w0 = *(const float4*)&W_mix1[(size_t)(k + 0) * H3 + c0];
            float4 w1 = *(const float4*)&W_mix1[(size_t)(k + 1) * H3 + c0];
            float4 w2 = *(const float4*)&W_mix1[(size_t)(k + 2) * H3 + c0];
            float4 w3 = *(const float4*)&W_mix1[(size_t)(k + 3) * H3 + c0];
            #pragma unroll
            for (int i = 0; i < 2; i++) {
                float4 s = *(const float4*)&qn_s[(ng * 2 + i) * H + k];
                FMA4(acc[i], s.x, w0); FMA4(acc[i], s.y, w1);
                FMA4(acc[i], s.z, w2); FMA4(acc[i], s.w, w3);
            }
        }
        for (int k = 0; k < H; k += 4) {
            float4 w0 = *(const float4*)&W_mix1[(size_t)(H + k + 0) * H3 + c0];
            float4 w1 = *(const float4*)&W_mix1[(size_t)(H + k + 1) * H3 + c0];
            float4 w2 = *(const float4*)&W_mix1[(size_t)(H + k + 2) * H3 + c0];
            float4 w3 = *(const float4*)&W_mix1[(size_t)(H + k + 3) * H3 + c0];
            #pragma unroll
            for (int i = 0; i < 2; i++) {
                float4 s = *(const float4*)&norm_s[(ng * 2 + i) * H + k];
                FMA4(acc[i], s.x, w0); FMA4(acc[i], s.y, w1);
                FMA4(acc[i], s.z, w2); FMA4(acc[i], s.w, w3);
            }
        }
        #pragma unroll
        for (int i = 0; i < 2; i++) {
            float4 v = acc[i];
            v.x = silu_f(v.x); v.y = silu_f(v.y); v.z = silu_f(v.z); v.w = silu_f(v.w);
            *(float4*)&muvh_s[(ng * 2 + i) * H3 + c0] = v;   // reuse as h
        }
    }
    __syncthreads();

    // mix2: K = 384
    {
        float4 acc[2];
        float4 bv = *(const float4*)&b_mix2[c0];
        acc[0] = bv; acc[1] = bv;
        for (int k = 0; k < H3; k += 4) {
            float4 w0 = *(const float4*)&W_mix2[(size_t)(k + 0) * H3 + c0];
            float4 w1 = *(const float4*)&W_mix2[(size_t)(k + 1) * H3 + c0];
            float4 w2 = *(const float4*)&W_mix2[(size_t)(k + 2) * H3 + c0];
            float4 w3 = *(const float4*)&W_mix2[(size_t)(k + 3) * H3 + c0];
            #pragma unroll
            for (int i = 0; i < 2; i++) {
                float4 s = *(const float4*)&muvh_s[(ng * 2 + i) * H3 + k];
                FMA4(acc[i], s.x, w0); FMA4(acc[i], s.y, w1);
                FMA4(acc[i], s.z, w2); FMA4(acc[i], s.w, w3);
            }
        }
        #pragma unroll
        for (int i = 0; i < 2; i++)
            *(float4*)&delta_s[(ng * 2 + i) * H3 + c0] = acc[i];
    }
    __syncthreads();

    // outputs
    for (int w = t; w < 8 * H / 4; w += 384) {
        int n = w / 32, c4 = (w % 32) * 4;
        int node = n0 + n;
        float4 qn = *(const float4*)&qn_s[n * H + c4];
        float4 dq = *(const float4*)&delta_s[n * H3 + c4];
        float4 dqm = *(const float4*)&delta_s[n * H3 + 2 * H + c4];
        float4 in_ = *(const float4*)&inner_s[n * H + c4];
        float4 o;
        o.x = qn.x + dq.x + dqm.x * in_.x;
        o.y = qn.y + dq.y + dqm.y * in_.y;
        o.z = qn.z + dq.z + dqm.z * in_.z;
        o.w = qn.w + dq.w + dqm.w * in_.w;
        *(float4*)&q_out[(size_t)node * H + c4] = o;
    }
    for (int w = t; w < 8 * H3 / 4; w += 384) {
        int n = w / 96, r = w % 96;
        int d = r / 32, c4 = (r % 32) * 4;
        int node = n0 + n;
        float4 m = *(const float4*)&mun_s[n * H3 + d * H + c4];
        float4 mw = *(const float4*)&muw_s[(n * 3 + d) * H + c4];
        float4 dms = *(const float4*)&delta_s[n * H3 + H + c4];
        float4 o;
        o.x = m.x + mw.x * dms.x;
        o.y = m.y + mw.y * dms.y;
        o.z = m.z + mw.z * dms.z;
        o.w = m.w + mw.w * dms.w;
        *(float4*)&mu_out[((size_t)node * 3 + d) * H + c4] = o;
    }
}

extern "C" void kernel_launch(void* const* d_in, const int* in_sizes, int n_in,
                              void* d_out, int out_size, void* d_ws, size_t ws_size,
                              hipStream_t stream) {
    const float* q        = (const float*)d_in[0];
    const float* mu       = (const float*)d_in[1];
    const int*   eidx     = (const int*)d_in[2];
    const float* rbf      = (const float*)d_in[3];
    const float* unitv    = (const float*)d_in[4];
    const float* cutoff   = (const float*)d_in[5];
    const float* W_inter1 = (const float*)d_in[6];
    const float* b_inter1 = (const float*)d_in[7];
    const float* W_inter2 = (const float*)d_in[8];
    const float* b_inter2 = (const float*)d_in[9];
    const float* W_filt1  = (const float*)d_in[10];
    const float* b_filt1  = (const float*)d_in[11];
    const float* W_filt2  = (const float*)d_in[12];
    const float* b_filt2  = (const float*)d_in[13];
    const float* W_vec    = (const float*)d_in[14];
    const float* W_mix1   = (const float*)d_in[15];
    const float* b_mix1   = (const float*)d_in[16];
    const float* W_mix2   = (const float*)d_in[17];
    const float* b_mix2   = (const float*)d_in[18];

    float* x      = (float*)d_ws;                      // NN*384
    float* acc_q  = x + (size_t)NN * H3;               // NN*128
    float* acc_mu = acc_q + (size_t)NN * H;            // NN*384
    float* q_out  = (float*)d_out;
    float* mu_out = q_out + (size_t)NN * H;

    hipMemsetAsync(acc_q, 0, (size_t)NN * (H + H3) * sizeof(float), stream);

    node_x_kernel<<<NN / 16, 384, 0, stream>>>(q, W_inter1, b_inter1, W_inter2, b_inter2, x);
    edge_kernel<<<NE / 32, 384, 0, stream>>>(eidx, rbf, unitv, cutoff,
                                             W_filt1, b_filt1, W_filt2, b_filt2,
                                             x, mu, acc_q, acc_mu);
    mix_kernel<<<NN / 8, 384, 0, stream>>>(q, mu, acc_q, acc_mu, W_vec,
                                           W_mix1, b_mix1, W_mix2, b_mix2,
                                           q_out, mu_out);
}

// Round 3
// 977.619 us; speedup vs baseline: 2.2042x; 2.2042x over previous
//
#include <hip/hip_runtime.h>

#define NN 10000
#define NE 256000
#define H 128
#define H2 256
#define H3 384
#define NRBF 20

__device__ __forceinline__ void FMA4(float4& a, float s, const float4& v) {
    a.x = fmaf(s, v.x, a.x); a.y = fmaf(s, v.y, a.y);
    a.z = fmaf(s, v.z, a.z); a.w = fmaf(s, v.w, a.w);
}

__device__ __forceinline__ float silu_f(float v) { return v / (1.f + __expf(-v)); }

// fp32 -> bf16 bits (RNE)
__device__ __forceinline__ unsigned short f2b(float f) {
    union { float f; unsigned u; } x; x.f = f;
    unsigned r = (x.u + 0x7FFFu + ((x.u >> 16) & 1u)) >> 16;
    return (unsigned short)r;
}
__device__ __forceinline__ float b2f(unsigned short b) {
    union { unsigned u; float f; } x; x.u = ((unsigned)b) << 16;
    return x.f;
}

// ---------------------------------------------------------------------------
// CSR build: histogram of targets
// ---------------------------------------------------------------------------
__global__ __launch_bounds__(256) void hist_kernel(const int* __restrict__ eidx,
                                                   int* __restrict__ counts) {
    int e = blockIdx.x * 256 + threadIdx.x;
    atomicAdd(&counts[eidx[e]], 1);
}

// Single-block exclusive scan over NN counts -> off[NN+1], cursor copy.
__global__ __launch_bounds__(1024) void scan_kernel(const int* __restrict__ counts,
                                                    int* __restrict__ off,
                                                    int* __restrict__ cursor) {
    __shared__ int sums[1024];
    const int t = threadIdx.x;
    const int base = t * 10;                     // 1024*10 >= 10000
    int local[10];
    int s = 0;
    #pragma unroll
    for (int i = 0; i < 10; i++) {
        int idx = base + i;
        int v = (idx < NN) ? counts[idx] : 0;
        local[i] = s; s += v;
    }
    sums[t] = s;
    __syncthreads();
    for (int d = 1; d < 1024; d <<= 1) {
        int v = (t >= d) ? sums[t - d] : 0;
        __syncthreads();
        sums[t] += v;
        __syncthreads();
    }
    int prefix = (t > 0) ? sums[t - 1] : 0;
    #pragma unroll
    for (int i = 0; i < 10; i++) {
        int idx = base + i;
        if (idx < NN) { off[idx] = prefix + local[i]; cursor[idx] = prefix + local[i]; }
    }
    if (t == 1023) off[NN] = sums[1023];
}

// Place edges into target-sorted order; copy src + unit vector alongside.
__global__ __launch_bounds__(256) void place_kernel(
    const int* __restrict__ eidx, const float* __restrict__ unitv,
    int* __restrict__ cursor, int* __restrict__ sorted_eid,
    int* __restrict__ sorted_src, float* __restrict__ sorted_unit) {
    int e = blockIdx.x * 256 + threadIdx.x;
    int tgt = eidx[e];
    int src = eidx[NE + e];
    int pos = atomicAdd(&cursor[tgt], 1);
    sorted_eid[pos] = e;
    sorted_src[pos] = src;
    sorted_unit[pos * 3 + 0] = unitv[(size_t)e * 3 + 0];
    sorted_unit[pos * 3 + 1] = unitv[(size_t)e * 3 + 1];
    sorted_unit[pos * 3 + 2] = unitv[(size_t)e * 3 + 2];
}

// ---------------------------------------------------------------------------
// x = silu(q @ W1 + b1) @ W2 + b2      [NN, 384]
// ---------------------------------------------------------------------------
__global__ __launch_bounds__(384) void node_x_kernel(
    const float* __restrict__ q,
    const float* __restrict__ W1, const float* __restrict__ b1,
    const float* __restrict__ W2, const float* __restrict__ b2,
    float* __restrict__ x) {
    __shared__ __align__(16) float q_s[16][H];
    __shared__ __align__(16) float h_s[16][H3];
    const int t = threadIdx.x;
    const int n0 = blockIdx.x * 16;

    for (int w = t; w < 16 * H / 4; w += 384) {
        int n = w / 32, c4 = (w % 32) * 4;
        *(float4*)&q_s[n][c4] = *(const float4*)&q[(size_t)(n0 + n) * H + c4];
    }
    __syncthreads();

    const int cg = t % 96, ng = t / 96;
    const int c0 = cg * 4;

    float4 acc[4];
    {
        float4 bv = *(const float4*)&b1[c0];
        #pragma unroll
        for (int i = 0; i < 4; i++) acc[i] = bv;
    }
    for (int k = 0; k < H; k += 4) {
        float4 w0 = *(const float4*)&W1[(size_t)(k + 0) * H3 + c0];
        float4 w1 = *(const float4*)&W1[(size_t)(k + 1) * H3 + c0];
        float4 w2 = *(const float4*)&W1[(size_t)(k + 2) * H3 + c0];
        float4 w3 = *(const float4*)&W1[(size_t)(k + 3) * H3 + c0];
        #pragma unroll
        for (int i = 0; i < 4; i++) {
            float4 qv = *(const float4*)&q_s[ng * 4 + i][k];
            FMA4(acc[i], qv.x, w0); FMA4(acc[i], qv.y, w1);
            FMA4(acc[i], qv.z, w2); FMA4(acc[i], qv.w, w3);
        }
    }
    #pragma unroll
    for (int i = 0; i < 4; i++) {
        float4 v = acc[i];
        v.x = silu_f(v.x); v.y = silu_f(v.y); v.z = silu_f(v.z); v.w = silu_f(v.w);
        *(float4*)&h_s[ng * 4 + i][c0] = v;
    }
    __syncthreads();

    {
        float4 bv = *(const float4*)&b2[c0];
        #pragma unroll
        for (int i = 0; i < 4; i++) acc[i] = bv;
    }
    for (int k = 0; k < H3; k += 4) {
        float4 w0 = *(const float4*)&W2[(size_t)(k + 0) * H3 + c0];
        float4 w1 = *(const float4*)&W2[(size_t)(k + 1) * H3 + c0];
        float4 w2 = *(const float4*)&W2[(size_t)(k + 2) * H3 + c0];
        float4 w3 = *(const float4*)&W2[(size_t)(k + 3) * H3 + c0];
        #pragma unroll
        for (int i = 0; i < 4; i++) {
            float4 hv = *(const float4*)&h_s[ng * 4 + i][k];
            FMA4(acc[i], hv.x, w0); FMA4(acc[i], hv.y, w1);
            FMA4(acc[i], hv.z, w2); FMA4(acc[i], hv.w, w3);
        }
    }
    #pragma unroll
    for (int i = 0; i < 4; i++)
        *(float4*)&x[(size_t)(n0 + ng * 4 + i) * H3 + c0] = acc[i];
}

// ---------------------------------------------------------------------------
// Filter MLP for 32 sorted slots/block; writes bf16 filters contiguously in
// sorted order. filt[j] = (silu(rbf[e]@Wf1+bf1)@Wf2+bf2)*cutoff[e], e=sorted_eid[j]
// ---------------------------------------------------------------------------
__global__ __launch_bounds__(384) void filter_kernel(
    const int* __restrict__ sorted_eid, const float* __restrict__ rbf,
    const float* __restrict__ cutoff,
    const float* __restrict__ Wf1, const float* __restrict__ bf1,
    const float* __restrict__ Wf2, const float* __restrict__ bf2,
    unsigned short* __restrict__ filt) {
    __shared__ __align__(16) float rbf_s[32][NRBF];
    __shared__ __align__(16) float h1_s[32][H];
    __shared__ int eid_s[32];
    __shared__ float cut_s[32];
    const int t = threadIdx.x;
    const int j0 = blockIdx.x * 32;

    if (t < 32) {
        int e = sorted_eid[j0 + t];
        eid_s[t] = e;
        cut_s[t] = cutoff[e];
    }
    __syncthreads();
    for (int w = t; w < 32 * NRBF; w += 384) {
        int i = w / NRBF, k = w % NRBF;
        rbf_s[i][k] = rbf[(size_t)eid_s[i] * NRBF + k];
    }
    __syncthreads();

    // layer 1
    for (int w = t; w < 32 * H; w += 384) {
        int i = w >> 7, c = w & 127;
        float a = bf1[c];
        #pragma unroll
        for (int k = 0; k < NRBF; k++) a = fmaf(rbf_s[i][k], Wf1[k * H + c], a);
        h1_s[i][c] = silu_f(a);
    }
    __syncthreads();

    // layer 2: 8 slots x 4 cols per thread
    {
        const int cg = t % 96, eg = t / 96;
        const int c0 = cg * 4;
        float4 acc[8];
        {
            float4 bv = *(const float4*)&bf2[c0];
            #pragma unroll
            for (int i = 0; i < 8; i++) acc[i] = bv;
        }
        for (int k = 0; k < H; k += 4) {
            float4 w0 = *(const float4*)&Wf2[(size_t)(k + 0) * H3 + c0];
            float4 w1 = *(const float4*)&Wf2[(size_t)(k + 1) * H3 + c0];
            float4 w2 = *(const float4*)&Wf2[(size_t)(k + 2) * H3 + c0];
            float4 w3 = *(const float4*)&Wf2[(size_t)(k + 3) * H3 + c0];
            #pragma unroll
            for (int i = 0; i < 8; i++) {
                float4 hv = *(const float4*)&h1_s[eg * 8 + i][k];
                FMA4(acc[i], hv.x, w0); FMA4(acc[i], hv.y, w1);
                FMA4(acc[i], hv.z, w2); FMA4(acc[i], hv.w, w3);
            }
        }
        #pragma unroll
        for (int i = 0; i < 8; i++) {
            int slot = eg * 8 + i;
            float cu = cut_s[slot];
            ushort4 o;
            o.x = f2b(acc[i].x * cu); o.y = f2b(acc[i].y * cu);
            o.z = f2b(acc[i].z * cu); o.w = f2b(acc[i].w * cu);
            *(ushort4*)&filt[(size_t)(j0 + slot) * H3 + c0] = o;
        }
    }
}

// ---------------------------------------------------------------------------
// Gather: 2 nodes per 256-thread block; thread owns channel cc of its node.
// Accumulates q_msg + 3 mu_msg components in registers. No atomics.
// ---------------------------------------------------------------------------
__global__ __launch_bounds__(256) void gather_kernel(
    const int* __restrict__ off, const int* __restrict__ sorted_src,
    const float* __restrict__ sorted_unit, const unsigned short* __restrict__ filt,
    const float* __restrict__ x, const float* __restrict__ mu,
    float* __restrict__ acc_q, float* __restrict__ acc_mu) {
    const int t = threadIdx.x;
    const int n = blockIdx.x * 2 + (t >> 7);
    const int cc = t & 127;
    const int j0 = off[n], j1 = off[n + 1];

    float aq = 0.f, am0 = 0.f, am1 = 0.f, am2 = 0.f;
    for (int j = j0; j < j1; ++j) {
        int src = sorted_src[j];
        float u0 = sorted_unit[j * 3 + 0];
        float u1 = sorted_unit[j * 3 + 1];
        float u2 = sorted_unit[j * 3 + 2];
        const float* xrow = x + (size_t)src * H3;
        const float* murow = mu + (size_t)src * H3;
        const unsigned short* frow = filt + (size_t)j * H3;
        float fq = b2f(frow[cc]);
        float fr = b2f(frow[cc + H]);
        float fm = b2f(frow[cc + 2 * H]);
        float xq = xrow[cc], xr = xrow[cc + H], xm = xrow[cc + 2 * H];
        float m0 = murow[cc], m1 = murow[cc + H], m2 = murow[cc + 2 * H];
        float xrs = xr * fr;
        float xms = xm * fm;
        aq  = fmaf(xq, fq, aq);
        am0 = fmaf(u0, xrs, am0); am0 = fmaf(m0, xms, am0);
        am1 = fmaf(u1, xrs, am1); am1 = fmaf(m1, xms, am1);
        am2 = fmaf(u2, xrs, am2); am2 = fmaf(m2, xms, am2);
    }
    acc_q[(size_t)n * H + cc] = aq;
    acc_mu[(size_t)n * H3 + cc] = am0;
    acc_mu[(size_t)n * H3 + H + cc] = am1;
    acc_mu[(size_t)n * H3 + 2 * H + cc] = am2;
}

// ---------------------------------------------------------------------------
// Mixing: per node. 8 nodes per block, 384 threads.
// ---------------------------------------------------------------------------
__global__ __launch_bounds__(384) void mix_kernel(
    const float* __restrict__ q, const float* __restrict__ mu,
    const float* __restrict__ acc_q, const float* __restrict__ acc_mu,
    const float* __restrict__ W_vec,
    const float* __restrict__ W_mix1, const float* __restrict__ b_mix1,
    const float* __restrict__ W_mix2, const float* __restrict__ b_mix2,
    float* __restrict__ q_out, float* __restrict__ mu_out) {
    __shared__ __align__(16) float qn_s[8 * H];
    __shared__ __align__(16) float mun_s[8 * H3];
    __shared__ __align__(16) float muw_s[8 * H3];
    __shared__ __align__(16) float norm_s[8 * H];
    __shared__ __align__(16) float inner_s[8 * H];
    __shared__ __align__(16) float delta_s[8 * H3];
    __shared__ __align__(16) float muvh_s[8 * H3];
    const int t = threadIdx.x;
    const int n0 = blockIdx.x * 8;

    for (int w = t; w < 8 * H / 4; w += 384) {
        int idx = w * 4;
        float4 a = *(const float4*)&q[(size_t)n0 * H + idx];
        float4 b = *(const float4*)&acc_q[(size_t)n0 * H + idx];
        a.x += b.x; a.y += b.y; a.z += b.z; a.w += b.w;
        *(float4*)&qn_s[idx] = a;
    }
    for (int w = t; w < 8 * H3 / 4; w += 384) {
        int idx = w * 4;
        float4 a = *(const float4*)&mu[(size_t)n0 * H3 + idx];
        float4 b = *(const float4*)&acc_mu[(size_t)n0 * H3 + idx];
        a.x += b.x; a.y += b.y; a.z += b.z; a.w += b.w;
        *(float4*)&mun_s[idx] = a;
    }
    __syncthreads();

    {
        const int cg = t % 64, g = t / 64;
        const int c0 = cg * 4;
        float4 acc[4];
        float4 z; z.x = z.y = z.z = z.w = 0.f;
        #pragma unroll
        for (int i = 0; i < 4; i++) acc[i] = z;
        for (int k = 0; k < H; k += 4) {
            float4 w0 = *(const float4*)&W_vec[(size_t)(k + 0) * H2 + c0];
            float4 w1 = *(const float4*)&W_vec[(size_t)(k + 1) * H2 + c0];
            float4 w2 = *(const float4*)&W_vec[(size_t)(k + 2) * H2 + c0];
            float4 w3 = *(const float4*)&W_vec[(size_t)(k + 3) * H2 + c0];
            #pragma unroll
            for (int i = 0; i < 4; i++) {
                float4 m = *(const float4*)&mun_s[(g * 4 + i) * H + k];
                FMA4(acc[i], m.x, w0); FMA4(acc[i], m.y, w1);
                FMA4(acc[i], m.z, w2); FMA4(acc[i], m.w, w3);
            }
        }
        #pragma unroll
        for (int i = 0; i < 4; i++) {
            int nd = g * 4 + i;
            if (c0 < H) *(float4*)&muvh_s[nd * H + c0] = acc[i];
            else        *(float4*)&muw_s[nd * H + (c0 - H)] = acc[i];
        }
    }
    __syncthreads();

    for (int w = t; w < 8 * H / 4; w += 384) {
        int n = w / 32, c4 = (w % 32) * 4;
        float4 v0 = *(const float4*)&muvh_s[(n * 3 + 0) * H + c4];
        float4 v1 = *(const float4*)&muvh_s[(n * 3 + 1) * H + c4];
        float4 v2 = *(const float4*)&muvh_s[(n * 3 + 2) * H + c4];
        float4 w0 = *(const float4*)&muw_s[(n * 3 + 0) * H + c4];
        float4 w1 = *(const float4*)&muw_s[(n * 3 + 1) * H + c4];
        float4 w2 = *(const float4*)&muw_s[(n * 3 + 2) * H + c4];
        float4 nr, in_;
        nr.x = sqrtf(v0.x * v0.x + v1.x * v1.x + v2.x * v2.x + 1e-8f);
        nr.y = sqrtf(v0.y * v0.y + v1.y * v1.y + v2.y * v2.y + 1e-8f);
        nr.z = sqrtf(v0.z * v0.z + v1.z * v1.z + v2.z * v2.z + 1e-8f);
        nr.w = sqrtf(v0.w * v0.w + v1.w * v1.w + v2.w * v2.w + 1e-8f);
        in_.x = v0.x * w0.x + v1.x * w1.x + v2.x * w2.x;
        in_.y = v0.y * w0.y + v1.y * w1.y + v2.y * w2.y;
        in_.z = v0.z * w0.z + v1.z * w1.z + v2.z * w2.z;
        in_.w = v0.w * w0.w + v1.w * w1.w + v2.w * w2.w;
        *(float4*)&norm_s[n * H + c4] = nr;
        *(float4*)&inner_s[n * H + c4] = in_;
    }
    __syncthreads();

    const int cg = t % 96, ng = t / 96;
    const int c0 = cg * 4;

    {
        float4 acc[2];
        float4 bv = *(const float4*)&b_mix1[c0];
        acc[0] = bv; acc[1] = bv;
        for (int k = 0; k < H; k += 4) {
            float4 w0 = *(const float4*)&W_mix1[(size_t)(k + 0) * H3 + c0];
            float4 w1 = *(const float4*)&W_mix1[(size_t)(k + 1) * H3 + c0];
            float4 w2 = *(const float4*)&W_mix1[(size_t)(k + 2) * H3 + c0];
            float4 w3 = *(const float4*)&W_mix1[(size_t)(k + 3) * H3 + c0];
            #pragma unroll
            for (int i = 0; i < 2; i++) {
                float4 s = *(const float4*)&qn_s[(ng * 2 + i) * H + k];
                FMA4(acc[i], s.x, w0); FMA4(acc[i], s.y, w1);
                FMA4(acc[i], s.z, w2); FMA4(acc[i], s.w, w3);
            }
        }
        for (int k = 0; k < H; k += 4) {
            float4 w0 = *(const float4*)&W_mix1[(size_t)(H + k + 0) * H3 + c0];
            float4 w1 = *(const float4*)&W_mix1[(size_t)(H + k + 1) * H3 + c0];
            float4 w2 = *(const float4*)&W_mix1[(size_t)(H + k + 2) * H3 + c0];
            float4 w3 = *(const float4*)&W_mix1[(size_t)(H + k + 3) * H3 + c0];
            #pragma unroll
            for (int i = 0; i < 2; i++) {
                float4 s = *(const float4*)&norm_s[(ng * 2 + i) * H + k];
                FMA4(acc[i], s.x, w0); FMA4(acc[i], s.y, w1);
                FMA4(acc[i], s.z, w2); FMA4(acc[i], s.w, w3);
            }
        }
        #pragma unroll
        for (int i = 0; i < 2; i++) {
            float4 v = acc[i];
            v.x = silu_f(v.x); v.y = silu_f(v.y); v.z = silu_f(v.z); v.w = silu_f(v.w);
            *(float4*)&muvh_s[(ng * 2 + i) * H3 + c0] = v;
        }
    }
    __syncthreads();

    {
        float4 acc[2];
        float4 bv = *(const float4*)&b_mix2[c0];
        acc[0] = bv; acc[1] = bv;
        for (int k = 0; k < H3; k += 4) {
            float4 w0 = *(const float4*)&W_mix2[(size_t)(k + 0) * H3 + c0];
            float4 w1 = *(const float4*)&W_mix2[(size_t)(k + 1) * H3 + c0];
            float4 w2 = *(const float4*)&W_mix2[(size_t)(k + 2) * H3 + c0];
            float4 w3 = *(const float4*)&W_mix2[(size_t)(k + 3) * H3 + c0];
            #pragma unroll
            for (int i = 0; i < 2; i++) {
                float4 s = *(const float4*)&muvh_s[(ng * 2 + i) * H3 + k];
                FMA4(acc[i], s.x, w0); FMA4(acc[i], s.y, w1);
                FMA4(acc[i], s.z, w2); FMA4(acc[i], s.w, w3);
            }
        }
        #pragma unroll
        for (int i = 0; i < 2; i++)
            *(float4*)&delta_s[(ng * 2 + i) * H3 + c0] = acc[i];
    }
    __syncthreads();

    for (int w = t; w < 8 * H / 4; w += 384) {
        int n = w / 32, c4 = (w % 32) * 4;
        int node = n0 + n;
        float4 qn = *(const float4*)&qn_s[n * H + c4];
        float4 dq = *(const float4*)&delta_s[n * H3 + c4];
        float4 dqm = *(const float4*)&delta_s[n * H3 + 2 * H + c4];
        float4 in_ = *(const float4*)&inner_s[n * H + c4];
        float4 o;
        o.x = qn.x + dq.x + dqm.x * in_.x;
        o.y = qn.y + dq.y + dqm.y * in_.y;
        o.z = qn.z + dq.z + dqm.z * in_.z;
        o.w = qn.w + dq.w + dqm.w * in_.w;
        *(float4*)&q_out[(size_t)node * H + c4] = o;
    }
    for (int w = t; w < 8 * H3 / 4; w += 384) {
        int n = w / 96, r = w % 96;
        int d = r / 32, c4 = (r % 32) * 4;
        int node = n0 + n;
        float4 m = *(const float4*)&mun_s[n * H3 + d * H + c4];
        float4 mw = *(const float4*)&muw_s[(n * 3 + d) * H + c4];
        float4 dms = *(const float4*)&delta_s[n * H3 + H + c4];
        float4 o;
        o.x = m.x + mw.x * dms.x;
        o.y = m.y + mw.y * dms.y;
        o.z = m.z + mw.z * dms.z;
        o.w = m.w + mw.w * dms.w;
        *(float4*)&mu_out[((size_t)node * 3 + d) * H + c4] = o;
    }
}

extern "C" void kernel_launch(void* const* d_in, const int* in_sizes, int n_in,
                              void* d_out, int out_size, void* d_ws, size_t ws_size,
                              hipStream_t stream) {
    const float* q        = (const float*)d_in[0];
    const float* mu       = (const float*)d_in[1];
    const int*   eidx     = (const int*)d_in[2];
    const float* rbf      = (const float*)d_in[3];
    const float* unitv    = (const float*)d_in[4];
    const float* cutoff   = (const float*)d_in[5];
    const float* W_inter1 = (const float*)d_in[6];
    const float* b_inter1 = (const float*)d_in[7];
    const float* W_inter2 = (const float*)d_in[8];
    const float* b_inter2 = (const float*)d_in[9];
    const float* W_filt1  = (const float*)d_in[10];
    const float* b_filt1  = (const float*)d_in[11];
    const float* W_filt2  = (const float*)d_in[12];
    const float* b_filt2  = (const float*)d_in[13];
    const float* W_vec    = (const float*)d_in[14];
    const float* W_mix1   = (const float*)d_in[15];
    const float* b_mix1   = (const float*)d_in[16];
    const float* W_mix2   = (const float*)d_in[17];
    const float* b_mix2   = (const float*)d_in[18];

    // workspace layout (bytes, 256-aligned chunks)
    char* p = (char*)d_ws;
    float* x           = (float*)p;            p += (size_t)NN * H3 * 4;      // 15.36 MB
    float* acc_q       = (float*)p;            p += (size_t)NN * H * 4;       //  5.12 MB
    float* acc_mu      = (float*)p;            p += (size_t)NN * H3 * 4;      // 15.36 MB
    float* sorted_unit = (float*)p;            p += (size_t)NE * 3 * 4;       //  3.07 MB
    int*   counts      = (int*)p;              p += (size_t)NN * 4;
    int*   off         = (int*)p;              p += (size_t)(NN + 1) * 4;
    p = (char*)(((size_t)p + 255) & ~(size_t)255);
    int*   cursor      = (int*)p;              p += (size_t)NN * 4;
    p = (char*)(((size_t)p + 255) & ~(size_t)255);
    int*   sorted_eid  = (int*)p;              p += (size_t)NE * 4;           //  1.02 MB
    int*   sorted_src  = (int*)p;              p += (size_t)NE * 4;           //  1.02 MB
    p = (char*)(((size_t)p + 255) & ~(size_t)255);
    unsigned short* filt = (unsigned short*)p; p += (size_t)NE * H3 * 2;      // 196.6 MB

    float* q_out  = (float*)d_out;
    float* mu_out = q_out + (size_t)NN * H;

    hipMemsetAsync(counts, 0, (size_t)NN * 4, stream);

    hist_kernel <<<NE / 256, 256, 0, stream>>>(eidx, counts);
    scan_kernel <<<1, 1024, 0, stream>>>(counts, off, cursor);
    place_kernel<<<NE / 256, 256, 0, stream>>>(eidx, unitv, cursor,
                                               sorted_eid, sorted_src, sorted_unit);
    node_x_kernel<<<NN / 16, 384, 0, stream>>>(q, W_inter1, b_inter1, W_inter2, b_inter2, x);
    filter_kernel<<<NE / 32, 384, 0, stream>>>(sorted_eid, rbf, cutoff,
                                               W_filt1, b_filt1, W_filt2, b_filt2, filt);
    gather_kernel<<<NN / 2, 256, 0, stream>>>(off, sorted_src, sorted_unit, filt,
                                              x, mu, acc_q, acc_mu);
    mix_kernel  <<<NN / 8, 384, 0, stream>>>(q, mu, acc_q, acc_mu, W_vec,
                                             W_mix1, b_mix1, W_mix2, b_mix2,
                                             q_out, mu_out);
}

// Round 4
// 704.067 us; speedup vs baseline: 3.0606x; 1.3885x over previous
//
#include <hip/hip_runtime.h>

#define NN 10000
#define NE 256000
#define H 128
#define H2 256
#define H3 384
#define NRBF 20

typedef __attribute__((ext_vector_type(8))) short bf16x8;
typedef __attribute__((ext_vector_type(4))) float f32x4;

__device__ __forceinline__ void FMA4(float4& a, float s, const float4& v) {
    a.x = fmaf(s, v.x, a.x); a.y = fmaf(s, v.y, a.y);
    a.z = fmaf(s, v.z, a.z); a.w = fmaf(s, v.w, a.w);
}

__device__ __forceinline__ float silu_f(float v) { return v / (1.f + __expf(-v)); }

// fp32 -> bf16 bits (RNE)
__device__ __forceinline__ unsigned short f2b(float f) {
    union { float f; unsigned u; } x; x.f = f;
    unsigned r = (x.u + 0x7FFFu + ((x.u >> 16) & 1u)) >> 16;
    return (unsigned short)r;
}
__device__ __forceinline__ float b2f(unsigned short b) {
    union { unsigned u; float f; } x; x.u = ((unsigned)b) << 16;
    return x.f;
}

// ---------------------------------------------------------------------------
// CSR build: histogram of targets
// ---------------------------------------------------------------------------
__global__ __launch_bounds__(256) void hist_kernel(const int* __restrict__ eidx,
                                                   int* __restrict__ counts) {
    int e = blockIdx.x * 256 + threadIdx.x;
    atomicAdd(&counts[eidx[e]], 1);
}

// Single-block exclusive scan over NN counts -> off[NN+1], cursor copy.
__global__ __launch_bounds__(1024) void scan_kernel(const int* __restrict__ counts,
                                                    int* __restrict__ off,
                                                    int* __restrict__ cursor) {
    __shared__ int sums[1024];
    const int t = threadIdx.x;
    const int base = t * 10;
    int local[10];
    int s = 0;
    #pragma unroll
    for (int i = 0; i < 10; i++) {
        int idx = base + i;
        int v = (idx < NN) ? counts[idx] : 0;
        local[i] = s; s += v;
    }
    sums[t] = s;
    __syncthreads();
    for (int d = 1; d < 1024; d <<= 1) {
        int v = (t >= d) ? sums[t - d] : 0;
        __syncthreads();
        sums[t] += v;
        __syncthreads();
    }
    int prefix = (t > 0) ? sums[t - 1] : 0;
    #pragma unroll
    for (int i = 0; i < 10; i++) {
        int idx = base + i;
        if (idx < NN) { off[idx] = prefix + local[i]; cursor[idx] = prefix + local[i]; }
    }
    if (t == 1023) off[NN] = sums[1023];
}

// Place edges into target-sorted order; copy src + unit vector alongside.
__global__ __launch_bounds__(256) void place_kernel(
    const int* __restrict__ eidx, const float* __restrict__ unitv,
    int* __restrict__ cursor, int* __restrict__ sorted_eid,
    int* __restrict__ sorted_src, float* __restrict__ sorted_unit) {
    int e = blockIdx.x * 256 + threadIdx.x;
    int tgt = eidx[e];
    int src = eidx[NE + e];
    int pos = atomicAdd(&cursor[tgt], 1);
    sorted_eid[pos] = e;
    sorted_src[pos] = src;
    sorted_unit[pos * 3 + 0] = unitv[(size_t)e * 3 + 0];
    sorted_unit[pos * 3 + 1] = unitv[(size_t)e * 3 + 1];
    sorted_unit[pos * 3 + 2] = unitv[(size_t)e * 3 + 2];
}

// ---------------------------------------------------------------------------
// Pack Wf2 [128,384] fp32 -> bf16 in MFMA B-fragment order.
// Bp[((c*4+kt)*64+lane)*8 + j] = bf16(Wf2[kt*32 + (lane>>4)*8 + j][c*16 + (lane&15)])
// 24 blocks x 256 threads; thread = (kt, lane) for col-tile c = blockIdx.x.
// ---------------------------------------------------------------------------
__global__ __launch_bounds__(256) void pack_b_kernel(const float* __restrict__ Wf2,
                                                     unsigned short* __restrict__ Bp) {
    const int c = blockIdx.x;
    const int kt = threadIdx.x >> 6, lane = threadIdx.x & 63;
    const int m = lane & 15, qd = lane >> 4;
    unsigned short v[8];
    #pragma unroll
    for (int j = 0; j < 8; j++) {
        int k = kt * 32 + qd * 8 + j;
        v[j] = f2b(Wf2[(size_t)k * H3 + c * 16 + m]);
    }
    size_t base = ((size_t)(c * 4 + kt) * 64 + lane) * 8;
    *(ushort4*)&Bp[base]     = *(ushort4*)&v[0];
    *(ushort4*)&Bp[base + 4] = *(ushort4*)&v[4];
}

// ---------------------------------------------------------------------------
// x = silu(q @ W1 + b1) @ W2 + b2      [NN, 384]
// ---------------------------------------------------------------------------
__global__ __launch_bounds__(384) void node_x_kernel(
    const float* __restrict__ q,
    const float* __restrict__ W1, const float* __restrict__ b1,
    const float* __restrict__ W2, const float* __restrict__ b2,
    float* __restrict__ x) {
    __shared__ __align__(16) float q_s[16][H];
    __shared__ __align__(16) float h_s[16][H3];
    const int t = threadIdx.x;
    const int n0 = blockIdx.x * 16;

    for (int w = t; w < 16 * H / 4; w += 384) {
        int n = w / 32, c4 = (w % 32) * 4;
        *(float4*)&q_s[n][c4] = *(const float4*)&q[(size_t)(n0 + n) * H + c4];
    }
    __syncthreads();

    const int cg = t % 96, ng = t / 96;
    const int c0 = cg * 4;

    float4 acc[4];
    {
        float4 bv = *(const float4*)&b1[c0];
        #pragma unroll
        for (int i = 0; i < 4; i++) acc[i] = bv;
    }
    for (int k = 0; k < H; k += 4) {
        float4 w0 = *(const float4*)&W1[(size_t)(k + 0) * H3 + c0];
        float4 w1 = *(const float4*)&W1[(size_t)(k + 1) * H3 + c0];
        float4 w2 = *(const float4*)&W1[(size_t)(k + 2) * H3 + c0];
        float4 w3 = *(const float4*)&W1[(size_t)(k + 3) * H3 + c0];
        #pragma unroll
        for (int i = 0; i < 4; i++) {
            float4 qv = *(const float4*)&q_s[ng * 4 + i][k];
            FMA4(acc[i], qv.x, w0); FMA4(acc[i], qv.y, w1);
            FMA4(acc[i], qv.z, w2); FMA4(acc[i], qv.w, w3);
        }
    }
    #pragma unroll
    for (int i = 0; i < 4; i++) {
        float4 v = acc[i];
        v.x = silu_f(v.x); v.y = silu_f(v.y); v.z = silu_f(v.z); v.w = silu_f(v.w);
        *(float4*)&h_s[ng * 4 + i][c0] = v;
    }
    __syncthreads();

    {
        float4 bv = *(const float4*)&b2[c0];
        #pragma unroll
        for (int i = 0; i < 4; i++) acc[i] = bv;
    }
    for (int k = 0; k < H3; k += 4) {
        float4 w0 = *(const float4*)&W2[(size_t)(k + 0) * H3 + c0];
        float4 w1 = *(const float4*)&W2[(size_t)(k + 1) * H3 + c0];
        float4 w2 = *(const float4*)&W2[(size_t)(k + 2) * H3 + c0];
        float4 w3 = *(const float4*)&W2[(size_t)(k + 3) * H3 + c0];
        #pragma unroll
        for (int i = 0; i < 4; i++) {
            float4 hv = *(const float4*)&h_s[ng * 4 + i][k];
            FMA4(acc[i], hv.x, w0); FMA4(acc[i], hv.y, w1);
            FMA4(acc[i], hv.z, w2); FMA4(acc[i], hv.w, w3);
        }
    }
    #pragma unroll
    for (int i = 0; i < 4; i++)
        *(float4*)&x[(size_t)(n0 + ng * 4 + i) * H3 + c0] = acc[i];
}

// ---------------------------------------------------------------------------
// Filter MLP, MFMA version. 64 sorted slots per 256-thread block (4 waves).
// Layer 1 (K=20) on VALU -> h1 bf16 in LDS. Layer 2 (64x384, K=128) on
// mfma_f32_16x16x32_bf16: wave w owns slots [w*16, w*16+16), loops 24 col
// tiles x 4 K-steps. B-fragments from pre-packed Bp (coalesced 16B/lane).
// ---------------------------------------------------------------------------
__global__ __launch_bounds__(256) void filter_kernel(
    const int* __restrict__ sorted_eid, const float* __restrict__ rbf,
    const float* __restrict__ cutoff,
    const float* __restrict__ Wf1, const float* __restrict__ bf1,
    const unsigned short* __restrict__ Bp, const float* __restrict__ bf2,
    unsigned short* __restrict__ filt) {
    __shared__ __align__(16) float rbf_s[64][NRBF];
    __shared__ __align__(16) unsigned short h1_s[64][136];   // +8 pad: break 32-bank stride
    __shared__ float cut_s[64];
    __shared__ int eid_s[64];
    const int t = threadIdx.x;
    const size_t j0 = (size_t)blockIdx.x * 64;

    if (t < 64) {
        int e = sorted_eid[j0 + t];
        eid_s[t] = e;
        cut_s[t] = cutoff[e];
    }
    __syncthreads();
    for (int w = t; w < 64 * NRBF; w += 256) {
        int i = w / NRBF, k = w % NRBF;
        rbf_s[i][k] = rbf[(size_t)eid_s[i] * NRBF + k];
    }
    __syncthreads();

    // layer 1: thread owns column c = t&127 for 32 slots; Wf1 col in registers
    {
        const int c = t & 127;
        float wr[NRBF];
        #pragma unroll
        for (int k = 0; k < NRBF; k++) wr[k] = Wf1[k * H + c];
        const float bv = bf1[c];
        for (int s = (t >> 7); s < 64; s += 2) {
            float a = bv;
            #pragma unroll
            for (int k = 0; k < NRBF; k++) a = fmaf(rbf_s[s][k], wr[k], a);
            h1_s[s][c] = f2b(silu_f(a));
        }
    }
    __syncthreads();

    // layer 2: MFMA
    {
        const int wv = t >> 6;              // wave 0..3 -> slot row
        const int lane = t & 63;
        const int m = lane & 15, qd = lane >> 4;
        const unsigned short* arow = &h1_s[wv * 16 + m][qd * 8];
        #pragma unroll 1
        for (int c = 0; c < 24; c++) {
            f32x4 acc = {0.f, 0.f, 0.f, 0.f};
            #pragma unroll
            for (int kt = 0; kt < 4; kt++) {
                bf16x8 af = *(const bf16x8*)(arow + kt * 32);
                bf16x8 bfr = *(const bf16x8*)(Bp + ((size_t)(c * 4 + kt) * 64 + lane) * 8);
                acc = __builtin_amdgcn_mfma_f32_16x16x32_bf16(af, bfr, acc, 0, 0, 0);
            }
            const int col = c * 16 + m;
            const float bb = bf2[col];
            #pragma unroll
            for (int r = 0; r < 4; r++) {
                int slot = wv * 16 + qd * 4 + r;
                float v = (acc[r] + bb) * cut_s[slot];
                filt[(j0 + slot) * H3 + col] = f2b(v);
            }
        }
    }
}

// ---------------------------------------------------------------------------
// Gather: 2 nodes per 256-thread block; thread owns channel cc of its node.
// ---------------------------------------------------------------------------
__global__ __launch_bounds__(256) void gather_kernel(
    const int* __restrict__ off, const int* __restrict__ sorted_src,
    const float* __restrict__ sorted_unit, const unsigned short* __restrict__ filt,
    const float* __restrict__ x, const float* __restrict__ mu,
    float* __restrict__ acc_q, float* __restrict__ acc_mu) {
    const int t = threadIdx.x;
    const int n = blockIdx.x * 2 + (t >> 7);
    const int cc = t & 127;
    const int j0 = off[n], j1 = off[n + 1];

    float aq = 0.f, am0 = 0.f, am1 = 0.f, am2 = 0.f;
    for (int j = j0; j < j1; ++j) {
        int src = sorted_src[j];
        float u0 = sorted_unit[j * 3 + 0];
        float u1 = sorted_unit[j * 3 + 1];
        float u2 = sorted_unit[j * 3 + 2];
        const float* xrow = x + (size_t)src * H3;
        const float* murow = mu + (size_t)src * H3;
        const unsigned short* frow = filt + (size_t)j * H3;
        float fq = b2f(frow[cc]);
        float fr = b2f(frow[cc + H]);
        float fm = b2f(frow[cc + 2 * H]);
        float xq = xrow[cc], xr = xrow[cc + H], xm = xrow[cc + 2 * H];
        float m0 = murow[cc], m1 = murow[cc + H], m2 = murow[cc + 2 * H];
        float xrs = xr * fr;
        float xms = xm * fm;
        aq  = fmaf(xq, fq, aq);
        am0 = fmaf(u0, xrs, am0); am0 = fmaf(m0, xms, am0);
        am1 = fmaf(u1, xrs, am1); am1 = fmaf(m1, xms, am1);
        am2 = fmaf(u2, xrs, am2); am2 = fmaf(m2, xms, am2);
    }
    acc_q[(size_t)n * H + cc] = aq;
    acc_mu[(size_t)n * H3 + cc] = am0;
    acc_mu[(size_t)n * H3 + H + cc] = am1;
    acc_mu[(size_t)n * H3 + 2 * H + cc] = am2;
}

// ---------------------------------------------------------------------------
// Mixing: per node. 8 nodes per block, 384 threads.
// ---------------------------------------------------------------------------
__global__ __launch_bounds__(384) void mix_kernel(
    const float* __restrict__ q, const float* __restrict__ mu,
    const float* __restrict__ acc_q, const float* __restrict__ acc_mu,
    const float* __restrict__ W_vec,
    const float* __restrict__ W_mix1, const float* __restrict__ b_mix1,
    const float* __restrict__ W_mix2, const float* __restrict__ b_mix2,
    float* __restrict__ q_out, float* __restrict__ mu_out) {
    __shared__ __align__(16) float qn_s[8 * H];
    __shared__ __align__(16) float mun_s[8 * H3];
    __shared__ __align__(16) float muw_s[8 * H3];
    __shared__ __align__(16) float norm_s[8 * H];
    __shared__ __align__(16) float inner_s[8 * H];
    __shared__ __align__(16) float delta_s[8 * H3];
    __shared__ __align__(16) float muvh_s[8 * H3];
    const int t = threadIdx.x;
    const int n0 = blockIdx.x * 8;

    for (int w = t; w < 8 * H / 4; w += 384) {
        int idx = w * 4;
        float4 a = *(const float4*)&q[(size_t)n0 * H + idx];
        float4 b = *(const float4*)&acc_q[(size_t)n0 * H + idx];
        a.x += b.x; a.y += b.y; a.z += b.z; a.w += b.w;
        *(float4*)&qn_s[idx] = a;
    }
    for (int w = t; w < 8 * H3 / 4; w += 384) {
        int idx = w * 4;
        float4 a = *(const float4*)&mu[(size_t)n0 * H3 + idx];
        float4 b = *(const float4*)&acc_mu[(size_t)n0 * H3 + idx];
        a.x += b.x; a.y += b.y; a.z += b.z; a.w += b.w;
        *(float4*)&mun_s[idx] = a;
    }
    __syncthreads();

    {
        const int cg = t % 64, g = t / 64;
        const int c0 = cg * 4;
        float4 acc[4];
        float4 z; z.x = z.y = z.z = z.w = 0.f;
        #pragma unroll
        for (int i = 0; i < 4; i++) acc[i] = z;
        for (int k = 0; k < H; k += 4) {
            float4 w0 = *(const float4*)&W_vec[(size_t)(k + 0) * H2 + c0];
            float4 w1 = *(const float4*)&W_vec[(size_t)(k + 1) * H2 + c0];
            float4 w2 = *(const float4*)&W_vec[(size_t)(k + 2) * H2 + c0];
            float4 w3 = *(const float4*)&W_vec[(size_t)(k + 3) * H2 + c0];
            #pragma unroll
            for (int i = 0; i < 4; i++) {
                float4 m = *(const float4*)&mun_s[(g * 4 + i) * H + k];
                FMA4(acc[i], m.x, w0); FMA4(acc[i], m.y, w1);
                FMA4(acc[i], m.z, w2); FMA4(acc[i], m.w, w3);
            }
        }
        #pragma unroll
        for (int i = 0; i < 4; i++) {
            int nd = g * 4 + i;
            if (c0 < H) *(float4*)&muvh_s[nd * H + c0] = acc[i];
            else        *(float4*)&muw_s[nd * H + (c0 - H)] = acc[i];
        }
    }
    __syncthreads();

    for (int w = t; w < 8 * H / 4; w += 384) {
        int n = w / 32, c4 = (w % 32) * 4;
        float4 v0 = *(const float4*)&muvh_s[(n * 3 + 0) * H + c4];
        float4 v1 = *(const float4*)&muvh_s[(n * 3 + 1) * H + c4];
        float4 v2 = *(const float4*)&muvh_s[(n * 3 + 2) * H + c4];
        float4 w0 = *(const float4*)&muw_s[(n * 3 + 0) * H + c4];
        float4 w1 = *(const float4*)&muw_s[(n * 3 + 1) * H + c4];
        float4 w2 = *(const float4*)&muw_s[(n * 3 + 2) * H + c4];
        float4 nr, in_;
        nr.x = sqrtf(v0.x * v0.x + v1.x * v1.x + v2.x * v2.x + 1e-8f);
        nr.y = sqrtf(v0.y * v0.y + v1.y * v1.y + v2.y * v2.y + 1e-8f);
        nr.z = sqrtf(v0.z * v0.z + v1.z * v1.z + v2.z * v2.z + 1e-8f);
        nr.w = sqrtf(v0.w * v0.w + v1.w * v1.w + v2.w * v2.w + 1e-8f);
        in_.x = v0.x * w0.x + v1.x * w1.x + v2.x * w2.x;
        in_.y = v0.y * w0.y + v1.y * w1.y + v2.y * w2.y;
        in_.z = v0.z * w0.z + v1.z * w1.z + v2.z * w2.z;
        in_.w = v0.w * w0.w + v1.w * w1.w + v2.w * w2.w;
        *(float4*)&norm_s[n * H + c4] = nr;
        *(float4*)&inner_s[n * H + c4] = in_;
    }
    __syncthreads();

    const int cg = t % 96, ng = t / 96;
    const int c0 = cg * 4;

    {
        float4 acc[2];
        float4 bv = *(const float4*)&b_mix1[c0];
        acc[0] = bv; acc[1] = bv;
        for (int k = 0; k < H; k += 4) {
            float4 w0 = *(const float4*)&W_mix1[(size_t)(k + 0) * H3 + c0];
            float4 w1 = *(const float4*)&W_mix1[(size_t)(k + 1) * H3 + c0];
            float4 w2 = *(const float4*)&W_mix1[(size_t)(k + 2) * H3 + c0];
            float4 w3 = *(const float4*)&W_mix1[(size_t)(k + 3) * H3 + c0];
            #pragma unroll
            for (int i = 0; i < 2; i++) {
                float4 s = *(const float4*)&qn_s[(ng * 2 + i) * H + k];
                FMA4(acc[i], s.x, w0); FMA4(acc[i], s.y, w1);
                FMA4(acc[i], s.z, w2); FMA4(acc[i], s.w, w3);
            }
        }
        for (int k = 0; k < H; k += 4) {
            float4 w0 = *(const float4*)&W_mix1[(size_t)(H + k + 0) * H3 + c0];
            float4 w1 = *(const float4*)&W_mix1[(size_t)(H + k + 1) * H3 + c0];
            float4 w2 = *(const float4*)&W_mix1[(size_t)(H + k + 2) * H3 + c0];
            float4 w3 = *(const float4*)&W_mix1[(size_t)(H + k + 3) * H3 + c0];
            #pragma unroll
            for (int i = 0; i < 2; i++) {
                float4 s = *(const float4*)&norm_s[(ng * 2 + i) * H + k];
                FMA4(acc[i], s.x, w0); FMA4(acc[i], s.y, w1);
                FMA4(acc[i], s.z, w2); FMA4(acc[i], s.w, w3);
            }
        }
        #pragma unroll
        for (int i = 0; i < 2; i++) {
            float4 v = acc[i];
            v.x = silu_f(v.x); v.y = silu_f(v.y); v.z = silu_f(v.z); v.w = silu_f(v.w);
            *(float4*)&muvh_s[(ng * 2 + i) * H3 + c0] = v;
        }
    }
    __syncthreads();

    {
        float4 acc[2];
        float4 bv = *(const float4*)&b_mix2[c0];
        acc[0] = bv; acc[1] = bv;
        for (int k = 0; k < H3; k += 4) {
            float4 w0 = *(const float4*)&W_mix2[(size_t)(k + 0) * H3 + c0];
            float4 w1 = *(const float4*)&W_mix2[(size_t)(k + 1) * H3 + c0];
            float4 w2 = *(const float4*)&W_mix2[(size_t)(k + 2) * H3 + c0];
            float4 w3 = *(const float4*)&W_mix2[(size_t)(k + 3) * H3 + c0];
            #pragma unroll
            for (int i = 0; i < 2; i++) {
                float4 s = *(const float4*)&muvh_s[(ng * 2 + i) * H3 + k];
                FMA4(acc[i], s.x, w0); FMA4(acc[i], s.y, w1);
                FMA4(acc[i], s.z, w2); FMA4(acc[i], s.w, w3);
            }
        }
        #pragma unroll
        for (int i = 0; i < 2; i++)
            *(float4*)&delta_s[(ng * 2 + i) * H3 + c0] = acc[i];
    }
    __syncthreads();

    for (int w = t; w < 8 * H / 4; w += 384) {
        int n = w / 32, c4 = (w % 32) * 4;
        int node = n0 + n;
        float4 qn = *(const float4*)&qn_s[n * H + c4];
        float4 dq = *(const float4*)&delta_s[n * H3 + c4];
        float4 dqm = *(const float4*)&delta_s[n * H3 + 2 * H + c4];
        float4 in_ = *(const float4*)&inner_s[n * H + c4];
        float4 o;
        o.x = qn.x + dq.x + dqm.x * in_.x;
        o.y = qn.y + dq.y + dqm.y * in_.y;
        o.z = qn.z + dq.z + dqm.z * in_.z;
        o.w = qn.w + dq.w + dqm.w * in_.w;
        *(float4*)&q_out[(size_t)node * H + c4] = o;
    }
    for (int w = t; w < 8 * H3 / 4; w += 384) {
        int n = w / 96, r = w % 96;
        int d = r / 32, c4 = (r % 32) * 4;
        int node = n0 + n;
        float4 m = *(const float4*)&mun_s[n * H3 + d * H + c4];
        float4 mw = *(const float4*)&muw_s[(n * 3 + d) * H + c4];
        float4 dms = *(const float4*)&delta_s[n * H3 + H + c4];
        float4 o;
        o.x = m.x + mw.x * dms.x;
        o.y = m.y + mw.y * dms.y;
        o.z = m.z + mw.z * dms.z;
        o.w = m.w + mw.w * dms.w;
        *(float4*)&mu_out[((size_t)node * 3 + d) * H + c4] = o;
    }
}

extern "C" void kernel_launch(void* const* d_in, const int* in_sizes, int n_in,
                              void* d_out, int out_size, void* d_ws, size_t ws_size,
                              hipStream_t stream) {
    const float* q        = (const float*)d_in[0];
    const float* mu       = (const float*)d_in[1];
    const int*   eidx     = (const int*)d_in[2];
    const float* rbf      = (const float*)d_in[3];
    const float* unitv    = (const float*)d_in[4];
    const float* cutoff   = (const float*)d_in[5];
    const float* W_inter1 = (const float*)d_in[6];
    const float* b_inter1 = (const float*)d_in[7];
    const float* W_inter2 = (const float*)d_in[8];
    const float* b_inter2 = (const float*)d_in[9];
    const float* W_filt1  = (const float*)d_in[10];
    const float* b_filt1  = (const float*)d_in[11];
    const float* W_filt2  = (const float*)d_in[12];
    const float* b_filt2  = (const float*)d_in[13];
    const float* W_vec    = (const float*)d_in[14];
    const float* W_mix1   = (const float*)d_in[15];
    const float* b_mix1   = (const float*)d_in[16];
    const float* W_mix2   = (const float*)d_in[17];
    const float* b_mix2   = (const float*)d_in[18];

    // workspace layout
    char* p = (char*)d_ws;
    float* x           = (float*)p;            p += (size_t)NN * H3 * 4;
    float* acc_q       = (float*)p;            p += (size_t)NN * H * 4;
    float* acc_mu      = (float*)p;            p += (size_t)NN * H3 * 4;
    float* sorted_unit = (float*)p;            p += (size_t)NE * 3 * 4;
    int*   counts      = (int*)p;              p += (size_t)NN * 4;
    int*   off         = (int*)p;              p += (size_t)(NN + 1) * 4;
    p = (char*)(((size_t)p + 255) & ~(size_t)255);
    int*   cursor      = (int*)p;              p += (size_t)NN * 4;
    p = (char*)(((size_t)p + 255) & ~(size_t)255);
    int*   sorted_eid  = (int*)p;              p += (size_t)NE * 4;
    int*   sorted_src  = (int*)p;              p += (size_t)NE * 4;
    p = (char*)(((size_t)p + 255) & ~(size_t)255);
    unsigned short* Bp = (unsigned short*)p;   p += (size_t)24 * 4 * 64 * 8 * 2;  // 96 KB
    p = (char*)(((size_t)p + 255) & ~(size_t)255);
    unsigned short* filt = (unsigned short*)p; p += (size_t)NE * H3 * 2;

    float* q_out  = (float*)d_out;
    float* mu_out = q_out + (size_t)NN * H;

    hipMemsetAsync(counts, 0, (size_t)NN * 4, stream);

    hist_kernel  <<<NE / 256, 256, 0, stream>>>(eidx, counts);
    pack_b_kernel<<<24, 256, 0, stream>>>(W_filt2, Bp);
    scan_kernel  <<<1, 1024, 0, stream>>>(counts, off, cursor);
    place_kernel <<<NE / 256, 256, 0, stream>>>(eidx, unitv, cursor,
                                                sorted_eid, sorted_src, sorted_unit);
    node_x_kernel<<<NN / 16, 384, 0, stream>>>(q, W_inter1, b_inter1, W_inter2, b_inter2, x);
    filter_kernel<<<NE / 64, 256, 0, stream>>>(sorted_eid, rbf, cutoff,
                                               W_filt1, b_filt1, Bp, b_filt2, filt);
    gather_kernel<<<NN / 2, 256, 0, stream>>>(off, sorted_src, sorted_unit, filt,
                                              x, mu, acc_q, acc_mu);
    mix_kernel   <<<NN / 8, 384, 0, stream>>>(q, mu, acc_q, acc_mu, W_vec,
                                              W_mix1, b_mix1, W_mix2, b_mix2,
                                              q_out, mu_out);
}

// Round 5
// 633.141 us; speedup vs baseline: 3.4035x; 1.1120x over previous
//
#include <hip/hip_runtime.h>

#define NN 10000
#define NE 256000
#define H 128
#define H2 256
#define H3 384
#define NRBF 20

typedef __attribute__((ext_vector_type(8))) short bf16x8;
typedef __attribute__((ext_vector_type(4))) float f32x4;

__device__ __forceinline__ void FMA4(float4& a, float s, const float4& v) {
    a.x = fmaf(s, v.x, a.x); a.y = fmaf(s, v.y, a.y);
    a.z = fmaf(s, v.z, a.z); a.w = fmaf(s, v.w, a.w);
}

__device__ __forceinline__ float silu_f(float v) { return v / (1.f + __expf(-v)); }

// fp32 -> bf16 bits (RNE)
__device__ __forceinline__ unsigned short f2b(float f) {
    union { float f; unsigned u; } x; x.f = f;
    unsigned r = (x.u + 0x7FFFu + ((x.u >> 16) & 1u)) >> 16;
    return (unsigned short)r;
}
__device__ __forceinline__ float b2f(unsigned short b) {
    union { unsigned u; float f; } x; x.u = ((unsigned)b) << 16;
    return x.f;
}

// ---------------------------------------------------------------------------
// CSR build: histogram of targets
// ---------------------------------------------------------------------------
__global__ __launch_bounds__(256) void hist_kernel(const int* __restrict__ eidx,
                                                   int* __restrict__ counts) {
    int e = blockIdx.x * 256 + threadIdx.x;
    atomicAdd(&counts[eidx[e]], 1);
}

// Single-block exclusive scan over NN counts -> off[NN+1], cursor copy.
__global__ __launch_bounds__(1024) void scan_kernel(const int* __restrict__ counts,
                                                    int* __restrict__ off,
                                                    int* __restrict__ cursor) {
    __shared__ int sums[1024];
    const int t = threadIdx.x;
    const int base = t * 10;
    int local[10];
    int s = 0;
    #pragma unroll
    for (int i = 0; i < 10; i++) {
        int idx = base + i;
        int v = (idx < NN) ? counts[idx] : 0;
        local[i] = s; s += v;
    }
    sums[t] = s;
    __syncthreads();
    for (int d = 1; d < 1024; d <<= 1) {
        int v = (t >= d) ? sums[t - d] : 0;
        __syncthreads();
        sums[t] += v;
        __syncthreads();
    }
    int prefix = (t > 0) ? sums[t - 1] : 0;
    #pragma unroll
    for (int i = 0; i < 10; i++) {
        int idx = base + i;
        if (idx < NN) { off[idx] = prefix + local[i]; cursor[idx] = prefix + local[i]; }
    }
    if (t == 1023) off[NN] = sums[1023];
}

// Place edges into target-sorted order; copy src + unit vector alongside.
__global__ __launch_bounds__(256) void place_kernel(
    const int* __restrict__ eidx, const float* __restrict__ unitv,
    int* __restrict__ cursor, int* __restrict__ sorted_eid,
    int* __restrict__ sorted_src, float* __restrict__ sorted_unit) {
    int e = blockIdx.x * 256 + threadIdx.x;
    int tgt = eidx[e];
    int src = eidx[NE + e];
    int pos = atomicAdd(&cursor[tgt], 1);
    sorted_eid[pos] = e;
    sorted_src[pos] = src;
    sorted_unit[pos * 3 + 0] = unitv[(size_t)e * 3 + 0];
    sorted_unit[pos * 3 + 1] = unitv[(size_t)e * 3 + 1];
    sorted_unit[pos * 3 + 2] = unitv[(size_t)e * 3 + 2];
}

// ---------------------------------------------------------------------------
// Pack Wf2 [128,384] fp32 -> bf16 (hi only) in MFMA B-fragment order.
// ---------------------------------------------------------------------------
__global__ __launch_bounds__(256) void pack_b_kernel(const float* __restrict__ Wf2,
                                                     unsigned short* __restrict__ Bp) {
    const int c = blockIdx.x;
    const int kt = threadIdx.x >> 6, lane = threadIdx.x & 63;
    const int m = lane & 15, qd = lane >> 4;
    unsigned short v[8];
    #pragma unroll
    for (int j = 0; j < 8; j++) {
        int k = kt * 32 + qd * 8 + j;
        v[j] = f2b(Wf2[(size_t)k * H3 + c * 16 + m]);
    }
    size_t base = ((size_t)(c * 4 + kt) * 64 + lane) * 8;
    *(ushort4*)&Bp[base]     = *(ushort4*)&v[0];
    *(ushort4*)&Bp[base + 4] = *(ushort4*)&v[4];
}

// ---------------------------------------------------------------------------
// Pack W [K x N] fp32 -> hi/lo bf16 MFMA B-fragments (split precision).
// dst[((ct*(K/32)+kt)*64+lane)*8+j] = W[kt*32+(lane>>4)*8+j][ct*16+(lane&15)]
// grid = (K/32) * (N/16) blocks of 64 threads; blockIdx.x = ct*(K/32)+kt.
// ---------------------------------------------------------------------------
__global__ __launch_bounds__(64) void pack_split_kernel(
    const float* __restrict__ W, int K, int N,
    unsigned short* __restrict__ hi, unsigned short* __restrict__ lo) {
    const int KT = K >> 5;
    const int kt = blockIdx.x % KT, ct = blockIdx.x / KT;
    const int lane = threadIdx.x;
    const int m = lane & 15, qd = lane >> 4;
    size_t base = ((size_t)(ct * KT + kt) * 64 + lane) * 8;
    #pragma unroll
    for (int j = 0; j < 8; j++) {
        int k = kt * 32 + qd * 8 + j;
        float v = W[(size_t)k * N + ct * 16 + m];
        unsigned short h = f2b(v);
        hi[base + j] = h;
        lo[base + j] = f2b(v - b2f(h));
    }
}

// ---------------------------------------------------------------------------
// x = silu(q @ W1 + b1) @ W2 + b2      [NN, 384]
// ---------------------------------------------------------------------------
__global__ __launch_bounds__(384) void node_x_kernel(
    const float* __restrict__ q,
    const float* __restrict__ W1, const float* __restrict__ b1,
    const float* __restrict__ W2, const float* __restrict__ b2,
    float* __restrict__ x) {
    __shared__ __align__(16) float q_s[16][H];
    __shared__ __align__(16) float h_s[16][H3];
    const int t = threadIdx.x;
    const int n0 = blockIdx.x * 16;

    for (int w = t; w < 16 * H / 4; w += 384) {
        int n = w / 32, c4 = (w % 32) * 4;
        *(float4*)&q_s[n][c4] = *(const float4*)&q[(size_t)(n0 + n) * H + c4];
    }
    __syncthreads();

    const int cg = t % 96, ng = t / 96;
    const int c0 = cg * 4;

    float4 acc[4];
    {
        float4 bv = *(const float4*)&b1[c0];
        #pragma unroll
        for (int i = 0; i < 4; i++) acc[i] = bv;
    }
    for (int k = 0; k < H; k += 4) {
        float4 w0 = *(const float4*)&W1[(size_t)(k + 0) * H3 + c0];
        float4 w1 = *(const float4*)&W1[(size_t)(k + 1) * H3 + c0];
        float4 w2 = *(const float4*)&W1[(size_t)(k + 2) * H3 + c0];
        float4 w3 = *(const float4*)&W1[(size_t)(k + 3) * H3 + c0];
        #pragma unroll
        for (int i = 0; i < 4; i++) {
            float4 qv = *(const float4*)&q_s[ng * 4 + i][k];
            FMA4(acc[i], qv.x, w0); FMA4(acc[i], qv.y, w1);
            FMA4(acc[i], qv.z, w2); FMA4(acc[i], qv.w, w3);
        }
    }
    #pragma unroll
    for (int i = 0; i < 4; i++) {
        float4 v = acc[i];
        v.x = silu_f(v.x); v.y = silu_f(v.y); v.z = silu_f(v.z); v.w = silu_f(v.w);
        *(float4*)&h_s[ng * 4 + i][c0] = v;
    }
    __syncthreads();

    {
        float4 bv = *(const float4*)&b2[c0];
        #pragma unroll
        for (int i = 0; i < 4; i++) acc[i] = bv;
    }
    for (int k = 0; k < H3; k += 4) {
        float4 w0 = *(const float4*)&W2[(size_t)(k + 0) * H3 + c0];
        float4 w1 = *(const float4*)&W2[(size_t)(k + 1) * H3 + c0];
        float4 w2 = *(const float4*)&W2[(size_t)(k + 2) * H3 + c0];
        float4 w3 = *(const float4*)&W2[(size_t)(k + 3) * H3 + c0];
        #pragma unroll
        for (int i = 0; i < 4; i++) {
            float4 hv = *(const float4*)&h_s[ng * 4 + i][k];
            FMA4(acc[i], hv.x, w0); FMA4(acc[i], hv.y, w1);
            FMA4(acc[i], hv.z, w2); FMA4(acc[i], hv.w, w3);
        }
    }
    #pragma unroll
    for (int i = 0; i < 4; i++)
        *(float4*)&x[(size_t)(n0 + ng * 4 + i) * H3 + c0] = acc[i];
}

// ---------------------------------------------------------------------------
// Filter MLP (MFMA), unchanged from R4.
// ---------------------------------------------------------------------------
__global__ __launch_bounds__(256) void filter_kernel(
    const int* __restrict__ sorted_eid, const float* __restrict__ rbf,
    const float* __restrict__ cutoff,
    const float* __restrict__ Wf1, const float* __restrict__ bf1,
    const unsigned short* __restrict__ Bp, const float* __restrict__ bf2,
    unsigned short* __restrict__ filt) {
    __shared__ __align__(16) float rbf_s[64][NRBF];
    __shared__ __align__(16) unsigned short h1_s[64][136];
    __shared__ float cut_s[64];
    __shared__ int eid_s[64];
    const int t = threadIdx.x;
    const size_t j0 = (size_t)blockIdx.x * 64;

    if (t < 64) {
        int e = sorted_eid[j0 + t];
        eid_s[t] = e;
        cut_s[t] = cutoff[e];
    }
    __syncthreads();
    for (int w = t; w < 64 * NRBF; w += 256) {
        int i = w / NRBF, k = w % NRBF;
        rbf_s[i][k] = rbf[(size_t)eid_s[i] * NRBF + k];
    }
    __syncthreads();

    {
        const int c = t & 127;
        float wr[NRBF];
        #pragma unroll
        for (int k = 0; k < NRBF; k++) wr[k] = Wf1[k * H + c];
        const float bv = bf1[c];
        for (int s = (t >> 7); s < 64; s += 2) {
            float a = bv;
            #pragma unroll
            for (int k = 0; k < NRBF; k++) a = fmaf(rbf_s[s][k], wr[k], a);
            h1_s[s][c] = f2b(silu_f(a));
        }
    }
    __syncthreads();

    {
        const int wv = t >> 6;
        const int lane = t & 63;
        const int m = lane & 15, qd = lane >> 4;
        const unsigned short* arow = &h1_s[wv * 16 + m][qd * 8];
        #pragma unroll 1
        for (int c = 0; c < 24; c++) {
            f32x4 acc = {0.f, 0.f, 0.f, 0.f};
            #pragma unroll
            for (int kt = 0; kt < 4; kt++) {
                bf16x8 af = *(const bf16x8*)(arow + kt * 32);
                bf16x8 bfr = *(const bf16x8*)(Bp + ((size_t)(c * 4 + kt) * 64 + lane) * 8);
                acc = __builtin_amdgcn_mfma_f32_16x16x32_bf16(af, bfr, acc, 0, 0, 0);
            }
            const int col = c * 16 + m;
            const float bb = bf2[col];
            #pragma unroll
            for (int r = 0; r < 4; r++) {
                int slot = wv * 16 + qd * 4 + r;
                float v = (acc[r] + bb) * cut_s[slot];
                filt[(j0 + slot) * H3 + col] = f2b(v);
            }
        }
    }
}

// ---------------------------------------------------------------------------
// Gather: unchanged from R4.
// ---------------------------------------------------------------------------
__global__ __launch_bounds__(256) void gather_kernel(
    const int* __restrict__ off, const int* __restrict__ sorted_src,
    const float* __restrict__ sorted_unit, const unsigned short* __restrict__ filt,
    const float* __restrict__ x, const float* __restrict__ mu,
    float* __restrict__ acc_q, float* __restrict__ acc_mu) {
    const int t = threadIdx.x;
    const int n = blockIdx.x * 2 + (t >> 7);
    const int cc = t & 127;
    const int j0 = off[n], j1 = off[n + 1];

    float aq = 0.f, am0 = 0.f, am1 = 0.f, am2 = 0.f;
    for (int j = j0; j < j1; ++j) {
        int src = sorted_src[j];
        float u0 = sorted_unit[j * 3 + 0];
        float u1 = sorted_unit[j * 3 + 1];
        float u2 = sorted_unit[j * 3 + 2];
        const float* xrow = x + (size_t)src * H3;
        const float* murow = mu + (size_t)src * H3;
        const unsigned short* frow = filt + (size_t)j * H3;
        float fq = b2f(frow[cc]);
        float fr = b2f(frow[cc + H]);
        float fm = b2f(frow[cc + 2 * H]);
        float xq = xrow[cc], xr = xrow[cc + H], xm = xrow[cc + 2 * H];
        float m0 = murow[cc], m1 = murow[cc + H], m2 = murow[cc + 2 * H];
        float xrs = xr * fr;
        float xms = xm * fm;
        aq  = fmaf(xq, fq, aq);
        am0 = fmaf(u0, xrs, am0); am0 = fmaf(m0, xms, am0);
        am1 = fmaf(u1, xrs, am1); am1 = fmaf(m1, xms, am1);
        am2 = fmaf(u2, xrs, am2); am2 = fmaf(m2, xms, am2);
    }
    acc_q[(size_t)n * H + cc] = aq;
    acc_mu[(size_t)n * H3 + cc] = am0;
    acc_mu[(size_t)n * H3 + H + cc] = am1;
    acc_mu[(size_t)n * H3 + 2 * H + cc] = am2;
}

// ---------------------------------------------------------------------------
// Mixing v2: split-bf16 MFMA for all three GEMMs, fp32 accumulate.
// 8 nodes per 256-thread block (4 waves), 1250 blocks. ~43 KB LDS.
// mu_cat rows padded to 4/node (32 rows) so norm/inner are lane-local.
// 3-pass split: acc = Alo*Bhi + Ahi*Blo + Ahi*Bhi  (err ~2^-17 rel).
// ---------------------------------------------------------------------------
__global__ __launch_bounds__(256) void mix_kernel(
    const float* __restrict__ q, const float* __restrict__ mu,
    const float* __restrict__ acc_q, const float* __restrict__ acc_mu,
    const unsigned short* __restrict__ Bv_hi, const unsigned short* __restrict__ Bv_lo,
    const unsigned short* __restrict__ B1_hi, const unsigned short* __restrict__ B1_lo,
    const unsigned short* __restrict__ B2_hi, const unsigned short* __restrict__ B2_lo,
    const float* __restrict__ b_mix1, const float* __restrict__ b_mix2,
    float* __restrict__ q_out, float* __restrict__ mu_out) {

    __shared__ __align__(16) unsigned short a_hi[16 * 392];   // A staging (hi)
    __shared__ __align__(16) unsigned short a_lo[16 * 392];   // A staging (lo)
    __shared__ __align__(16) float qn_s[8][128];
    __shared__ __align__(16) float norm_s[8][128];
    __shared__ __align__(16) float inner_s[8][128];
    __shared__ __align__(16) unsigned short muw_s[24][136];   // [n*3+d][c] bf16

    const int t = threadIdx.x;
    const int wv = t >> 6, lane = t & 63;
    const int m = lane & 15, qd = lane >> 4;      // qd in 0..3
    const int n0 = blockIdx.x * 8;

    // ---- phase 0: qn_s = q + acc_q (8x128); stage mu_cat A (32 rows x K=128, stride 136)
    {
        float4 a = *(const float4*)&q[(size_t)n0 * H + t * 4];
        float4 b = *(const float4*)&acc_q[(size_t)n0 * H + t * 4];
        a.x += b.x; a.y += b.y; a.z += b.z; a.w += b.w;
        ((float4*)qn_s)[t] = a;
    }
    for (int i = t; i < 32 * 32; i += 256) {
        int r = i >> 5, c4 = (i & 31) * 4;
        int n = r >> 2, d = r & 3;
        float4 v;
        if (d < 3) {
            float4 a = *(const float4*)&mu[((size_t)(n0 + n) * 3 + d) * H + c4];
            float4 b = *(const float4*)&acc_mu[(size_t)(n0 + n) * H3 + d * H + c4];
            v.x = a.x + b.x; v.y = a.y + b.y; v.z = a.z + b.z; v.w = a.w + b.w;
        } else { v.x = v.y = v.z = v.w = 0.f; }
        ushort4 h, l;
        h.x = f2b(v.x); l.x = f2b(v.x - b2f(h.x));
        h.y = f2b(v.y); l.y = f2b(v.y - b2f(h.y));
        h.z = f2b(v.z); l.z = f2b(v.z - b2f(h.z));
        h.w = f2b(v.w); l.w = f2b(v.w - b2f(h.w));
        *(ushort4*)&a_hi[r * 136 + c4] = h;
        *(ushort4*)&a_lo[r * 136 + c4] = l;
    }
    __syncthreads();

    // ---- mu_cat GEMM: 32 rows x 256 cols, K=128 (KT=4)
    // wave = (rt = wv>>1 row-tile, pp = wv&1 col parity); lane holds node rt*4+qd.
    {
        const int rt = wv >> 1, pp = wv & 1;
        const unsigned short* arh = &a_hi[(rt * 16 + m) * 136];
        const unsigned short* arl = &a_lo[(rt * 16 + m) * 136];
        const int node = rt * 4 + qd;
        f32x4 muv[4];
        #pragma unroll
        for (int jj = 0; jj < 4; jj++) {
            int ct = 2 * jj + pp;
            f32x4 acc = {0.f, 0.f, 0.f, 0.f};
            #pragma unroll
            for (int kt = 0; kt < 4; kt++) {
                bf16x8 ah = *(const bf16x8*)(arh + kt * 32 + qd * 8);
                bf16x8 al = *(const bf16x8*)(arl + kt * 32 + qd * 8);
                size_t bo = ((size_t)(ct * 4 + kt) * 64 + lane) * 8;
                bf16x8 bh = *(const bf16x8*)(Bv_hi + bo);
                bf16x8 bl = *(const bf16x8*)(Bv_lo + bo);
                acc = __builtin_amdgcn_mfma_f32_16x16x32_bf16(al, bh, acc, 0, 0, 0);
                acc = __builtin_amdgcn_mfma_f32_16x16x32_bf16(ah, bl, acc, 0, 0, 0);
                acc = __builtin_amdgcn_mfma_f32_16x16x32_bf16(ah, bh, acc, 0, 0, 0);
            }
            muv[jj] = acc;
        }
        #pragma unroll
        for (int jj = 0; jj < 4; jj++) {
            int ct = 8 + 2 * jj + pp;
            f32x4 acc = {0.f, 0.f, 0.f, 0.f};
            #pragma unroll
            for (int kt = 0; kt < 4; kt++) {
                bf16x8 ah = *(const bf16x8*)(arh + kt * 32 + qd * 8);
                bf16x8 al = *(const bf16x8*)(arl + kt * 32 + qd * 8);
                size_t bo = ((size_t)(ct * 4 + kt) * 64 + lane) * 8;
                bf16x8 bh = *(const bf16x8*)(Bv_hi + bo);
                bf16x8 bl = *(const bf16x8*)(Bv_lo + bo);
                acc = __builtin_amdgcn_mfma_f32_16x16x32_bf16(al, bh, acc, 0, 0, 0);
                acc = __builtin_amdgcn_mfma_f32_16x16x32_bf16(ah, bl, acc, 0, 0, 0);
                acc = __builtin_amdgcn_mfma_f32_16x16x32_bf16(ah, bh, acc, 0, 0, 0);
            }
            int cw = (2 * jj + pp) * 16 + m;      // same channel as muv[jj]
            float v0 = muv[jj][0], v1 = muv[jj][1], v2 = muv[jj][2];
            float w0 = acc[0], w1 = acc[1], w2 = acc[2];
            norm_s[node][cw]  = sqrtf(v0 * v0 + v1 * v1 + v2 * v2 + 1e-8f);
            inner_s[node][cw] = v0 * w0 + v1 * w1 + v2 * w2;
            muw_s[node * 3 + 0][cw] = f2b(w0);
            muw_s[node * 3 + 1][cw] = f2b(w1);
            muw_s[node * 3 + 2][cw] = f2b(w2);
        }
    }
    __syncthreads();

    // ---- stage mix1 A: scalar_input 16 rows (8 valid) x K=256, stride 264
    for (int i = t; i < 16 * 64; i += 256) {
        int r = i >> 6, c4 = (i & 63) * 4;
        float4 v;
        if (r < 8) v = (c4 < 128) ? *(const float4*)&qn_s[r][c4]
                                  : *(const float4*)&norm_s[r][c4 - 128];
        else { v.x = v.y = v.z = v.w = 0.f; }
        ushort4 h, l;
        h.x = f2b(v.x); l.x = f2b(v.x - b2f(h.x));
        h.y = f2b(v.y); l.y = f2b(v.y - b2f(h.y));
        h.z = f2b(v.z); l.z = f2b(v.z - b2f(h.z));
        h.w = f2b(v.w); l.w = f2b(v.w - b2f(h.w));
        *(ushort4*)&a_hi[r * 264 + c4] = h;
        *(ushort4*)&a_lo[r * 264 + c4] = l;
    }
    __syncthreads();

    // ---- mix1 GEMM: 16 rows x 384 cols, K=256 (KT=8). wave tiles ct = jj*4+wv.
    f32x4 hreg[6];
    {
        const unsigned short* arh = &a_hi[m * 264];
        const unsigned short* arl = &a_lo[m * 264];
        #pragma unroll
        for (int jj = 0; jj < 6; jj++) {
            int ct = jj * 4 + wv;
            f32x4 acc = {0.f, 0.f, 0.f, 0.f};
            #pragma unroll
            for (int kt = 0; kt < 8; kt++) {
                bf16x8 ah = *(const bf16x8*)(arh + kt * 32 + qd * 8);
                bf16x8 al = *(const bf16x8*)(arl + kt * 32 + qd * 8);
                size_t bo = ((size_t)(ct * 8 + kt) * 64 + lane) * 8;
                bf16x8 bh = *(const bf16x8*)(B1_hi + bo);
                bf16x8 bl = *(const bf16x8*)(B1_lo + bo);
                acc = __builtin_amdgcn_mfma_f32_16x16x32_bf16(al, bh, acc, 0, 0, 0);
                acc = __builtin_amdgcn_mfma_f32_16x16x32_bf16(ah, bl, acc, 0, 0, 0);
                acc = __builtin_amdgcn_mfma_f32_16x16x32_bf16(ah, bh, acc, 0, 0, 0);
            }
            float bb = b_mix1[ct * 16 + m];
            #pragma unroll
            for (int r = 0; r < 4; r++) acc[r] = silu_f(acc[r] + bb);
            hreg[jj] = acc;
        }
    }
    __syncthreads();

    // ---- stage mix2 A: h 16 rows (8 valid) x K=384, stride 392
    for (int i = t; i < 8 * 96; i += 256) {          // zero rows 8..15
        int r = 8 + i / 96, c4 = (i % 96) * 4;
        ushort4 z; z.x = z.y = z.z = z.w = 0;
        *(ushort4*)&a_hi[r * 392 + c4] = z;
        *(ushort4*)&a_lo[r * 392 + c4] = z;
    }
    if (qd < 2) {
        #pragma unroll
        for (int jj = 0; jj < 6; jj++) {
            int c = (jj * 4 + wv) * 16 + m;
            #pragma unroll
            for (int r = 0; r < 4; r++) {
                int nd = qd * 4 + r;                  // node 0..7
                float v = hreg[jj][r];
                unsigned short h = f2b(v);
                a_hi[nd * 392 + c] = h;
                a_lo[nd * 392 + c] = f2b(v - b2f(h));
            }
        }
    }
    __syncthreads();

    // ---- mix2 GEMM: 16 rows x 384 cols, K=384 (KT=12) + fused epilogue
    {
        const unsigned short* arh = &a_hi[m * 392];
        const unsigned short* arl = &a_lo[m * 392];
        f32x4 dreg[6];
        #pragma unroll
        for (int jj = 0; jj < 6; jj++) {
            int ct = jj * 4 + wv;
            f32x4 acc = {0.f, 0.f, 0.f, 0.f};
            #pragma unroll
            for (int kt = 0; kt < 12; kt++) {
                bf16x8 ah = *(const bf16x8*)(arh + kt * 32 + qd * 8);
                bf16x8 al = *(const bf16x8*)(arl + kt * 32 + qd * 8);
                size_t bo = ((size_t)(ct * 12 + kt) * 64 + lane) * 8;
                bf16x8 bh = *(const bf16x8*)(B2_hi + bo);
                bf16x8 bl = *(const bf16x8*)(B2_lo + bo);
                acc = __builtin_amdgcn_mfma_f32_16x16x32_bf16(al, bh, acc, 0, 0, 0);
                acc = __builtin_amdgcn_mfma_f32_16x16x32_bf16(ah, bl, acc, 0, 0, 0);
                acc = __builtin_amdgcn_mfma_f32_16x16x32_bf16(ah, bh, acc, 0, 0, 0);
            }
            float bb = b_mix2[ct * 16 + m];
            #pragma unroll
            for (int r = 0; r < 4; r++) acc[r] += bb;
            dreg[jj] = acc;
        }

        if (qd < 2) {
            // q_out: dq tiles jj=0,1 (ct<8) pair with dqmu tiles jj+4 (ct+16)
            #pragma unroll
            for (int jj = 0; jj < 2; jj++) {
                int c = (jj * 4 + wv) * 16 + m;
                #pragma unroll
                for (int r = 0; r < 4; r++) {
                    int nd = qd * 4 + r;
                    float val = qn_s[nd][c] + dreg[jj][r]
                              + dreg[jj + 4][r] * inner_s[nd][c];
                    q_out[(size_t)(n0 + nd) * H + c] = val;
                }
            }
            // mu_out: dms tiles jj=2,3 (ct in [8,16)); cw = ct*16+m-128
            #pragma unroll
            for (int jj = 2; jj < 4; jj++) {
                int cw = (jj * 4 + wv) * 16 + m - 128;
                #pragma unroll
                for (int r = 0; r < 4; r++) {
                    int nd = qd * 4 + r;
                    float dms = dreg[jj][r];
                    #pragma unroll
                    for (int d = 0; d < 3; d++) {
                        size_t gi = ((size_t)(n0 + nd) * 3 + d) * H + cw;
                        float mun = mu[gi] + acc_mu[(size_t)(n0 + nd) * H3 + d * H + cw];
                        mu_out[gi] = mun + b2f(muw_s[nd * 3 + d][cw]) * dms;
                    }
                }
            }
        }
    }
}

extern "C" void kernel_launch(void* const* d_in, const int* in_sizes, int n_in,
                              void* d_out, int out_size, void* d_ws, size_t ws_size,
                              hipStream_t stream) {
    const float* q        = (const float*)d_in[0];
    const float* mu       = (const float*)d_in[1];
    const int*   eidx     = (const int*)d_in[2];
    const float* rbf      = (const float*)d_in[3];
    const float* unitv    = (const float*)d_in[4];
    const float* cutoff   = (const float*)d_in[5];
    const float* W_inter1 = (const float*)d_in[6];
    const float* b_inter1 = (const float*)d_in[7];
    const float* W_inter2 = (const float*)d_in[8];
    const float* b_inter2 = (const float*)d_in[9];
    const float* W_filt1  = (const float*)d_in[10];
    const float* b_filt1  = (const float*)d_in[11];
    const float* W_filt2  = (const float*)d_in[12];
    const float* b_filt2  = (const float*)d_in[13];
    const float* W_vec    = (const float*)d_in[14];
    const float* W_mix1   = (const float*)d_in[15];
    const float* b_mix1   = (const float*)d_in[16];
    const float* W_mix2   = (const float*)d_in[17];
    const float* b_mix2   = (const float*)d_in[18];

    // workspace layout
    char* p = (char*)d_ws;
    float* x           = (float*)p;            p += (size_t)NN * H3 * 4;
    float* acc_q       = (float*)p;            p += (size_t)NN * H * 4;
    float* acc_mu      = (float*)p;            p += (size_t)NN * H3 * 4;
    float* sorted_unit = (float*)p;            p += (size_t)NE * 3 * 4;
    int*   counts      = (int*)p;              p += (size_t)NN * 4;
    int*   off         = (int*)p;              p += (size_t)(NN + 1) * 4;
    p = (char*)(((size_t)p + 255) & ~(size_t)255);
    int*   cursor      = (int*)p;              p += (size_t)NN * 4;
    p = (char*)(((size_t)p + 255) & ~(size_t)255);
    int*   sorted_eid  = (int*)p;              p += (size_t)NE * 4;
    int*   sorted_src  = (int*)p;              p += (size_t)NE * 4;
    p = (char*)(((size_t)p + 255) & ~(size_t)255);
    unsigned short* Bp    = (unsigned short*)p; p += (size_t)H * H3 * 2;        // 96 KB
    unsigned short* Bv_hi = (unsigned short*)p; p += (size_t)H * H2 * 2;
    unsigned short* Bv_lo = (unsigned short*)p; p += (size_t)H * H2 * 2;
    unsigned short* B1_hi = (unsigned short*)p; p += (size_t)H2 * H3 * 2;
    unsigned short* B1_lo = (unsigned short*)p; p += (size_t)H2 * H3 * 2;
    unsigned short* B2_hi = (unsigned short*)p; p += (size_t)H3 * H3 * 2;
    unsigned short* B2_lo = (unsigned short*)p; p += (size_t)H3 * H3 * 2;
    p = (char*)(((size_t)p + 255) & ~(size_t)255);
    unsigned short* filt = (unsigned short*)p;  p += (size_t)NE * H3 * 2;

    float* q_out  = (float*)d_out;
    float* mu_out = q_out + (size_t)NN * H;

    hipMemsetAsync(counts, 0, (size_t)NN * 4, stream);

    hist_kernel  <<<NE / 256, 256, 0, stream>>>(eidx, counts);
    pack_b_kernel<<<24, 256, 0, stream>>>(W_filt2, Bp);
    pack_split_kernel<<<(H  / 32) * (H2 / 16), 64, 0, stream>>>(W_vec,  H,  H2, Bv_hi, Bv_lo);
    pack_split_kernel<<<(H2 / 32) * (H3 / 16), 64, 0, stream>>>(W_mix1, H2, H3, B1_hi, B1_lo);
    pack_split_kernel<<<(H3 / 32) * (H3 / 16), 64, 0, stream>>>(W_mix2, H3, H3, B2_hi, B2_lo);
    scan_kernel  <<<1, 1024, 0, stream>>>(counts, off, cursor);
    place_kernel <<<NE / 256, 256, 0, stream>>>(eidx, unitv, cursor,
                                                sorted_eid, sorted_src, sorted_unit);
    node_x_kernel<<<NN / 16, 384, 0, stream>>>(q, W_inter1, b_inter1, W_inter2, b_inter2, x);
    filter_kernel<<<NE / 64, 256, 0, stream>>>(sorted_eid, rbf, cutoff,
                                               W_filt1, b_filt1, Bp, b_filt2, filt);
    gather_kernel<<<NN / 2, 256, 0, stream>>>(off, sorted_src, sorted_unit, filt,
                                              x, mu, acc_q, acc_mu);
    mix_kernel   <<<NN / 8, 256, 0, stream>>>(q, mu, acc_q, acc_mu,
                                              Bv_hi, Bv_lo, B1_hi, B1_lo, B2_hi, B2_lo,
                                              b_mix1, b_mix2, q_out, mu_out);
}

// Round 6
// 605.131 us; speedup vs baseline: 3.5610x; 1.0463x over previous
//
#include <hip/hip_runtime.h>

#define NN 10000
#define NE 256000
#define H 128
#define H2 256
#define H3 384
#define NRBF 20

typedef __attribute__((ext_vector_type(8))) short bf16x8;
typedef __attribute__((ext_vector_type(4))) float f32x4;

__device__ __forceinline__ void FMA4(float4& a, float s, const float4& v) {
    a.x = fmaf(s, v.x, a.x); a.y = fmaf(s, v.y, a.y);
    a.z = fmaf(s, v.z, a.z); a.w = fmaf(s, v.w, a.w);
}

__device__ __forceinline__ float silu_f(float v) { return v / (1.f + __expf(-v)); }

// fp32 -> bf16 bits (RNE)
__device__ __forceinline__ unsigned short f2b(float f) {
    union { float f; unsigned u; } x; x.f = f;
    unsigned r = (x.u + 0x7FFFu + ((x.u >> 16) & 1u)) >> 16;
    return (unsigned short)r;
}
__device__ __forceinline__ float b2f(unsigned short b) {
    union { unsigned u; float f; } x; x.u = ((unsigned)b) << 16;
    return x.f;
}

// ---------------------------------------------------------------------------
// CSR build: histogram of targets
// ---------------------------------------------------------------------------
__global__ __launch_bounds__(256) void hist_kernel(const int* __restrict__ eidx,
                                                   int* __restrict__ counts) {
    int e = blockIdx.x * 256 + threadIdx.x;
    atomicAdd(&counts[eidx[e]], 1);
}

// Single-block exclusive scan over NN counts -> off[NN+1], cursor copy.
__global__ __launch_bounds__(1024) void scan_kernel(const int* __restrict__ counts,
                                                    int* __restrict__ off,
                                                    int* __restrict__ cursor) {
    __shared__ int sums[1024];
    const int t = threadIdx.x;
    const int base = t * 10;
    int local[10];
    int s = 0;
    #pragma unroll
    for (int i = 0; i < 10; i++) {
        int idx = base + i;
        int v = (idx < NN) ? counts[idx] : 0;
        local[i] = s; s += v;
    }
    sums[t] = s;
    __syncthreads();
    for (int d = 1; d < 1024; d <<= 1) {
        int v = (t >= d) ? sums[t - d] : 0;
        __syncthreads();
        sums[t] += v;
        __syncthreads();
    }
    int prefix = (t > 0) ? sums[t - 1] : 0;
    #pragma unroll
    for (int i = 0; i < 10; i++) {
        int idx = base + i;
        if (idx < NN) { off[idx] = prefix + local[i]; cursor[idx] = prefix + local[i]; }
    }
    if (t == 1023) off[NN] = sums[1023];
}

// Place edges into target-sorted order; copy src + unit vector alongside.
__global__ __launch_bounds__(256) void place_kernel(
    const int* __restrict__ eidx, const float* __restrict__ unitv,
    int* __restrict__ cursor, int* __restrict__ sorted_eid,
    int* __restrict__ sorted_src, float* __restrict__ sorted_unit) {
    int e = blockIdx.x * 256 + threadIdx.x;
    int tgt = eidx[e];
    int src = eidx[NE + e];
    int pos = atomicAdd(&cursor[tgt], 1);
    sorted_eid[pos] = e;
    sorted_src[pos] = src;
    sorted_unit[pos * 3 + 0] = unitv[(size_t)e * 3 + 0];
    sorted_unit[pos * 3 + 1] = unitv[(size_t)e * 3 + 1];
    sorted_unit[pos * 3 + 2] = unitv[(size_t)e * 3 + 2];
}

// ---------------------------------------------------------------------------
// Pack Wf2 [128,384] fp32 -> bf16 (hi only) in MFMA B-fragment order.
// ---------------------------------------------------------------------------
__global__ __launch_bounds__(256) void pack_b_kernel(const float* __restrict__ Wf2,
                                                     unsigned short* __restrict__ Bp) {
    const int c = blockIdx.x;
    const int kt = threadIdx.x >> 6, lane = threadIdx.x & 63;
    const int m = lane & 15, qd = lane >> 4;
    unsigned short v[8];
    #pragma unroll
    for (int j = 0; j < 8; j++) {
        int k = kt * 32 + qd * 8 + j;
        v[j] = f2b(Wf2[(size_t)k * H3 + c * 16 + m]);
    }
    size_t base = ((size_t)(c * 4 + kt) * 64 + lane) * 8;
    *(ushort4*)&Bp[base]     = *(ushort4*)&v[0];
    *(ushort4*)&Bp[base + 4] = *(ushort4*)&v[4];
}

// ---------------------------------------------------------------------------
// Pack W [K x N] fp32 -> hi/lo bf16 MFMA B-fragments (split precision).
// ---------------------------------------------------------------------------
__global__ __launch_bounds__(64) void pack_split_kernel(
    const float* __restrict__ W, int K, int N,
    unsigned short* __restrict__ hi, unsigned short* __restrict__ lo) {
    const int KT = K >> 5;
    const int kt = blockIdx.x % KT, ct = blockIdx.x / KT;
    const int lane = threadIdx.x;
    const int m = lane & 15, qd = lane >> 4;
    size_t base = ((size_t)(ct * KT + kt) * 64 + lane) * 8;
    #pragma unroll
    for (int j = 0; j < 8; j++) {
        int k = kt * 32 + qd * 8 + j;
        float v = W[(size_t)k * N + ct * 16 + m];
        unsigned short h = f2b(v);
        hi[base + j] = h;
        lo[base + j] = f2b(v - b2f(h));
    }
}

// mu fp32 -> bf16 copy
__global__ __launch_bounds__(256) void mu2b_kernel(const float* __restrict__ mu,
                                                   unsigned short* __restrict__ mu_b) {
    int i = blockIdx.x * 256 + threadIdx.x;        // over NN*H3/4
    float4 v = ((const float4*)mu)[i];
    ushort4 o;
    o.x = f2b(v.x); o.y = f2b(v.y); o.z = f2b(v.z); o.w = f2b(v.w);
    ((ushort4*)mu_b)[i] = o;
}

// ---------------------------------------------------------------------------
// x = silu(q @ W1 + b1) @ W2 + b2      [NN, 384] -> stored as bf16
// ---------------------------------------------------------------------------
__global__ __launch_bounds__(384) void node_x_kernel(
    const float* __restrict__ q,
    const float* __restrict__ W1, const float* __restrict__ b1,
    const float* __restrict__ W2, const float* __restrict__ b2,
    unsigned short* __restrict__ x_b) {
    __shared__ __align__(16) float q_s[16][H];
    __shared__ __align__(16) float h_s[16][H3];
    const int t = threadIdx.x;
    const int n0 = blockIdx.x * 16;

    for (int w = t; w < 16 * H / 4; w += 384) {
        int n = w / 32, c4 = (w % 32) * 4;
        *(float4*)&q_s[n][c4] = *(const float4*)&q[(size_t)(n0 + n) * H + c4];
    }
    __syncthreads();

    const int cg = t % 96, ng = t / 96;
    const int c0 = cg * 4;

    float4 acc[4];
    {
        float4 bv = *(const float4*)&b1[c0];
        #pragma unroll
        for (int i = 0; i < 4; i++) acc[i] = bv;
    }
    for (int k = 0; k < H; k += 4) {
        float4 w0 = *(const float4*)&W1[(size_t)(k + 0) * H3 + c0];
        float4 w1 = *(const float4*)&W1[(size_t)(k + 1) * H3 + c0];
        float4 w2 = *(const float4*)&W1[(size_t)(k + 2) * H3 + c0];
        float4 w3 = *(const float4*)&W1[(size_t)(k + 3) * H3 + c0];
        #pragma unroll
        for (int i = 0; i < 4; i++) {
            float4 qv = *(const float4*)&q_s[ng * 4 + i][k];
            FMA4(acc[i], qv.x, w0); FMA4(acc[i], qv.y, w1);
            FMA4(acc[i], qv.z, w2); FMA4(acc[i], qv.w, w3);
        }
    }
    #pragma unroll
    for (int i = 0; i < 4; i++) {
        float4 v = acc[i];
        v.x = silu_f(v.x); v.y = silu_f(v.y); v.z = silu_f(v.z); v.w = silu_f(v.w);
        *(float4*)&h_s[ng * 4 + i][c0] = v;
    }
    __syncthreads();

    {
        float4 bv = *(const float4*)&b2[c0];
        #pragma unroll
        for (int i = 0; i < 4; i++) acc[i] = bv;
    }
    for (int k = 0; k < H3; k += 4) {
        float4 w0 = *(const float4*)&W2[(size_t)(k + 0) * H3 + c0];
        float4 w1 = *(const float4*)&W2[(size_t)(k + 1) * H3 + c0];
        float4 w2 = *(const float4*)&W2[(size_t)(k + 2) * H3 + c0];
        float4 w3 = *(const float4*)&W2[(size_t)(k + 3) * H3 + c0];
        #pragma unroll
        for (int i = 0; i < 4; i++) {
            float4 hv = *(const float4*)&h_s[ng * 4 + i][k];
            FMA4(acc[i], hv.x, w0); FMA4(acc[i], hv.y, w1);
            FMA4(acc[i], hv.z, w2); FMA4(acc[i], hv.w, w3);
        }
    }
    #pragma unroll
    for (int i = 0; i < 4; i++) {
        ushort4 o;
        o.x = f2b(acc[i].x); o.y = f2b(acc[i].y);
        o.z = f2b(acc[i].z); o.w = f2b(acc[i].w);
        *(ushort4*)&x_b[(size_t)(n0 + ng * 4 + i) * H3 + c0] = o;
    }
}

// ---------------------------------------------------------------------------
// Fused edge kernel: one block per target node. Per 32-edge chunk:
//   layer1 VALU -> h1 (LDS bf16); layer2 MFMA (packed Bp) -> filt (LDS bf16);
//   message multiply-accumulate (bf16 x/mu tables) into registers.
// Direct store of acc_q/acc_mu: no atomics, no filt HBM round-trip.
// ---------------------------------------------------------------------------
__global__ __launch_bounds__(256) void edge_fused_kernel(
    const int* __restrict__ off, const int* __restrict__ sorted_eid,
    const int* __restrict__ sorted_src, const float* __restrict__ sorted_unit,
    const float* __restrict__ rbf, const float* __restrict__ cutoff,
    const float* __restrict__ Wf1, const float* __restrict__ bf1,
    const unsigned short* __restrict__ Bp, const float* __restrict__ bf2,
    const unsigned short* __restrict__ x_b, const unsigned short* __restrict__ mu_b,
    float* __restrict__ acc_q, float* __restrict__ acc_mu) {
    __shared__ __align__(16) float rbf_s[32][NRBF];
    __shared__ __align__(16) unsigned short h1_s[32][136];
    __shared__ __align__(16) unsigned short filt_s[32][392];
    __shared__ float red_s[8 * 128];
    __shared__ int src_s[32];
    __shared__ float cut_s[32];
    __shared__ float unit_s[32][3];

    const int t = threadIdx.x;
    const int n = blockIdx.x;
    const int j0 = off[n], j1 = off[n + 1];

    const int wv = t >> 6, lane = t & 63;
    const int m = lane & 15, qd = lane >> 4;
    const int cc = t & 127, hh = t >> 7;

    // Wf1 column in registers (reused across chunks)
    float wr[NRBF];
    {
        #pragma unroll
        for (int k = 0; k < NRBF; k++) wr[k] = Wf1[k * H + cc];
    }
    const float b1v = bf1[cc];

    float aq = 0.f, am0 = 0.f, am1 = 0.f, am2 = 0.f;

    for (int c0 = j0; c0 < j1; c0 += 32) {
        const int cnt = min(32, j1 - c0);
        __syncthreads();   // protect prev chunk's filt_s before overwrite

        // meta
        if (t < cnt) {
            int e = sorted_eid[c0 + t];
            cut_s[t] = cutoff[e];
            src_s[t] = sorted_src[c0 + t];
            unit_s[t][0] = sorted_unit[(c0 + t) * 3 + 0];
            unit_s[t][1] = sorted_unit[(c0 + t) * 3 + 1];
            unit_s[t][2] = sorted_unit[(c0 + t) * 3 + 2];
        }
        // rbf (re-reads sorted_eid; L1-cached)
        for (int i = t; i < cnt * NRBF; i += 256) {
            int s = i / NRBF, k = i % NRBF;
            int e = sorted_eid[c0 + s];
            rbf_s[s][k] = rbf[(size_t)e * NRBF + k];
        }
        __syncthreads();

        // layer 1: thread owns col cc for half of slots
        for (int s = hh; s < cnt; s += 2) {
            float a = b1v;
            #pragma unroll
            for (int k = 0; k < NRBF; k++) a = fmaf(rbf_s[s][k], wr[k], a);
            h1_s[s][cc] = f2b(silu_f(a));
        }
        __syncthreads();

        // layer 2 MFMA: wave = (slot-tile st, col-half ch)
        {
            const int st = wv >> 1, ch = wv & 1;
            const unsigned short* arow = &h1_s[st * 16 + m][qd * 8];
            #pragma unroll 1
            for (int j = 0; j < 12; j++) {
                const int ct = ch * 12 + j;
                f32x4 acc = {0.f, 0.f, 0.f, 0.f};
                #pragma unroll
                for (int kt = 0; kt < 4; kt++) {
                    bf16x8 af = *(const bf16x8*)(arow + kt * 32);
                    bf16x8 bfr = *(const bf16x8*)(Bp + ((size_t)(ct * 4 + kt) * 64 + lane) * 8);
                    acc = __builtin_amdgcn_mfma_f32_16x16x32_bf16(af, bfr, acc, 0, 0, 0);
                }
                const int col = ct * 16 + m;
                const float bb = bf2[col];
                #pragma unroll
                for (int r = 0; r < 4; r++) {
                    int slot = st * 16 + qd * 4 + r;
                    filt_s[slot][col] = f2b((acc[r] + bb) * cut_s[slot]);
                }
            }
        }
        __syncthreads();

        // message accumulate: half hh handles slots [hh*16, min(hh*16+16, cnt))
        {
            const int s1 = min(hh * 16 + 16, cnt);
            for (int s = hh * 16; s < s1; ++s) {
                const int src = src_s[s];
                const float u0 = unit_s[s][0], u1 = unit_s[s][1], u2 = unit_s[s][2];
                const unsigned short* xrow = x_b + (size_t)src * H3;
                const unsigned short* murow = mu_b + (size_t)src * H3;
                float fq = b2f(filt_s[s][cc]);
                float fr = b2f(filt_s[s][cc + H]);
                float fm = b2f(filt_s[s][cc + 2 * H]);
                float xq = b2f(xrow[cc]), xr = b2f(xrow[cc + H]), xm = b2f(xrow[cc + 2 * H]);
                float m0 = b2f(murow[cc]), m1 = b2f(murow[cc + H]), m2 = b2f(murow[cc + 2 * H]);
                float xrs = xr * fr;
                float xms = xm * fm;
                aq  = fmaf(xq, fq, aq);
                am0 = fmaf(u0, xrs, am0); am0 = fmaf(m0, xms, am0);
                am1 = fmaf(u1, xrs, am1); am1 = fmaf(m1, xms, am1);
                am2 = fmaf(u2, xrs, am2); am2 = fmaf(m2, xms, am2);
            }
        }
    }
    __syncthreads();

    // combine halves and store
    red_s[(hh * 4 + 0) * 128 + cc] = aq;
    red_s[(hh * 4 + 1) * 128 + cc] = am0;
    red_s[(hh * 4 + 2) * 128 + cc] = am1;
    red_s[(hh * 4 + 3) * 128 + cc] = am2;
    __syncthreads();
    if (t < 128) {
        float q0 = red_s[0 * 128 + t] + red_s[4 * 128 + t];
        float v0 = red_s[1 * 128 + t] + red_s[5 * 128 + t];
        float v1 = red_s[2 * 128 + t] + red_s[6 * 128 + t];
        float v2 = red_s[3 * 128 + t] + red_s[7 * 128 + t];
        acc_q[(size_t)n * H + t] = q0;
        acc_mu[(size_t)n * H3 + t] = v0;
        acc_mu[(size_t)n * H3 + H + t] = v1;
        acc_mu[(size_t)n * H3 + 2 * H + t] = v2;
    }
}

// ---------------------------------------------------------------------------
// Mixing: split-bf16 MFMA (unchanged from R5).
// ---------------------------------------------------------------------------
__global__ __launch_bounds__(256) void mix_kernel(
    const float* __restrict__ q, const float* __restrict__ mu,
    const float* __restrict__ acc_q, const float* __restrict__ acc_mu,
    const unsigned short* __restrict__ Bv_hi, const unsigned short* __restrict__ Bv_lo,
    const unsigned short* __restrict__ B1_hi, const unsigned short* __restrict__ B1_lo,
    const unsigned short* __restrict__ B2_hi, const unsigned short* __restrict__ B2_lo,
    const float* __restrict__ b_mix1, const float* __restrict__ b_mix2,
    float* __restrict__ q_out, float* __restrict__ mu_out) {

    __shared__ __align__(16) unsigned short a_hi[16 * 392];
    __shared__ __align__(16) unsigned short a_lo[16 * 392];
    __shared__ __align__(16) float qn_s[8][128];
    __shared__ __align__(16) float norm_s[8][128];
    __shared__ __align__(16) float inner_s[8][128];
    __shared__ __align__(16) unsigned short muw_s[24][136];

    const int t = threadIdx.x;
    const int wv = t >> 6, lane = t & 63;
    const int m = lane & 15, qd = lane >> 4;
    const int n0 = blockIdx.x * 8;

    {
        float4 a = *(const float4*)&q[(size_t)n0 * H + t * 4];
        float4 b = *(const float4*)&acc_q[(size_t)n0 * H + t * 4];
        a.x += b.x; a.y += b.y; a.z += b.z; a.w += b.w;
        ((float4*)qn_s)[t] = a;
    }
    for (int i = t; i < 32 * 32; i += 256) {
        int r = i >> 5, c4 = (i & 31) * 4;
        int n = r >> 2, d = r & 3;
        float4 v;
        if (d < 3) {
            float4 a = *(const float4*)&mu[((size_t)(n0 + n) * 3 + d) * H + c4];
            float4 b = *(const float4*)&acc_mu[(size_t)(n0 + n) * H3 + d * H + c4];
            v.x = a.x + b.x; v.y = a.y + b.y; v.z = a.z + b.z; v.w = a.w + b.w;
        } else { v.x = v.y = v.z = v.w = 0.f; }
        ushort4 h, l;
        h.x = f2b(v.x); l.x = f2b(v.x - b2f(h.x));
        h.y = f2b(v.y); l.y = f2b(v.y - b2f(h.y));
        h.z = f2b(v.z); l.z = f2b(v.z - b2f(h.z));
        h.w = f2b(v.w); l.w = f2b(v.w - b2f(h.w));
        *(ushort4*)&a_hi[r * 136 + c4] = h;
        *(ushort4*)&a_lo[r * 136 + c4] = l;
    }
    __syncthreads();

    {
        const int rt = wv >> 1, pp = wv & 1;
        const unsigned short* arh = &a_hi[(rt * 16 + m) * 136];
        const unsigned short* arl = &a_lo[(rt * 16 + m) * 136];
        const int node = rt * 4 + qd;
        f32x4 muv[4];
        #pragma unroll
        for (int jj = 0; jj < 4; jj++) {
            int ct = 2 * jj + pp;
            f32x4 acc = {0.f, 0.f, 0.f, 0.f};
            #pragma unroll
            for (int kt = 0; kt < 4; kt++) {
                bf16x8 ah = *(const bf16x8*)(arh + kt * 32 + qd * 8);
                bf16x8 al = *(const bf16x8*)(arl + kt * 32 + qd * 8);
                size_t bo = ((size_t)(ct * 4 + kt) * 64 + lane) * 8;
                bf16x8 bh = *(const bf16x8*)(Bv_hi + bo);
                bf16x8 bl = *(const bf16x8*)(Bv_lo + bo);
                acc = __builtin_amdgcn_mfma_f32_16x16x32_bf16(al, bh, acc, 0, 0, 0);
                acc = __builtin_amdgcn_mfma_f32_16x16x32_bf16(ah, bl, acc, 0, 0, 0);
                acc = __builtin_amdgcn_mfma_f32_16x16x32_bf16(ah, bh, acc, 0, 0, 0);
            }
            muv[jj] = acc;
        }
        #pragma unroll
        for (int jj = 0; jj < 4; jj++) {
            int ct = 8 + 2 * jj + pp;
            f32x4 acc = {0.f, 0.f, 0.f, 0.f};
            #pragma unroll
            for (int kt = 0; kt < 4; kt++) {
                bf16x8 ah = *(const bf16x8*)(arh + kt * 32 + qd * 8);
                bf16x8 al = *(const bf16x8*)(arl + kt * 32 + qd * 8);
                size_t bo = ((size_t)(ct * 4 + kt) * 64 + lane) * 8;
                bf16x8 bh = *(const bf16x8*)(Bv_hi + bo);
                bf16x8 bl = *(const bf16x8*)(Bv_lo + bo);
                acc = __builtin_amdgcn_mfma_f32_16x16x32_bf16(al, bh, acc, 0, 0, 0);
                acc = __builtin_amdgcn_mfma_f32_16x16x32_bf16(ah, bl, acc, 0, 0, 0);
                acc = __builtin_amdgcn_mfma_f32_16x16x32_bf16(ah, bh, acc, 0, 0, 0);
            }
            int cw = (2 * jj + pp) * 16 + m;
            float v0 = muv[jj][0], v1 = muv[jj][1], v2 = muv[jj][2];
            float w0 = acc[0], w1 = acc[1], w2 = acc[2];
            norm_s[node][cw]  = sqrtf(v0 * v0 + v1 * v1 + v2 * v2 + 1e-8f);
            inner_s[node][cw] = v0 * w0 + v1 * w1 + v2 * w2;
            muw_s[node * 3 + 0][cw] = f2b(w0);
            muw_s[node * 3 + 1][cw] = f2b(w1);
            muw_s[node * 3 + 2][cw] = f2b(w2);
        }
    }
    __syncthreads();

    for (int i = t; i < 16 * 64; i += 256) {
        int r = i >> 6, c4 = (i & 63) * 4;
        float4 v;
        if (r < 8) v = (c4 < 128) ? *(const float4*)&qn_s[r][c4]
                                  : *(const float4*)&norm_s[r][c4 - 128];
        else { v.x = v.y = v.z = v.w = 0.f; }
        ushort4 h, l;
        h.x = f2b(v.x); l.x = f2b(v.x - b2f(h.x));
        h.y = f2b(v.y); l.y = f2b(v.y - b2f(h.y));
        h.z = f2b(v.z); l.z = f2b(v.z - b2f(h.z));
        h.w = f2b(v.w); l.w = f2b(v.w - b2f(h.w));
        *(ushort4*)&a_hi[r * 264 + c4] = h;
        *(ushort4*)&a_lo[r * 264 + c4] = l;
    }
    __syncthreads();

    f32x4 hreg[6];
    {
        const unsigned short* arh = &a_hi[m * 264];
        const unsigned short* arl = &a_lo[m * 264];
        #pragma unroll
        for (int jj = 0; jj < 6; jj++) {
            int ct = jj * 4 + wv;
            f32x4 acc = {0.f, 0.f, 0.f, 0.f};
            #pragma unroll
            for (int kt = 0; kt < 8; kt++) {
                bf16x8 ah = *(const bf16x8*)(arh + kt * 32 + qd * 8);
                bf16x8 al = *(const bf16x8*)(arl + kt * 32 + qd * 8);
                size_t bo = ((size_t)(ct * 8 + kt) * 64 + lane) * 8;
                bf16x8 bh = *(const bf16x8*)(B1_hi + bo);
                bf16x8 bl = *(const bf16x8*)(B1_lo + bo);
                acc = __builtin_amdgcn_mfma_f32_16x16x32_bf16(al, bh, acc, 0, 0, 0);
                acc = __builtin_amdgcn_mfma_f32_16x16x32_bf16(ah, bl, acc, 0, 0, 0);
                acc = __builtin_amdgcn_mfma_f32_16x16x32_bf16(ah, bh, acc, 0, 0, 0);
            }
            float bb = b_mix1[ct * 16 + m];
            #pragma unroll
            for (int r = 0; r < 4; r++) acc[r] = silu_f(acc[r] + bb);
            hreg[jj] = acc;
        }
    }
    __syncthreads();

    for (int i = t; i < 8 * 96; i += 256) {
        int r = 8 + i / 96, c4 = (i % 96) * 4;
        ushort4 z; z.x = z.y = z.z = z.w = 0;
        *(ushort4*)&a_hi[r * 392 + c4] = z;
        *(ushort4*)&a_lo[r * 392 + c4] = z;
    }
    if (qd < 2) {
        #pragma unroll
        for (int jj = 0; jj < 6; jj++) {
            int c = (jj * 4 + wv) * 16 + m;
            #pragma unroll
            for (int r = 0; r < 4; r++) {
                int nd = qd * 4 + r;
                float v = hreg[jj][r];
                unsigned short h = f2b(v);
                a_hi[nd * 392 + c] = h;
                a_lo[nd * 392 + c] = f2b(v - b2f(h));
            }
        }
    }
    __syncthreads();

    {
        const unsigned short* arh = &a_hi[m * 392];
        const unsigned short* arl = &a_lo[m * 392];
        f32x4 dreg[6];
        #pragma unroll
        for (int jj = 0; jj < 6; jj++) {
            int ct = jj * 4 + wv;
            f32x4 acc = {0.f, 0.f, 0.f, 0.f};
            #pragma unroll
            for (int kt = 0; kt < 12; kt++) {
                bf16x8 ah = *(const bf16x8*)(arh + kt * 32 + qd * 8);
                bf16x8 al = *(const bf16x8*)(arl + kt * 32 + qd * 8);
                size_t bo = ((size_t)(ct * 12 + kt) * 64 + lane) * 8;
                bf16x8 bh = *(const bf16x8*)(B2_hi + bo);
                bf16x8 bl = *(const bf16x8*)(B2_lo + bo);
                acc = __builtin_amdgcn_mfma_f32_16x16x32_bf16(al, bh, acc, 0, 0, 0);
                acc = __builtin_amdgcn_mfma_f32_16x16x32_bf16(ah, bl, acc, 0, 0, 0);
                acc = __builtin_amdgcn_mfma_f32_16x16x32_bf16(ah, bh, acc, 0, 0, 0);
            }
            float bb = b_mix2[ct * 16 + m];
            #pragma unroll
            for (int r = 0; r < 4; r++) acc[r] += bb;
            dreg[jj] = acc;
        }

        if (qd < 2) {
            #pragma unroll
            for (int jj = 0; jj < 2; jj++) {
                int c = (jj * 4 + wv) * 16 + m;
                #pragma unroll
                for (int r = 0; r < 4; r++) {
                    int nd = qd * 4 + r;
                    float val = qn_s[nd][c] + dreg[jj][r]
                              + dreg[jj + 4][r] * inner_s[nd][c];
                    q_out[(size_t)(n0 + nd) * H + c] = val;
                }
            }
            #pragma unroll
            for (int jj = 2; jj < 4; jj++) {
                int cw = (jj * 4 + wv) * 16 + m - 128;
                #pragma unroll
                for (int r = 0; r < 4; r++) {
                    int nd = qd * 4 + r;
                    float dms = dreg[jj][r];
                    #pragma unroll
                    for (int d = 0; d < 3; d++) {
                        size_t gi = ((size_t)(n0 + nd) * 3 + d) * H + cw;
                        float mun = mu[gi] + acc_mu[(size_t)(n0 + nd) * H3 + d * H + cw];
                        mu_out[gi] = mun + b2f(muw_s[nd * 3 + d][cw]) * dms;
                    }
                }
            }
        }
    }
}

extern "C" void kernel_launch(void* const* d_in, const int* in_sizes, int n_in,
                              void* d_out, int out_size, void* d_ws, size_t ws_size,
                              hipStream_t stream) {
    const float* q        = (const float*)d_in[0];
    const float* mu       = (const float*)d_in[1];
    const int*   eidx     = (const int*)d_in[2];
    const float* rbf      = (const float*)d_in[3];
    const float* unitv    = (const float*)d_in[4];
    const float* cutoff   = (const float*)d_in[5];
    const float* W_inter1 = (const float*)d_in[6];
    const float* b_inter1 = (const float*)d_in[7];
    const float* W_inter2 = (const float*)d_in[8];
    const float* b_inter2 = (const float*)d_in[9];
    const float* W_filt1  = (const float*)d_in[10];
    const float* b_filt1  = (const float*)d_in[11];
    const float* W_filt2  = (const float*)d_in[12];
    const float* b_filt2  = (const float*)d_in[13];
    const float* W_vec    = (const float*)d_in[14];
    const float* W_mix1   = (const float*)d_in[15];
    const float* b_mix1   = (const float*)d_in[16];
    const float* W_mix2   = (const float*)d_in[17];
    const float* b_mix2   = (const float*)d_in[18];

    // workspace layout
    char* p = (char*)d_ws;
    float* acc_q       = (float*)p;            p += (size_t)NN * H * 4;
    float* acc_mu      = (float*)p;            p += (size_t)NN * H3 * 4;
    float* sorted_unit = (float*)p;            p += (size_t)NE * 3 * 4;
    int*   counts      = (int*)p;              p += (size_t)NN * 4;
    int*   off         = (int*)p;              p += (size_t)(NN + 1) * 4;
    p = (char*)(((size_t)p + 255) & ~(size_t)255);
    int*   cursor      = (int*)p;              p += (size_t)NN * 4;
    p = (char*)(((size_t)p + 255) & ~(size_t)255);
    int*   sorted_eid  = (int*)p;              p += (size_t)NE * 4;
    int*   sorted_src  = (int*)p;              p += (size_t)NE * 4;
    p = (char*)(((size_t)p + 255) & ~(size_t)255);
    unsigned short* Bp    = (unsigned short*)p; p += (size_t)H * H3 * 2;
    unsigned short* Bv_hi = (unsigned short*)p; p += (size_t)H * H2 * 2;
    unsigned short* Bv_lo = (unsigned short*)p; p += (size_t)H * H2 * 2;
    unsigned short* B1_hi = (unsigned short*)p; p += (size_t)H2 * H3 * 2;
    unsigned short* B1_lo = (unsigned short*)p; p += (size_t)H2 * H3 * 2;
    unsigned short* B2_hi = (unsigned short*)p; p += (size_t)H3 * H3 * 2;
    unsigned short* B2_lo = (unsigned short*)p; p += (size_t)H3 * H3 * 2;
    p = (char*)(((size_t)p + 255) & ~(size_t)255);
    unsigned short* x_b  = (unsigned short*)p;  p += (size_t)NN * H3 * 2;
    unsigned short* mu_b = (unsigned short*)p;  p += (size_t)NN * H3 * 2;

    float* q_out  = (float*)d_out;
    float* mu_out = q_out + (size_t)NN * H;

    hipMemsetAsync(counts, 0, (size_t)NN * 4, stream);

    hist_kernel  <<<NE / 256, 256, 0, stream>>>(eidx, counts);
    pack_b_kernel<<<24, 256, 0, stream>>>(W_filt2, Bp);
    pack_split_kernel<<<(H  / 32) * (H2 / 16), 64, 0, stream>>>(W_vec,  H,  H2, Bv_hi, Bv_lo);
    pack_split_kernel<<<(H2 / 32) * (H3 / 16), 64, 0, stream>>>(W_mix1, H2, H3, B1_hi, B1_lo);
    pack_split_kernel<<<(H3 / 32) * (H3 / 16), 64, 0, stream>>>(W_mix2, H3, H3, B2_hi, B2_lo);
    scan_kernel  <<<1, 1024, 0, stream>>>(counts, off, cursor);
    place_kernel <<<NE / 256, 256, 0, stream>>>(eidx, unitv, cursor,
                                                sorted_eid, sorted_src, sorted_unit);
    node_x_kernel<<<NN / 16, 384, 0, stream>>>(q, W_inter1, b_inter1, W_inter2, b_inter2, x_b);
    mu2b_kernel  <<<NN * H3 / (4 * 256), 256, 0, stream>>>(mu, mu_b);
    edge_fused_kernel<<<NN, 256, 0, stream>>>(off, sorted_eid, sorted_src, sorted_unit,
                                              rbf, cutoff, W_filt1, b_filt1, Bp, b_filt2,
                                              x_b, mu_b, acc_q, acc_mu);
    mix_kernel   <<<NN / 8, 256, 0, stream>>>(q, mu, acc_q, acc_mu,
                                              Bv_hi, Bv_lo, B1_hi, B1_lo, B2_hi, B2_lo,
                                              b_mix1, b_mix2, q_out, mu_out);
}

// Round 7
// 524.499 us; speedup vs baseline: 4.1085x; 1.1537x over previous
//
#include <hip/hip_runtime.h>

#define NN 10000
#define NE 256000
#define H 128
#define H2 256
#define H3 384
#define NRBF 20

typedef __attribute__((ext_vector_type(8))) short bf16x8;
typedef __attribute__((ext_vector_type(4))) float f32x4;

__device__ __forceinline__ void FMA4(float4& a, float s, const float4& v) {
    a.x = fmaf(s, v.x, a.x); a.y = fmaf(s, v.y, a.y);
    a.z = fmaf(s, v.z, a.z); a.w = fmaf(s, v.w, a.w);
}

__device__ __forceinline__ float silu_f(float v) { return v / (1.f + __expf(-v)); }

// fp32 -> bf16 bits (RNE)
__device__ __forceinline__ unsigned short f2b(float f) {
    union { float f; unsigned u; } x; x.f = f;
    unsigned r = (x.u + 0x7FFFu + ((x.u >> 16) & 1u)) >> 16;
    return (unsigned short)r;
}
__device__ __forceinline__ float b2f(unsigned short b) {
    union { unsigned u; float f; } x; x.u = ((unsigned)b) << 16;
    return x.f;
}

// ---------------------------------------------------------------------------
// CSR build
// ---------------------------------------------------------------------------
__global__ __launch_bounds__(256) void hist_kernel(const int* __restrict__ eidx,
                                                   int* __restrict__ counts) {
    int e = blockIdx.x * 256 + threadIdx.x;
    atomicAdd(&counts[eidx[e]], 1);
}

__global__ __launch_bounds__(1024) void scan_kernel(const int* __restrict__ counts,
                                                    int* __restrict__ off,
                                                    int* __restrict__ cursor) {
    __shared__ int sums[1024];
    const int t = threadIdx.x;
    const int base = t * 10;
    int local[10];
    int s = 0;
    #pragma unroll
    for (int i = 0; i < 10; i++) {
        int idx = base + i;
        int v = (idx < NN) ? counts[idx] : 0;
        local[i] = s; s += v;
    }
    sums[t] = s;
    __syncthreads();
    for (int d = 1; d < 1024; d <<= 1) {
        int v = (t >= d) ? sums[t - d] : 0;
        __syncthreads();
        sums[t] += v;
        __syncthreads();
    }
    int prefix = (t > 0) ? sums[t - 1] : 0;
    #pragma unroll
    for (int i = 0; i < 10; i++) {
        int idx = base + i;
        if (idx < NN) { off[idx] = prefix + local[i]; cursor[idx] = prefix + local[i]; }
    }
    if (t == 1023) off[NN] = sums[1023];
}

__global__ __launch_bounds__(256) void place_kernel(
    const int* __restrict__ eidx, const float* __restrict__ unitv,
    int* __restrict__ cursor, int* __restrict__ sorted_eid,
    int* __restrict__ sorted_src, float* __restrict__ sorted_unit) {
    int e = blockIdx.x * 256 + threadIdx.x;
    int tgt = eidx[e];
    int src = eidx[NE + e];
    int pos = atomicAdd(&cursor[tgt], 1);
    sorted_eid[pos] = e;
    sorted_src[pos] = src;
    sorted_unit[pos * 3 + 0] = unitv[(size_t)e * 3 + 0];
    sorted_unit[pos * 3 + 1] = unitv[(size_t)e * 3 + 1];
    sorted_unit[pos * 3 + 2] = unitv[(size_t)e * 3 + 2];
}

// ---------------------------------------------------------------------------
// Pack W [K x N] fp32 -> bf16 (hi only) MFMA B-fragments.
// dst[((ct*(K/32)+kt)*64+lane)*8+j] = bf16(W[kt*32+(lane>>4)*8+j][ct*16+(lane&15)])
// grid = (K/32)*(N/16) blocks of 64 threads.
// ---------------------------------------------------------------------------
__global__ __launch_bounds__(64) void pack_hi_kernel(
    const float* __restrict__ W, int K, int N, unsigned short* __restrict__ dst) {
    const int KT = K >> 5;
    const int kt = blockIdx.x % KT, ct = blockIdx.x / KT;
    const int lane = threadIdx.x;
    const int m = lane & 15, qd = lane >> 4;
    size_t base = ((size_t)(ct * KT + kt) * 64 + lane) * 8;
    unsigned short v[8];
    #pragma unroll
    for (int j = 0; j < 8; j++) {
        int k = kt * 32 + qd * 8 + j;
        v[j] = f2b(W[(size_t)k * N + ct * 16 + m]);
    }
    *(ushort4*)&dst[base]     = *(ushort4*)&v[0];
    *(ushort4*)&dst[base + 4] = *(ushort4*)&v[4];
}

// hi/lo split pack (for mix kernel, needs fp32-grade precision)
__global__ __launch_bounds__(64) void pack_split_kernel(
    const float* __restrict__ W, int K, int N,
    unsigned short* __restrict__ hi, unsigned short* __restrict__ lo) {
    const int KT = K >> 5;
    const int kt = blockIdx.x % KT, ct = blockIdx.x / KT;
    const int lane = threadIdx.x;
    const int m = lane & 15, qd = lane >> 4;
    size_t base = ((size_t)(ct * KT + kt) * 64 + lane) * 8;
    #pragma unroll
    for (int j = 0; j < 8; j++) {
        int k = kt * 32 + qd * 8 + j;
        float v = W[(size_t)k * N + ct * 16 + m];
        unsigned short h = f2b(v);
        hi[base + j] = h;
        lo[base + j] = f2b(v - b2f(h));
    }
}

// mu fp32 -> bf16 copy
__global__ __launch_bounds__(256) void mu2b_kernel(const float* __restrict__ mu,
                                                   unsigned short* __restrict__ mu_b) {
    int i = blockIdx.x * 256 + threadIdx.x;
    float4 v = ((const float4*)mu)[i];
    ushort4 o;
    o.x = f2b(v.x); o.y = f2b(v.y); o.z = f2b(v.z); o.w = f2b(v.w);
    ((ushort4*)mu_b)[i] = o;
}

// ---------------------------------------------------------------------------
// node_x (MFMA): x_b = bf16(silu(q@W1+b1) @ W2 + b2). 32 nodes per 256-thread
// block (4 waves: st=row-tile, ch=col-half). Same fragment scheme as filter.
// ---------------------------------------------------------------------------
__global__ __launch_bounds__(256) void node_x_kernel(
    const float* __restrict__ q,
    const unsigned short* __restrict__ Bp1, const float* __restrict__ b1,
    const unsigned short* __restrict__ Bp2, const float* __restrict__ b2,
    unsigned short* __restrict__ x_b) {
    __shared__ __align__(16) unsigned short qa_s[32 * 136];
    __shared__ __align__(16) unsigned short h1_s[32 * 392];
    const int t = threadIdx.x;
    const int wv = t >> 6, lane = t & 63;
    const int m = lane & 15, qd = lane >> 4;
    const int st = wv >> 1, ch = wv & 1;
    const int n0 = blockIdx.x * 32;

    for (int i = t; i < 32 * 32; i += 256) {
        int r = i >> 5, c4 = (i & 31) * 4;
        int node = n0 + r;
        ushort4 o;
        if (node < NN) {
            float4 v = *(const float4*)&q[(size_t)node * H + c4];
            o.x = f2b(v.x); o.y = f2b(v.y); o.z = f2b(v.z); o.w = f2b(v.w);
        } else { o.x = o.y = o.z = o.w = 0; }
        *(ushort4*)&qa_s[r * 136 + c4] = o;
    }
    __syncthreads();

    // layer 1: K=128
    {
        const unsigned short* arow = &qa_s[(st * 16 + m) * 136 + qd * 8];
        #pragma unroll 1
        for (int jc = 0; jc < 12; jc++) {
            int ct = ch * 12 + jc;
            f32x4 acc = {0.f, 0.f, 0.f, 0.f};
            #pragma unroll
            for (int kt = 0; kt < 4; kt++) {
                bf16x8 af = *(const bf16x8*)(arow + kt * 32);
                bf16x8 bfr = *(const bf16x8*)(Bp1 + ((size_t)(ct * 4 + kt) * 64 + lane) * 8);
                acc = __builtin_amdgcn_mfma_f32_16x16x32_bf16(af, bfr, acc, 0, 0, 0);
            }
            int col = ct * 16 + m;
            float bb = b1[col];
            #pragma unroll
            for (int r = 0; r < 4; r++) {
                int row = st * 16 + qd * 4 + r;
                h1_s[row * 392 + col] = f2b(silu_f(acc[r] + bb));
            }
        }
    }
    __syncthreads();

    // layer 2: K=384
    {
        const unsigned short* arow = &h1_s[(st * 16 + m) * 392 + qd * 8];
        #pragma unroll 1
        for (int jc = 0; jc < 12; jc++) {
            int ct = ch * 12 + jc;
            f32x4 acc = {0.f, 0.f, 0.f, 0.f};
            #pragma unroll
            for (int kt = 0; kt < 12; kt++) {
                bf16x8 af = *(const bf16x8*)(arow + kt * 32);
                bf16x8 bfr = *(const bf16x8*)(Bp2 + ((size_t)(ct * 12 + kt) * 64 + lane) * 8);
                acc = __builtin_amdgcn_mfma_f32_16x16x32_bf16(af, bfr, acc, 0, 0, 0);
            }
            int col = ct * 16 + m;
            float bb = b2[col];
            #pragma unroll
            for (int r = 0; r < 4; r++) {
                int row = n0 + st * 16 + qd * 4 + r;
                if (row < NN) x_b[(size_t)row * H3 + col] = f2b(acc[r] + bb);
            }
        }
    }
}

// ---------------------------------------------------------------------------
// Filter MLP (MFMA), 64 sorted slots per 256-thread block. Writes filt bf16.
// ---------------------------------------------------------------------------
__global__ __launch_bounds__(256) void filter_kernel(
    const int* __restrict__ sorted_eid, const float* __restrict__ rbf,
    const float* __restrict__ cutoff,
    const float* __restrict__ Wf1, const float* __restrict__ bf1,
    const unsigned short* __restrict__ Bp, const float* __restrict__ bf2,
    unsigned short* __restrict__ filt) {
    __shared__ __align__(16) float rbf_s[64][NRBF];
    __shared__ __align__(16) unsigned short h1_s[64][136];
    __shared__ float cut_s[64];
    __shared__ int eid_s[64];
    const int t = threadIdx.x;
    const size_t j0 = (size_t)blockIdx.x * 64;

    if (t < 64) {
        int e = sorted_eid[j0 + t];
        eid_s[t] = e;
        cut_s[t] = cutoff[e];
    }
    __syncthreads();
    for (int w = t; w < 64 * NRBF; w += 256) {
        int i = w / NRBF, k = w % NRBF;
        rbf_s[i][k] = rbf[(size_t)eid_s[i] * NRBF + k];
    }
    __syncthreads();

    {
        const int c = t & 127;
        float wr[NRBF];
        #pragma unroll
        for (int k = 0; k < NRBF; k++) wr[k] = Wf1[k * H + c];
        const float bv = bf1[c];
        for (int s = (t >> 7); s < 64; s += 2) {
            float a = bv;
            #pragma unroll
            for (int k = 0; k < NRBF; k++) a = fmaf(rbf_s[s][k], wr[k], a);
            h1_s[s][c] = f2b(silu_f(a));
        }
    }
    __syncthreads();

    {
        const int wv = t >> 6;
        const int lane = t & 63;
        const int m = lane & 15, qd = lane >> 4;
        const unsigned short* arow = &h1_s[wv * 16 + m][qd * 8];
        #pragma unroll 1
        for (int c = 0; c < 24; c++) {
            f32x4 acc = {0.f, 0.f, 0.f, 0.f};
            #pragma unroll
            for (int kt = 0; kt < 4; kt++) {
                bf16x8 af = *(const bf16x8*)(arow + kt * 32);
                bf16x8 bfr = *(const bf16x8*)(Bp + ((size_t)(c * 4 + kt) * 64 + lane) * 8);
                acc = __builtin_amdgcn_mfma_f32_16x16x32_bf16(af, bfr, acc, 0, 0, 0);
            }
            const int col = c * 16 + m;
            const float bb = bf2[col];
            #pragma unroll
            for (int r = 0; r < 4; r++) {
                int slot = wv * 16 + qd * 4 + r;
                float v = (acc[r] + bb) * cut_s[slot];
                filt[(j0 + slot) * H3 + col] = f2b(v);
            }
        }
    }
}

// ---------------------------------------------------------------------------
// Gather v2: one node per 256-thread block. 4 edge-interleaved groups of 64
// lanes; each lane owns a channel pair (ushort2 loads). LDS-reduce 4 partials.
// ---------------------------------------------------------------------------
__global__ __launch_bounds__(256) void gather_kernel(
    const int* __restrict__ off, const int* __restrict__ sorted_src,
    const float* __restrict__ sorted_unit, const unsigned short* __restrict__ filt,
    const unsigned short* __restrict__ x_b, const unsigned short* __restrict__ mu_b,
    float* __restrict__ acc_q, float* __restrict__ acc_mu) {
    __shared__ float red_s[16][128];
    const int t = threadIdx.x;
    const int n = blockIdx.x;
    const int g = t >> 6, lane = t & 63;
    const int c2 = lane * 2;
    const int j0 = off[n], j1 = off[n + 1];

    float aq0 = 0.f, aq1 = 0.f, a00 = 0.f, a01 = 0.f;
    float a10 = 0.f, a11 = 0.f, a20 = 0.f, a21 = 0.f;
    for (int j = j0 + g; j < j1; j += 4) {
        int src = sorted_src[j];
        float u0 = sorted_unit[j * 3 + 0];
        float u1 = sorted_unit[j * 3 + 1];
        float u2 = sorted_unit[j * 3 + 2];
        const unsigned short* frow = filt + (size_t)j * H3 + c2;
        const unsigned short* xrow = x_b + (size_t)src * H3 + c2;
        const unsigned short* murow = mu_b + (size_t)src * H3 + c2;
        ushort2 fq = *(const ushort2*)(frow);
        ushort2 fr = *(const ushort2*)(frow + H);
        ushort2 fm = *(const ushort2*)(frow + 2 * H);
        ushort2 xq = *(const ushort2*)(xrow);
        ushort2 xr = *(const ushort2*)(xrow + H);
        ushort2 xm = *(const ushort2*)(xrow + 2 * H);
        ushort2 m0 = *(const ushort2*)(murow);
        ushort2 m1 = *(const ushort2*)(murow + H);
        ushort2 m2 = *(const ushort2*)(murow + 2 * H);
        float xrs0 = b2f(xr.x) * b2f(fr.x), xrs1 = b2f(xr.y) * b2f(fr.y);
        float xms0 = b2f(xm.x) * b2f(fm.x), xms1 = b2f(xm.y) * b2f(fm.y);
        aq0 = fmaf(b2f(xq.x), b2f(fq.x), aq0);
        aq1 = fmaf(b2f(xq.y), b2f(fq.y), aq1);
        a00 = fmaf(u0, xrs0, a00); a00 = fmaf(b2f(m0.x), xms0, a00);
        a01 = fmaf(u0, xrs1, a01); a01 = fmaf(b2f(m0.y), xms1, a01);
        a10 = fmaf(u1, xrs0, a10); a10 = fmaf(b2f(m1.x), xms0, a10);
        a11 = fmaf(u1, xrs1, a11); a11 = fmaf(b2f(m1.y), xms1, a11);
        a20 = fmaf(u2, xrs0, a20); a20 = fmaf(b2f(m2.x), xms0, a20);
        a21 = fmaf(u2, xrs1, a21); a21 = fmaf(b2f(m2.y), xms1, a21);
    }
    red_s[g * 4 + 0][c2] = aq0; red_s[g * 4 + 0][c2 + 1] = aq1;
    red_s[g * 4 + 1][c2] = a00; red_s[g * 4 + 1][c2 + 1] = a01;
    red_s[g * 4 + 2][c2] = a10; red_s[g * 4 + 2][c2 + 1] = a11;
    red_s[g * 4 + 3][c2] = a20; red_s[g * 4 + 3][c2 + 1] = a21;
    __syncthreads();
    if (t < 128) {
        float vq = red_s[0][t] + red_s[4][t] + red_s[8][t] + red_s[12][t];
        float v0 = red_s[1][t] + red_s[5][t] + red_s[9][t] + red_s[13][t];
        float v1 = red_s[2][t] + red_s[6][t] + red_s[10][t] + red_s[14][t];
        float v2 = red_s[3][t] + red_s[7][t] + red_s[11][t] + red_s[15][t];
        acc_q[(size_t)n * H + t] = vq;
        acc_mu[(size_t)n * H3 + t] = v0;
        acc_mu[(size_t)n * H3 + H + t] = v1;
        acc_mu[(size_t)n * H3 + 2 * H + t] = v2;
    }
}

// ---------------------------------------------------------------------------
// Mixing: split-bf16 MFMA (unchanged).
// ---------------------------------------------------------------------------
__global__ __launch_bounds__(256) void mix_kernel(
    const float* __restrict__ q, const float* __restrict__ mu,
    const float* __restrict__ acc_q, const float* __restrict__ acc_mu,
    const unsigned short* __restrict__ Bv_hi, const unsigned short* __restrict__ Bv_lo,
    const unsigned short* __restrict__ B1_hi, const unsigned short* __restrict__ B1_lo,
    const unsigned short* __restrict__ B2_hi, const unsigned short* __restrict__ B2_lo,
    const float* __restrict__ b_mix1, const float* __restrict__ b_mix2,
    float* __restrict__ q_out, float* __restrict__ mu_out) {

    __shared__ __align__(16) unsigned short a_hi[16 * 392];
    __shared__ __align__(16) unsigned short a_lo[16 * 392];
    __shared__ __align__(16) float qn_s[8][128];
    __shared__ __align__(16) float norm_s[8][128];
    __shared__ __align__(16) float inner_s[8][128];
    __shared__ __align__(16) unsigned short muw_s[24][136];

    const int t = threadIdx.x;
    const int wv = t >> 6, lane = t & 63;
    const int m = lane & 15, qd = lane >> 4;
    const int n0 = blockIdx.x * 8;

    {
        float4 a = *(const float4*)&q[(size_t)n0 * H + t * 4];
        float4 b = *(const float4*)&acc_q[(size_t)n0 * H + t * 4];
        a.x += b.x; a.y += b.y; a.z += b.z; a.w += b.w;
        ((float4*)qn_s)[t] = a;
    }
    for (int i = t; i < 32 * 32; i += 256) {
        int r = i >> 5, c4 = (i & 31) * 4;
        int n = r >> 2, d = r & 3;
        float4 v;
        if (d < 3) {
            float4 a = *(const float4*)&mu[((size_t)(n0 + n) * 3 + d) * H + c4];
            float4 b = *(const float4*)&acc_mu[(size_t)(n0 + n) * H3 + d * H + c4];
            v.x = a.x + b.x; v.y = a.y + b.y; v.z = a.z + b.z; v.w = a.w + b.w;
        } else { v.x = v.y = v.z = v.w = 0.f; }
        ushort4 h, l;
        h.x = f2b(v.x); l.x = f2b(v.x - b2f(h.x));
        h.y = f2b(v.y); l.y = f2b(v.y - b2f(h.y));
        h.z = f2b(v.z); l.z = f2b(v.z - b2f(h.z));
        h.w = f2b(v.w); l.w = f2b(v.w - b2f(h.w));
        *(ushort4*)&a_hi[r * 136 + c4] = h;
        *(ushort4*)&a_lo[r * 136 + c4] = l;
    }
    __syncthreads();

    {
        const int rt = wv >> 1, pp = wv & 1;
        const unsigned short* arh = &a_hi[(rt * 16 + m) * 136];
        const unsigned short* arl = &a_lo[(rt * 16 + m) * 136];
        const int node = rt * 4 + qd;
        f32x4 muv[4];
        #pragma unroll
        for (int jj = 0; jj < 4; jj++) {
            int ct = 2 * jj + pp;
            f32x4 acc = {0.f, 0.f, 0.f, 0.f};
            #pragma unroll
            for (int kt = 0; kt < 4; kt++) {
                bf16x8 ah = *(const bf16x8*)(arh + kt * 32 + qd * 8);
                bf16x8 al = *(const bf16x8*)(arl + kt * 32 + qd * 8);
                size_t bo = ((size_t)(ct * 4 + kt) * 64 + lane) * 8;
                bf16x8 bh = *(const bf16x8*)(Bv_hi + bo);
                bf16x8 bl = *(const bf16x8*)(Bv_lo + bo);
                acc = __builtin_amdgcn_mfma_f32_16x16x32_bf16(al, bh, acc, 0, 0, 0);
                acc = __builtin_amdgcn_mfma_f32_16x16x32_bf16(ah, bl, acc, 0, 0, 0);
                acc = __builtin_amdgcn_mfma_f32_16x16x32_bf16(ah, bh, acc, 0, 0, 0);
            }
            muv[jj] = acc;
        }
        #pragma unroll
        for (int jj = 0; jj < 4; jj++) {
            int ct = 8 + 2 * jj + pp;
            f32x4 acc = {0.f, 0.f, 0.f, 0.f};
            #pragma unroll
            for (int kt = 0; kt < 4; kt++) {
                bf16x8 ah = *(const bf16x8*)(arh + kt * 32 + qd * 8);
                bf16x8 al = *(const bf16x8*)(arl + kt * 32 + qd * 8);
                size_t bo = ((size_t)(ct * 4 + kt) * 64 + lane) * 8;
                bf16x8 bh = *(const bf16x8*)(Bv_hi + bo);
                bf16x8 bl = *(const bf16x8*)(Bv_lo + bo);
                acc = __builtin_amdgcn_mfma_f32_16x16x32_bf16(al, bh, acc, 0, 0, 0);
                acc = __builtin_amdgcn_mfma_f32_16x16x32_bf16(ah, bl, acc, 0, 0, 0);
                acc = __builtin_amdgcn_mfma_f32_16x16x32_bf16(ah, bh, acc, 0, 0, 0);
            }
            int cw = (2 * jj + pp) * 16 + m;
            float v0 = muv[jj][0], v1 = muv[jj][1], v2 = muv[jj][2];
            float w0 = acc[0], w1 = acc[1], w2 = acc[2];
            norm_s[node][cw]  = sqrtf(v0 * v0 + v1 * v1 + v2 * v2 + 1e-8f);
            inner_s[node][cw] = v0 * w0 + v1 * w1 + v2 * w2;
            muw_s[node * 3 + 0][cw] = f2b(w0);
            muw_s[node * 3 + 1][cw] = f2b(w1);
            muw_s[node * 3 + 2][cw] = f2b(w2);
        }
    }
    __syncthreads();

    for (int i = t; i < 16 * 64; i += 256) {
        int r = i >> 6, c4 = (i & 63) * 4;
        float4 v;
        if (r < 8) v = (c4 < 128) ? *(const float4*)&qn_s[r][c4]
                                  : *(const float4*)&norm_s[r][c4 - 128];
        else { v.x = v.y = v.z = v.w = 0.f; }
        ushort4 h, l;
        h.x = f2b(v.x); l.x = f2b(v.x - b2f(h.x));
        h.y = f2b(v.y); l.y = f2b(v.y - b2f(h.y));
        h.z = f2b(v.z); l.z = f2b(v.z - b2f(h.z));
        h.w = f2b(v.w); l.w = f2b(v.w - b2f(h.w));
        *(ushort4*)&a_hi[r * 264 + c4] = h;
        *(ushort4*)&a_lo[r * 264 + c4] = l;
    }
    __syncthreads();

    f32x4 hreg[6];
    {
        const unsigned short* arh = &a_hi[m * 264];
        const unsigned short* arl = &a_lo[m * 264];
        #pragma unroll
        for (int jj = 0; jj < 6; jj++) {
            int ct = jj * 4 + wv;
            f32x4 acc = {0.f, 0.f, 0.f, 0.f};
            #pragma unroll
            for (int kt = 0; kt < 8; kt++) {
                bf16x8 ah = *(const bf16x8*)(arh + kt * 32 + qd * 8);
                bf16x8 al = *(const bf16x8*)(arl + kt * 32 + qd * 8);
                size_t bo = ((size_t)(ct * 8 + kt) * 64 + lane) * 8;
                bf16x8 bh = *(const bf16x8*)(B1_hi + bo);
                bf16x8 bl = *(const bf16x8*)(B1_lo + bo);
                acc = __builtin_amdgcn_mfma_f32_16x16x32_bf16(al, bh, acc, 0, 0, 0);
                acc = __builtin_amdgcn_mfma_f32_16x16x32_bf16(ah, bl, acc, 0, 0, 0);
                acc = __builtin_amdgcn_mfma_f32_16x16x32_bf16(ah, bh, acc, 0, 0, 0);
            }
            float bb = b_mix1[ct * 16 + m];
            #pragma unroll
            for (int r = 0; r < 4; r++) acc[r] = silu_f(acc[r] + bb);
            hreg[jj] = acc;
        }
    }
    __syncthreads();

    for (int i = t; i < 8 * 96; i += 256) {
        int r = 8 + i / 96, c4 = (i % 96) * 4;
        ushort4 z; z.x = z.y = z.z = z.w = 0;
        *(ushort4*)&a_hi[r * 392 + c4] = z;
        *(ushort4*)&a_lo[r * 392 + c4] = z;
    }
    if (qd < 2) {
        #pragma unroll
        for (int jj = 0; jj < 6; jj++) {
            int c = (jj * 4 + wv) * 16 + m;
            #pragma unroll
            for (int r = 0; r < 4; r++) {
                int nd = qd * 4 + r;
                float v = hreg[jj][r];
                unsigned short h = f2b(v);
                a_hi[nd * 392 + c] = h;
                a_lo[nd * 392 + c] = f2b(v - b2f(h));
            }
        }
    }
    __syncthreads();

    {
        const unsigned short* arh = &a_hi[m * 392];
        const unsigned short* arl = &a_lo[m * 392];
        f32x4 dreg[6];
        #pragma unroll
        for (int jj = 0; jj < 6; jj++) {
            int ct = jj * 4 + wv;
            f32x4 acc = {0.f, 0.f, 0.f, 0.f};
            #pragma unroll
            for (int kt = 0; kt < 12; kt++) {
                bf16x8 ah = *(const bf16x8*)(arh + kt * 32 + qd * 8);
                bf16x8 al = *(const bf16x8*)(arl + kt * 32 + qd * 8);
                size_t bo = ((size_t)(ct * 12 + kt) * 64 + lane) * 8;
                bf16x8 bh = *(const bf16x8*)(B2_hi + bo);
                bf16x8 bl = *(const bf16x8*)(B2_lo + bo);
                acc = __builtin_amdgcn_mfma_f32_16x16x32_bf16(al, bh, acc, 0, 0, 0);
                acc = __builtin_amdgcn_mfma_f32_16x16x32_bf16(ah, bl, acc, 0, 0, 0);
                acc = __builtin_amdgcn_mfma_f32_16x16x32_bf16(ah, bh, acc, 0, 0, 0);
            }
            float bb = b_mix2[ct * 16 + m];
            #pragma unroll
            for (int r = 0; r < 4; r++) acc[r] += bb;
            dreg[jj] = acc;
        }

        if (qd < 2) {
            #pragma unroll
            for (int jj = 0; jj < 2; jj++) {
                int c = (jj * 4 + wv) * 16 + m;
                #pragma unroll
                for (int r = 0; r < 4; r++) {
                    int nd = qd * 4 + r;
                    float val = qn_s[nd][c] + dreg[jj][r]
                              + dreg[jj + 4][r] * inner_s[nd][c];
                    q_out[(size_t)(n0 + nd) * H + c] = val;
                }
            }
            #pragma unroll
            for (int jj = 2; jj < 4; jj++) {
                int cw = (jj * 4 + wv) * 16 + m - 128;
                #pragma unroll
                for (int r = 0; r < 4; r++) {
                    int nd = qd * 4 + r;
                    float dms = dreg[jj][r];
                    #pragma unroll
                    for (int d = 0; d < 3; d++) {
                        size_t gi = ((size_t)(n0 + nd) * 3 + d) * H + cw;
                        float mun = mu[gi] + acc_mu[(size_t)(n0 + nd) * H3 + d * H + cw];
                        mu_out[gi] = mun + b2f(muw_s[nd * 3 + d][cw]) * dms;
                    }
                }
            }
        }
    }
}

extern "C" void kernel_launch(void* const* d_in, const int* in_sizes, int n_in,
                              void* d_out, int out_size, void* d_ws, size_t ws_size,
                              hipStream_t stream) {
    const float* q        = (const float*)d_in[0];
    const float* mu       = (const float*)d_in[1];
    const int*   eidx     = (const int*)d_in[2];
    const float* rbf      = (const float*)d_in[3];
    const float* unitv    = (const float*)d_in[4];
    const float* cutoff   = (const float*)d_in[5];
    const float* W_inter1 = (const float*)d_in[6];
    const float* b_inter1 = (const float*)d_in[7];
    const float* W_inter2 = (const float*)d_in[8];
    const float* b_inter2 = (const float*)d_in[9];
    const float* W_filt1  = (const float*)d_in[10];
    const float* b_filt1  = (const float*)d_in[11];
    const float* W_filt2  = (const float*)d_in[12];
    const float* b_filt2  = (const float*)d_in[13];
    const float* W_vec    = (const float*)d_in[14];
    const float* W_mix1   = (const float*)d_in[15];
    const float* b_mix1   = (const float*)d_in[16];
    const float* W_mix2   = (const float*)d_in[17];
    const float* b_mix2   = (const float*)d_in[18];

    // workspace layout
    char* p = (char*)d_ws;
    float* acc_q       = (float*)p;            p += (size_t)NN * H * 4;
    float* acc_mu      = (float*)p;            p += (size_t)NN * H3 * 4;
    float* sorted_unit = (float*)p;            p += (size_t)NE * 3 * 4;
    int*   counts      = (int*)p;              p += (size_t)NN * 4;
    int*   off         = (int*)p;              p += (size_t)(NN + 1) * 4;
    p = (char*)(((size_t)p + 255) & ~(size_t)255);
    int*   cursor      = (int*)p;              p += (size_t)NN * 4;
    p = (char*)(((size_t)p + 255) & ~(size_t)255);
    int*   sorted_eid  = (int*)p;              p += (size_t)NE * 4;
    int*   sorted_src  = (int*)p;              p += (size_t)NE * 4;
    p = (char*)(((size_t)p + 255) & ~(size_t)255);
    unsigned short* Bp    = (unsigned short*)p; p += (size_t)H * H3 * 2;
    unsigned short* Bp1   = (unsigned short*)p; p += (size_t)H * H3 * 2;
    unsigned short* Bp2   = (unsigned short*)p; p += (size_t)H3 * H3 * 2;
    unsigned short* Bv_hi = (unsigned short*)p; p += (size_t)H * H2 * 2;
    unsigned short* Bv_lo = (unsigned short*)p; p += (size_t)H * H2 * 2;
    unsigned short* B1_hi = (unsigned short*)p; p += (size_t)H2 * H3 * 2;
    unsigned short* B1_lo = (unsigned short*)p; p += (size_t)H2 * H3 * 2;
    unsigned short* B2_hi = (unsigned short*)p; p += (size_t)H3 * H3 * 2;
    unsigned short* B2_lo = (unsigned short*)p; p += (size_t)H3 * H3 * 2;
    p = (char*)(((size_t)p + 255) & ~(size_t)255);
    unsigned short* x_b  = (unsigned short*)p;  p += (size_t)NN * H3 * 2;
    unsigned short* mu_b = (unsigned short*)p;  p += (size_t)NN * H3 * 2;
    p = (char*)(((size_t)p + 255) & ~(size_t)255);
    unsigned short* filt = (unsigned short*)p;  p += (size_t)NE * H3 * 2;

    float* q_out  = (float*)d_out;
    float* mu_out = q_out + (size_t)NN * H;

    hipMemsetAsync(counts, 0, (size_t)NN * 4, stream);

    hist_kernel  <<<NE / 256, 256, 0, stream>>>(eidx, counts);
    pack_hi_kernel<<<(H / 32) * (H3 / 16), 64, 0, stream>>>(W_filt2, H, H3, Bp);
    pack_hi_kernel<<<(H / 32) * (H3 / 16), 64, 0, stream>>>(W_inter1, H, H3, Bp1);
    pack_hi_kernel<<<(H3 / 32) * (H3 / 16), 64, 0, stream>>>(W_inter2, H3, H3, Bp2);
    pack_split_kernel<<<(H  / 32) * (H2 / 16), 64, 0, stream>>>(W_vec,  H,  H2, Bv_hi, Bv_lo);
    pack_split_kernel<<<(H2 / 32) * (H3 / 16), 64, 0, stream>>>(W_mix1, H2, H3, B1_hi, B1_lo);
    pack_split_kernel<<<(H3 / 32) * (H3 / 16), 64, 0, stream>>>(W_mix2, H3, H3, B2_hi, B2_lo);
    scan_kernel  <<<1, 1024, 0, stream>>>(counts, off, cursor);
    place_kernel <<<NE / 256, 256, 0, stream>>>(eidx, unitv, cursor,
                                                sorted_eid, sorted_src, sorted_unit);
    node_x_kernel<<<(NN + 31) / 32, 256, 0, stream>>>(q, Bp1, b_inter1, Bp2, b_inter2, x_b);
    mu2b_kernel  <<<NN * H3 / (4 * 256), 256, 0, stream>>>(mu, mu_b);
    filter_kernel<<<NE / 64, 256, 0, stream>>>(sorted_eid, rbf, cutoff,
                                               W_filt1, b_filt1, Bp, b_filt2, filt);
    gather_kernel<<<NN, 256, 0, stream>>>(off, sorted_src, sorted_unit, filt,
                                          x_b, mu_b, acc_q, acc_mu);
    mix_kernel   <<<NN / 8, 256, 0, stream>>>(q, mu, acc_q, acc_mu,
                                              Bv_hi, Bv_lo, B1_hi, B1_lo, B2_hi, B2_lo,
                                              b_mix1, b_mix2, q_out, mu_out);
}

// Round 8
// 491.506 us; speedup vs baseline: 4.3843x; 1.0671x over previous
//
#include <hip/hip_runtime.h>

#define NN 10000
#define NE 256000
#define H 128
#define H2 256
#define H3 384
#define NRBF 20

typedef __attribute__((ext_vector_type(8))) short bf16x8;
typedef __attribute__((ext_vector_type(4))) float f32x4;

__device__ __forceinline__ void FMA4(float4& a, float s, const float4& v) {
    a.x = fmaf(s, v.x, a.x); a.y = fmaf(s, v.y, a.y);
    a.z = fmaf(s, v.z, a.z); a.w = fmaf(s, v.w, a.w);
}

__device__ __forceinline__ float silu_f(float v) { return v / (1.f + __expf(-v)); }

// fp32 -> bf16 bits (RNE)
__device__ __forceinline__ unsigned short f2b(float f) {
    union { float f; unsigned u; } x; x.f = f;
    unsigned r = (x.u + 0x7FFFu + ((x.u >> 16) & 1u)) >> 16;
    return (unsigned short)r;
}
__device__ __forceinline__ float b2f(unsigned short b) {
    union { unsigned u; float f; } x; x.u = ((unsigned)b) << 16;
    return x.f;
}

// ---------------------------------------------------------------------------
// CSR build
// ---------------------------------------------------------------------------
__global__ __launch_bounds__(256) void hist_kernel(const int* __restrict__ eidx,
                                                   int* __restrict__ counts) {
    int e = blockIdx.x * 256 + threadIdx.x;
    atomicAdd(&counts[eidx[e]], 1);
}

__global__ __launch_bounds__(1024) void scan_kernel(const int* __restrict__ counts,
                                                    int* __restrict__ off,
                                                    int* __restrict__ cursor) {
    __shared__ int sums[1024];
    const int t = threadIdx.x;
    const int base = t * 10;
    int local[10];
    int s = 0;
    #pragma unroll
    for (int i = 0; i < 10; i++) {
        int idx = base + i;
        int v = (idx < NN) ? counts[idx] : 0;
        local[i] = s; s += v;
    }
    sums[t] = s;
    __syncthreads();
    for (int d = 1; d < 1024; d <<= 1) {
        int v = (t >= d) ? sums[t - d] : 0;
        __syncthreads();
        sums[t] += v;
        __syncthreads();
    }
    int prefix = (t > 0) ? sums[t - 1] : 0;
    #pragma unroll
    for (int i = 0; i < 10; i++) {
        int idx = base + i;
        if (idx < NN) { off[idx] = prefix + local[i]; cursor[idx] = prefix + local[i]; }
    }
    if (t == 1023) off[NN] = sums[1023];
}

__global__ __launch_bounds__(256) void place_kernel(
    const int* __restrict__ eidx, const float* __restrict__ unitv,
    int* __restrict__ cursor, int* __restrict__ sorted_eid,
    int* __restrict__ sorted_src, float* __restrict__ sorted_unit) {
    int e = blockIdx.x * 256 + threadIdx.x;
    int tgt = eidx[e];
    int src = eidx[NE + e];
    int pos = atomicAdd(&cursor[tgt], 1);
    sorted_eid[pos] = e;
    sorted_src[pos] = src;
    sorted_unit[pos * 3 + 0] = unitv[(size_t)e * 3 + 0];
    sorted_unit[pos * 3 + 1] = unitv[(size_t)e * 3 + 1];
    sorted_unit[pos * 3 + 2] = unitv[(size_t)e * 3 + 2];
}

// ---------------------------------------------------------------------------
// Pack W [K x N] fp32 -> bf16 (hi only) MFMA B-fragments.
// ---------------------------------------------------------------------------
__global__ __launch_bounds__(64) void pack_hi_kernel(
    const float* __restrict__ W, int K, int N, unsigned short* __restrict__ dst) {
    const int KT = K >> 5;
    const int kt = blockIdx.x % KT, ct = blockIdx.x / KT;
    const int lane = threadIdx.x;
    const int m = lane & 15, qd = lane >> 4;
    size_t base = ((size_t)(ct * KT + kt) * 64 + lane) * 8;
    unsigned short v[8];
    #pragma unroll
    for (int j = 0; j < 8; j++) {
        int k = kt * 32 + qd * 8 + j;
        v[j] = f2b(W[(size_t)k * N + ct * 16 + m]);
    }
    *(ushort4*)&dst[base]     = *(ushort4*)&v[0];
    *(ushort4*)&dst[base + 4] = *(ushort4*)&v[4];
}

// hi/lo split pack (for mix kernel, needs fp32-grade precision)
__global__ __launch_bounds__(64) void pack_split_kernel(
    const float* __restrict__ W, int K, int N,
    unsigned short* __restrict__ hi, unsigned short* __restrict__ lo) {
    const int KT = K >> 5;
    const int kt = blockIdx.x % KT, ct = blockIdx.x / KT;
    const int lane = threadIdx.x;
    const int m = lane & 15, qd = lane >> 4;
    size_t base = ((size_t)(ct * KT + kt) * 64 + lane) * 8;
    #pragma unroll
    for (int j = 0; j < 8; j++) {
        int k = kt * 32 + qd * 8 + j;
        float v = W[(size_t)k * N + ct * 16 + m];
        unsigned short h = f2b(v);
        hi[base + j] = h;
        lo[base + j] = f2b(v - b2f(h));
    }
}

// mu fp32 -> bf16 copy
__global__ __launch_bounds__(256) void mu2b_kernel(const float* __restrict__ mu,
                                                   unsigned short* __restrict__ mu_b) {
    int i = blockIdx.x * 256 + threadIdx.x;
    float4 v = ((const float4*)mu)[i];
    ushort4 o;
    o.x = f2b(v.x); o.y = f2b(v.y); o.z = f2b(v.z); o.w = f2b(v.w);
    ((ushort4*)mu_b)[i] = o;
}

// ---------------------------------------------------------------------------
// node_x (MFMA): x_b = bf16(silu(q@W1+b1) @ W2 + b2). 32 nodes per block.
// ---------------------------------------------------------------------------
__global__ __launch_bounds__(256) void node_x_kernel(
    const float* __restrict__ q,
    const unsigned short* __restrict__ Bp1, const float* __restrict__ b1,
    const unsigned short* __restrict__ Bp2, const float* __restrict__ b2,
    unsigned short* __restrict__ x_b) {
    __shared__ __align__(16) unsigned short qa_s[32 * 136];
    __shared__ __align__(16) unsigned short h1_s[32 * 392];
    const int t = threadIdx.x;
    const int wv = t >> 6, lane = t & 63;
    const int m = lane & 15, qd = lane >> 4;
    const int st = wv >> 1, ch = wv & 1;
    const int n0 = blockIdx.x * 32;

    for (int i = t; i < 32 * 32; i += 256) {
        int r = i >> 5, c4 = (i & 31) * 4;
        int node = n0 + r;
        ushort4 o;
        if (node < NN) {
            float4 v = *(const float4*)&q[(size_t)node * H + c4];
            o.x = f2b(v.x); o.y = f2b(v.y); o.z = f2b(v.z); o.w = f2b(v.w);
        } else { o.x = o.y = o.z = o.w = 0; }
        *(ushort4*)&qa_s[r * 136 + c4] = o;
    }
    __syncthreads();

    {
        const unsigned short* arow = &qa_s[(st * 16 + m) * 136 + qd * 8];
        #pragma unroll 1
        for (int jc = 0; jc < 12; jc++) {
            int ct = ch * 12 + jc;
            f32x4 acc = {0.f, 0.f, 0.f, 0.f};
            #pragma unroll
            for (int kt = 0; kt < 4; kt++) {
                bf16x8 af = *(const bf16x8*)(arow + kt * 32);
                bf16x8 bfr = *(const bf16x8*)(Bp1 + ((size_t)(ct * 4 + kt) * 64 + lane) * 8);
                acc = __builtin_amdgcn_mfma_f32_16x16x32_bf16(af, bfr, acc, 0, 0, 0);
            }
            int col = ct * 16 + m;
            float bb = b1[col];
            #pragma unroll
            for (int r = 0; r < 4; r++) {
                int row = st * 16 + qd * 4 + r;
                h1_s[row * 392 + col] = f2b(silu_f(acc[r] + bb));
            }
        }
    }
    __syncthreads();

    {
        const unsigned short* arow = &h1_s[(st * 16 + m) * 392 + qd * 8];
        #pragma unroll 1
        for (int jc = 0; jc < 12; jc++) {
            int ct = ch * 12 + jc;
            f32x4 acc = {0.f, 0.f, 0.f, 0.f};
            #pragma unroll
            for (int kt = 0; kt < 12; kt++) {
                bf16x8 af = *(const bf16x8*)(arow + kt * 32);
                bf16x8 bfr = *(const bf16x8*)(Bp2 + ((size_t)(ct * 12 + kt) * 64 + lane) * 8);
                acc = __builtin_amdgcn_mfma_f32_16x16x32_bf16(af, bfr, acc, 0, 0, 0);
            }
            int col = ct * 16 + m;
            float bb = b2[col];
            #pragma unroll
            for (int r = 0; r < 4; r++) {
                int row = n0 + st * 16 + qd * 4 + r;
                if (row < NN) x_b[(size_t)row * H3 + col] = f2b(acc[r] + bb);
            }
        }
    }
}

// ---------------------------------------------------------------------------
// Filter MLP (MFMA), unchanged from R7.
// ---------------------------------------------------------------------------
__global__ __launch_bounds__(256) void filter_kernel(
    const int* __restrict__ sorted_eid, const float* __restrict__ rbf,
    const float* __restrict__ cutoff,
    const float* __restrict__ Wf1, const float* __restrict__ bf1,
    const unsigned short* __restrict__ Bp, const float* __restrict__ bf2,
    unsigned short* __restrict__ filt) {
    __shared__ __align__(16) float rbf_s[64][NRBF];
    __shared__ __align__(16) unsigned short h1_s[64][136];
    __shared__ float cut_s[64];
    __shared__ int eid_s[64];
    const int t = threadIdx.x;
    const size_t j0 = (size_t)blockIdx.x * 64;

    if (t < 64) {
        int e = sorted_eid[j0 + t];
        eid_s[t] = e;
        cut_s[t] = cutoff[e];
    }
    __syncthreads();
    for (int w = t; w < 64 * NRBF; w += 256) {
        int i = w / NRBF, k = w % NRBF;
        rbf_s[i][k] = rbf[(size_t)eid_s[i] * NRBF + k];
    }
    __syncthreads();

    {
        const int c = t & 127;
        float wr[NRBF];
        #pragma unroll
        for (int k = 0; k < NRBF; k++) wr[k] = Wf1[k * H + c];
        const float bv = bf1[c];
        for (int s = (t >> 7); s < 64; s += 2) {
            float a = bv;
            #pragma unroll
            for (int k = 0; k < NRBF; k++) a = fmaf(rbf_s[s][k], wr[k], a);
            h1_s[s][c] = f2b(silu_f(a));
        }
    }
    __syncthreads();

    {
        const int wv = t >> 6;
        const int lane = t & 63;
        const int m = lane & 15, qd = lane >> 4;
        const unsigned short* arow = &h1_s[wv * 16 + m][qd * 8];
        #pragma unroll 1
        for (int c = 0; c < 24; c++) {
            f32x4 acc = {0.f, 0.f, 0.f, 0.f};
            #pragma unroll
            for (int kt = 0; kt < 4; kt++) {
                bf16x8 af = *(const bf16x8*)(arow + kt * 32);
                bf16x8 bfr = *(const bf16x8*)(Bp + ((size_t)(c * 4 + kt) * 64 + lane) * 8);
                acc = __builtin_amdgcn_mfma_f32_16x16x32_bf16(af, bfr, acc, 0, 0, 0);
            }
            const int col = c * 16 + m;
            const float bb = bf2[col];
            #pragma unroll
            for (int r = 0; r < 4; r++) {
                int slot = wv * 16 + qd * 4 + r;
                float v = (acc[r] + bb) * cut_s[slot];
                filt[(j0 + slot) * H3 + col] = f2b(v);
            }
        }
    }
}

// ---------------------------------------------------------------------------
// Gather v2 (unchanged from R7).
// ---------------------------------------------------------------------------
__global__ __launch_bounds__(256) void gather_kernel(
    const int* __restrict__ off, const int* __restrict__ sorted_src,
    const float* __restrict__ sorted_unit, const unsigned short* __restrict__ filt,
    const unsigned short* __restrict__ x_b, const unsigned short* __restrict__ mu_b,
    float* __restrict__ acc_q, float* __restrict__ acc_mu) {
    __shared__ float red_s[16][128];
    const int t = threadIdx.x;
    const int n = blockIdx.x;
    const int g = t >> 6, lane = t & 63;
    const int c2 = lane * 2;
    const int j0 = off[n], j1 = off[n + 1];

    float aq0 = 0.f, aq1 = 0.f, a00 = 0.f, a01 = 0.f;
    float a10 = 0.f, a11 = 0.f, a20 = 0.f, a21 = 0.f;
    for (int j = j0 + g; j < j1; j += 4) {
        int src = sorted_src[j];
        float u0 = sorted_unit[j * 3 + 0];
        float u1 = sorted_unit[j * 3 + 1];
        float u2 = sorted_unit[j * 3 + 2];
        const unsigned short* frow = filt + (size_t)j * H3 + c2;
        const unsigned short* xrow = x_b + (size_t)src * H3 + c2;
        const unsigned short* murow = mu_b + (size_t)src * H3 + c2;
        ushort2 fq = *(const ushort2*)(frow);
        ushort2 fr = *(const ushort2*)(frow + H);
        ushort2 fm = *(const ushort2*)(frow + 2 * H);
        ushort2 xq = *(const ushort2*)(xrow);
        ushort2 xr = *(const ushort2*)(xrow + H);
        ushort2 xm = *(const ushort2*)(xrow + 2 * H);
        ushort2 m0 = *(const ushort2*)(murow);
        ushort2 m1 = *(const ushort2*)(murow + H);
        ushort2 m2 = *(const ushort2*)(murow + 2 * H);
        float xrs0 = b2f(xr.x) * b2f(fr.x), xrs1 = b2f(xr.y) * b2f(fr.y);
        float xms0 = b2f(xm.x) * b2f(fm.x), xms1 = b2f(xm.y) * b2f(fm.y);
        aq0 = fmaf(b2f(xq.x), b2f(fq.x), aq0);
        aq1 = fmaf(b2f(xq.y), b2f(fq.y), aq1);
        a00 = fmaf(u0, xrs0, a00); a00 = fmaf(b2f(m0.x), xms0, a00);
        a01 = fmaf(u0, xrs1, a01); a01 = fmaf(b2f(m0.y), xms1, a01);
        a10 = fmaf(u1, xrs0, a10); a10 = fmaf(b2f(m1.x), xms0, a10);
        a11 = fmaf(u1, xrs1, a11); a11 = fmaf(b2f(m1.y), xms1, a11);
        a20 = fmaf(u2, xrs0, a20); a20 = fmaf(b2f(m2.x), xms0, a20);
        a21 = fmaf(u2, xrs1, a21); a21 = fmaf(b2f(m2.y), xms1, a21);
    }
    red_s[g * 4 + 0][c2] = aq0; red_s[g * 4 + 0][c2 + 1] = aq1;
    red_s[g * 4 + 1][c2] = a00; red_s[g * 4 + 1][c2 + 1] = a01;
    red_s[g * 4 + 2][c2] = a10; red_s[g * 4 + 2][c2 + 1] = a11;
    red_s[g * 4 + 3][c2] = a20; red_s[g * 4 + 3][c2 + 1] = a21;
    __syncthreads();
    if (t < 128) {
        float vq = red_s[0][t] + red_s[4][t] + red_s[8][t] + red_s[12][t];
        float v0 = red_s[1][t] + red_s[5][t] + red_s[9][t] + red_s[13][t];
        float v1 = red_s[2][t] + red_s[6][t] + red_s[10][t] + red_s[14][t];
        float v2 = red_s[3][t] + red_s[7][t] + red_s[11][t] + red_s[15][t];
        acc_q[(size_t)n * H + t] = vq;
        acc_mu[(size_t)n * H3 + t] = v0;
        acc_mu[(size_t)n * H3 + H + t] = v1;
        acc_mu[(size_t)n * H3 + 2 * H + t] = v2;
    }
}

// ---------------------------------------------------------------------------
// Mixing v3: 16 nodes per 512-thread block (8 waves), 625 blocks.
// A staged fp32 in LDS; hi/lo split fragments hoisted into registers per wave
// (zero LDS traffic inside ct loops). Same 3-pass split numerics as v2.
// LDS ~63 KB -> 2 blocks/CU (16 waves).
// ---------------------------------------------------------------------------
__global__ __launch_bounds__(512, 4) void mix_kernel(
    const float* __restrict__ q, const float* __restrict__ mu,
    const float* __restrict__ acc_q, const float* __restrict__ acc_mu,
    const unsigned short* __restrict__ Bv_hi, const unsigned short* __restrict__ Bv_lo,
    const unsigned short* __restrict__ B1_hi, const unsigned short* __restrict__ B1_lo,
    const unsigned short* __restrict__ B2_hi, const unsigned short* __restrict__ B2_lo,
    const float* __restrict__ b_mix1, const float* __restrict__ b_mix2,
    float* __restrict__ q_out, float* __restrict__ mu_out) {

    __shared__ __align__(16) float A_f32[64 * 132];            // 33.8 KB, reused 3x
    __shared__ __align__(16) float qn_s[16][128];              // 8 KB
    __shared__ __align__(16) float inner_s[16][128];           // 8 KB
    __shared__ __align__(16) unsigned short muw_s[48][136];    // 13 KB

    const int t = threadIdx.x;
    const int wv = t >> 6, lane = t & 63;
    const int m = lane & 15, qd = lane >> 4;
    const int n0 = blockIdx.x * 16;

    // ---- phase 0: qn_s = q + acc_q (16x128); mu+acc_mu -> A_f32 (64 rows x 132)
    {
        int r = t >> 5, c4 = (t & 31) * 4;                    // 512 = 16*32
        float4 a = *(const float4*)&q[(size_t)(n0 + r) * H + c4];
        float4 b = *(const float4*)&acc_q[(size_t)(n0 + r) * H + c4];
        a.x += b.x; a.y += b.y; a.z += b.z; a.w += b.w;
        *(float4*)&qn_s[r][c4] = a;
    }
    for (int i = t; i < 64 * 32; i += 512) {
        int r = i >> 5, c4 = (i & 31) * 4;
        int n = r >> 2, d = r & 3;
        float4 v;
        if (d < 3) {
            float4 a = *(const float4*)&mu[((size_t)(n0 + n) * 3 + d) * H + c4];
            float4 b = *(const float4*)&acc_mu[(size_t)(n0 + n) * H3 + d * H + c4];
            v.x = a.x + b.x; v.y = a.y + b.y; v.z = a.z + b.z; v.w = a.w + b.w;
        } else { v.x = v.y = v.z = v.w = 0.f; }
        *(float4*)&A_f32[r * 132 + c4] = v;
    }
    __syncthreads();

    // ---- mu_cat: 64 rows x 256 cols, K=128. wave = rt*2+pp (rt=wv>>1).
    {
        const int rt = wv >> 1, pp = wv & 1;
        const int node = rt * 4 + qd;
        // hoist A fragments (hi/lo) into registers
        bf16x8 ah[4], al[4];
        {
            const float* arow = &A_f32[(rt * 16 + m) * 132 + qd * 8];
            #pragma unroll
            for (int kt = 0; kt < 4; kt++) {
                float v[8];
                *(float4*)&v[0] = *(const float4*)(arow + kt * 32);
                *(float4*)&v[4] = *(const float4*)(arow + kt * 32 + 4);
                #pragma unroll
                for (int j = 0; j < 8; j++) {
                    unsigned short h = f2b(v[j]);
                    ah[kt][j] = (short)h;
                    al[kt][j] = (short)f2b(v[j] - b2f(h));
                }
            }
        }
        __syncthreads();   // all frag loads done before A_f32 reuse writes below

        // copy qn into mix1-A rows (cols 0..127), stride 260
        {
            int r = t >> 5, c4 = (t & 31) * 4;
            *(float4*)&A_f32[r * 260 + c4] = *(const float4*)&qn_s[r][c4];
        }

        #pragma unroll 1
        for (int jj = 0; jj < 4; jj++) {
            int ctv = 2 * jj + pp;
            f32x4 av = {0.f, 0.f, 0.f, 0.f};
            f32x4 aw = {0.f, 0.f, 0.f, 0.f};
            #pragma unroll
            for (int kt = 0; kt < 4; kt++) {
                size_t bov = ((size_t)(ctv * 4 + kt) * 64 + lane) * 8;
                size_t bow = ((size_t)((ctv + 8) * 4 + kt) * 64 + lane) * 8;
                bf16x8 bvh = *(const bf16x8*)(Bv_hi + bov);
                bf16x8 bvl = *(const bf16x8*)(Bv_lo + bov);
                bf16x8 bwh = *(const bf16x8*)(Bv_hi + bow);
                bf16x8 bwl = *(const bf16x8*)(Bv_lo + bow);
                av = __builtin_amdgcn_mfma_f32_16x16x32_bf16(al[kt], bvh, av, 0, 0, 0);
                av = __builtin_amdgcn_mfma_f32_16x16x32_bf16(ah[kt], bvl, av, 0, 0, 0);
                av = __builtin_amdgcn_mfma_f32_16x16x32_bf16(ah[kt], bvh, av, 0, 0, 0);
                aw = __builtin_amdgcn_mfma_f32_16x16x32_bf16(al[kt], bwh, aw, 0, 0, 0);
                aw = __builtin_amdgcn_mfma_f32_16x16x32_bf16(ah[kt], bwl, aw, 0, 0, 0);
                aw = __builtin_amdgcn_mfma_f32_16x16x32_bf16(ah[kt], bwh, aw, 0, 0, 0);
            }
            int cw = ctv * 16 + m;
            float v0 = av[0], v1 = av[1], v2 = av[2];
            float w0 = aw[0], w1 = aw[1], w2 = aw[2];
            // norm goes straight into mix1-A (col 128+cw)
            A_f32[node * 260 + 128 + cw] = sqrtf(v0 * v0 + v1 * v1 + v2 * v2 + 1e-8f);
            inner_s[node][cw] = v0 * w0 + v1 * w1 + v2 * w2;
            muw_s[node * 3 + 0][cw] = f2b(w0);
            muw_s[node * 3 + 1][cw] = f2b(w1);
            muw_s[node * 3 + 2][cw] = f2b(w2);
        }
    }
    __syncthreads();

    // ---- mix1: 16 rows x 384 cols, K=256 (2 halves of 4 kt). wave ct = jj*8+wv.
    f32x4 hacc[3] = {{0.f,0.f,0.f,0.f},{0.f,0.f,0.f,0.f},{0.f,0.f,0.f,0.f}};
    #pragma unroll 1
    for (int half = 0; half < 2; half++) {
        bf16x8 ah[4], al[4];
        const float* arow = &A_f32[m * 260 + half * 128 + qd * 8];
        #pragma unroll
        for (int u = 0; u < 4; u++) {
            float v[8];
            *(float4*)&v[0] = *(const float4*)(arow + u * 32);
            *(float4*)&v[4] = *(const float4*)(arow + u * 32 + 4);
            #pragma unroll
            for (int j = 0; j < 8; j++) {
                unsigned short h = f2b(v[j]);
                ah[u][j] = (short)h;
                al[u][j] = (short)f2b(v[j] - b2f(h));
            }
        }
        #pragma unroll
        for (int jj = 0; jj < 3; jj++) {
            int ct = jj * 8 + wv;
            #pragma unroll
            for (int u = 0; u < 4; u++) {
                int kt = half * 4 + u;
                size_t bo = ((size_t)(ct * 8 + kt) * 64 + lane) * 8;
                bf16x8 bh = *(const bf16x8*)(B1_hi + bo);
                bf16x8 bl = *(const bf16x8*)(B1_lo + bo);
                hacc[jj] = __builtin_amdgcn_mfma_f32_16x16x32_bf16(al[u], bh, hacc[jj], 0, 0, 0);
                hacc[jj] = __builtin_amdgcn_mfma_f32_16x16x32_bf16(ah[u], bl, hacc[jj], 0, 0, 0);
                hacc[jj] = __builtin_amdgcn_mfma_f32_16x16x32_bf16(ah[u], bh, hacc[jj], 0, 0, 0);
            }
        }
    }
    __syncthreads();   // mix1 A reads complete before h overwrite

    // h = silu(hacc + bias) -> A_f32 rows 16 x stride 388
    #pragma unroll
    for (int jj = 0; jj < 3; jj++) {
        int ct = jj * 8 + wv;
        int c = ct * 16 + m;
        float bb = b_mix1[c];
        #pragma unroll
        for (int r = 0; r < 4; r++) {
            int node = qd * 4 + r;
            A_f32[node * 388 + c] = silu_f(hacc[jj][r] + bb);
        }
    }
    __syncthreads();

    // ---- mix2: 16 rows x 384 cols, K=384 (2 halves of 6 kt) + fused epilogue
    {
        f32x4 dacc[3] = {{0.f,0.f,0.f,0.f},{0.f,0.f,0.f,0.f},{0.f,0.f,0.f,0.f}};
        #pragma unroll 1
        for (int half = 0; half < 2; half++) {
            bf16x8 ah[6], al[6];
            const float* arow = &A_f32[m * 388 + half * 192 + qd * 8];
            #pragma unroll
            for (int u = 0; u < 6; u++) {
                float v[8];
                *(float4*)&v[0] = *(const float4*)(arow + u * 32);
                *(float4*)&v[4] = *(const float4*)(arow + u * 32 + 4);
                #pragma unroll
                for (int j = 0; j < 8; j++) {
                    unsigned short h = f2b(v[j]);
                    ah[u][j] = (short)h;
                    al[u][j] = (short)f2b(v[j] - b2f(h));
                }
            }
            #pragma unroll
            for (int jj = 0; jj < 3; jj++) {
                int ct = jj * 8 + wv;
                #pragma unroll
                for (int u = 0; u < 6; u++) {
                    int kt = half * 6 + u;
                    size_t bo = ((size_t)(ct * 12 + kt) * 64 + lane) * 8;
                    bf16x8 bh = *(const bf16x8*)(B2_hi + bo);
                    bf16x8 bl = *(const bf16x8*)(B2_lo + bo);
                    dacc[jj] = __builtin_amdgcn_mfma_f32_16x16x32_bf16(al[u], bh, dacc[jj], 0, 0, 0);
                    dacc[jj] = __builtin_amdgcn_mfma_f32_16x16x32_bf16(ah[u], bl, dacc[jj], 0, 0, 0);
                    dacc[jj] = __builtin_amdgcn_mfma_f32_16x16x32_bf16(ah[u], bh, dacc[jj], 0, 0, 0);
                }
            }
        }
        // bias: tiles ct = wv (dq), 8+wv (dms), 16+wv (dqmu); all at channel c
        const int c = wv * 16 + m;
        float bq = b_mix2[c], bs = b_mix2[128 + c], bu = b_mix2[256 + c];
        #pragma unroll
        for (int r = 0; r < 4; r++) {
            int node = qd * 4 + r;
            float dq   = dacc[0][r] + bq;
            float dms  = dacc[1][r] + bs;
            float dqmu = dacc[2][r] + bu;
            q_out[(size_t)(n0 + node) * H + c] =
                qn_s[node][c] + dq + dqmu * inner_s[node][c];
            #pragma unroll
            for (int d = 0; d < 3; d++) {
                size_t gi = ((size_t)(n0 + node) * 3 + d) * H + c;
                float mun = mu[gi] + acc_mu[(size_t)(n0 + node) * H3 + d * H + c];
                mu_out[gi] = mun + b2f(muw_s[node * 3 + d][c]) * dms;
            }
        }
    }
}

extern "C" void kernel_launch(void* const* d_in, const int* in_sizes, int n_in,
                              void* d_out, int out_size, void* d_ws, size_t ws_size,
                              hipStream_t stream) {
    const float* q        = (const float*)d_in[0];
    const float* mu       = (const float*)d_in[1];
    const int*   eidx     = (const int*)d_in[2];
    const float* rbf      = (const float*)d_in[3];
    const float* unitv    = (const float*)d_in[4];
    const float* cutoff   = (const float*)d_in[5];
    const float* W_inter1 = (const float*)d_in[6];
    const float* b_inter1 = (const float*)d_in[7];
    const float* W_inter2 = (const float*)d_in[8];
    const float* b_inter2 = (const float*)d_in[9];
    const float* W_filt1  = (const float*)d_in[10];
    const float* b_filt1  = (const float*)d_in[11];
    const float* W_filt2  = (const float*)d_in[12];
    const float* b_filt2  = (const float*)d_in[13];
    const float* W_vec    = (const float*)d_in[14];
    const float* W_mix1   = (const float*)d_in[15];
    const float* b_mix1   = (const float*)d_in[16];
    const float* W_mix2   = (const float*)d_in[17];
    const float* b_mix2   = (const float*)d_in[18];

    // workspace layout
    char* p = (char*)d_ws;
    float* acc_q       = (float*)p;            p += (size_t)NN * H * 4;
    float* acc_mu      = (float*)p;            p += (size_t)NN * H3 * 4;
    float* sorted_unit = (float*)p;            p += (size_t)NE * 3 * 4;
    int*   counts      = (int*)p;              p += (size_t)NN * 4;
    int*   off         = (int*)p;              p += (size_t)(NN + 1) * 4;
    p = (char*)(((size_t)p + 255) & ~(size_t)255);
    int*   cursor      = (int*)p;              p += (size_t)NN * 4;
    p = (char*)(((size_t)p + 255) & ~(size_t)255);
    int*   sorted_eid  = (int*)p;              p += (size_t)NE * 4;
    int*   sorted_src  = (int*)p;              p += (size_t)NE * 4;
    p = (char*)(((size_t)p + 255) & ~(size_t)255);
    unsigned short* Bp    = (unsigned short*)p; p += (size_t)H * H3 * 2;
    unsigned short* Bp1   = (unsigned short*)p; p += (size_t)H * H3 * 2;
    unsigned short* Bp2   = (unsigned short*)p; p += (size_t)H3 * H3 * 2;
    unsigned short* Bv_hi = (unsigned short*)p; p += (size_t)H * H2 * 2;
    unsigned short* Bv_lo = (unsigned short*)p; p += (size_t)H * H2 * 2;
    unsigned short* B1_hi = (unsigned short*)p; p += (size_t)H2 * H3 * 2;
    unsigned short* B1_lo = (unsigned short*)p; p += (size_t)H2 * H3 * 2;
    unsigned short* B2_hi = (unsigned short*)p; p += (size_t)H3 * H3 * 2;
    unsigned short* B2_lo = (unsigned short*)p; p += (size_t)H3 * H3 * 2;
    p = (char*)(((size_t)p + 255) & ~(size_t)255);
    unsigned short* x_b  = (unsigned short*)p;  p += (size_t)NN * H3 * 2;
    unsigned short* mu_b = (unsigned short*)p;  p += (size_t)NN * H3 * 2;
    p = (char*)(((size_t)p + 255) & ~(size_t)255);
    unsigned short* filt = (unsigned short*)p;  p += (size_t)NE * H3 * 2;

    float* q_out  = (float*)d_out;
    float* mu_out = q_out + (size_t)NN * H;

    hipMemsetAsync(counts, 0, (size_t)NN * 4, stream);

    hist_kernel  <<<NE / 256, 256, 0, stream>>>(eidx, counts);
    pack_hi_kernel<<<(H / 32) * (H3 / 16), 64, 0, stream>>>(W_filt2, H, H3, Bp);
    pack_hi_kernel<<<(H / 32) * (H3 / 16), 64, 0, stream>>>(W_inter1, H, H3, Bp1);
    pack_hi_kernel<<<(H3 / 32) * (H3 / 16), 64, 0, stream>>>(W_inter2, H3, H3, Bp2);
    pack_split_kernel<<<(H  / 32) * (H2 / 16), 64, 0, stream>>>(W_vec,  H,  H2, Bv_hi, Bv_lo);
    pack_split_kernel<<<(H2 / 32) * (H3 / 16), 64, 0, stream>>>(W_mix1, H2, H3, B1_hi, B1_lo);
    pack_split_kernel<<<(H3 / 32) * (H3 / 16), 64, 0, stream>>>(W_mix2, H3, H3, B2_hi, B2_lo);
    scan_kernel  <<<1, 1024, 0, stream>>>(counts, off, cursor);
    place_kernel <<<NE / 256, 256, 0, stream>>>(eidx, unitv, cursor,
                                                sorted_eid, sorted_src, sorted_unit);
    node_x_kernel<<<(NN + 31) / 32, 256, 0, stream>>>(q, Bp1, b_inter1, Bp2, b_inter2, x_b);
    mu2b_kernel  <<<NN * H3 / (4 * 256), 256, 0, stream>>>(mu, mu_b);
    filter_kernel<<<NE / 64, 256, 0, stream>>>(sorted_eid, rbf, cutoff,
                                               W_filt1, b_filt1, Bp, b_filt2, filt);
    gather_kernel<<<NN, 256, 0, stream>>>(off, sorted_src, sorted_unit, filt,
                                          x_b, mu_b, acc_q, acc_mu);
    mix_kernel   <<<NN / 16, 512, 0, stream>>>(q, mu, acc_q, acc_mu,
                                               Bv_hi, Bv_lo, B1_hi, B1_lo, B2_hi, B2_lo,
                                               b_mix1, b_mix2, q_out, mu_out);
}

// Round 9
// 490.338 us; speedup vs baseline: 4.3947x; 1.0024x over previous
//
#include <hip/hip_runtime.h>

#define NN 10000
#define NE 256000
#define H 128
#define H2 256
#define H3 384
#define NRBF 20

typedef __attribute__((ext_vector_type(8))) short bf16x8;
typedef __attribute__((ext_vector_type(4))) float f32x4;

__device__ __forceinline__ float silu_f(float v) { return v / (1.f + __expf(-v)); }

// fp32 -> bf16 bits (RNE)
__device__ __forceinline__ unsigned short f2b(float f) {
    union { float f; unsigned u; } x; x.f = f;
    unsigned r = (x.u + 0x7FFFu + ((x.u >> 16) & 1u)) >> 16;
    return (unsigned short)r;
}
__device__ __forceinline__ float b2f(unsigned short b) {
    union { unsigned u; float f; } x; x.u = ((unsigned)b) << 16;
    return x.f;
}

// ---------------------------------------------------------------------------
// CSR build
// ---------------------------------------------------------------------------
__global__ __launch_bounds__(256) void hist_kernel(const int* __restrict__ eidx,
                                                   int* __restrict__ counts) {
    int e = blockIdx.x * 256 + threadIdx.x;
    atomicAdd(&counts[eidx[e]], 1);
}

__global__ __launch_bounds__(1024) void scan_kernel(const int* __restrict__ counts,
                                                    int* __restrict__ off,
                                                    int* __restrict__ cursor) {
    __shared__ int sums[1024];
    const int t = threadIdx.x;
    const int base = t * 10;
    int local[10];
    int s = 0;
    #pragma unroll
    for (int i = 0; i < 10; i++) {
        int idx = base + i;
        int v = (idx < NN) ? counts[idx] : 0;
        local[i] = s; s += v;
    }
    sums[t] = s;
    __syncthreads();
    for (int d = 1; d < 1024; d <<= 1) {
        int v = (t >= d) ? sums[t - d] : 0;
        __syncthreads();
        sums[t] += v;
        __syncthreads();
    }
    int prefix = (t > 0) ? sums[t - 1] : 0;
    #pragma unroll
    for (int i = 0; i < 10; i++) {
        int idx = base + i;
        if (idx < NN) { off[idx] = prefix + local[i]; cursor[idx] = prefix + local[i]; }
    }
    if (t == 1023) off[NN] = sums[1023];
}

__global__ __launch_bounds__(256) void place_kernel(
    const int* __restrict__ eidx, const float* __restrict__ unitv,
    int* __restrict__ cursor, int* __restrict__ sorted_eid,
    int* __restrict__ sorted_src, float* __restrict__ sorted_unit) {
    int e = blockIdx.x * 256 + threadIdx.x;
    int tgt = eidx[e];
    int src = eidx[NE + e];
    int pos = atomicAdd(&cursor[tgt], 1);
    sorted_eid[pos] = e;
    sorted_src[pos] = src;
    sorted_unit[pos * 3 + 0] = unitv[(size_t)e * 3 + 0];
    sorted_unit[pos * 3 + 1] = unitv[(size_t)e * 3 + 1];
    sorted_unit[pos * 3 + 2] = unitv[(size_t)e * 3 + 2];
}

// ---------------------------------------------------------------------------
// Unified weight packing (one launch). 64-thread blocks, range-switched.
// ---------------------------------------------------------------------------
__device__ __forceinline__ void pack_hi_one(const float* __restrict__ W, int K, int N,
                                            unsigned short* __restrict__ dst,
                                            int b, int lane) {
    const int KT = K >> 5;
    const int kt = b % KT, ct = b / KT;
    const int m = lane & 15, qd = lane >> 4;
    size_t base = ((size_t)(ct * KT + kt) * 64 + lane) * 8;
    unsigned short v[8];
    #pragma unroll
    for (int j = 0; j < 8; j++) {
        int k = kt * 32 + qd * 8 + j;
        v[j] = f2b(W[(size_t)k * N + ct * 16 + m]);
    }
    *(ushort4*)&dst[base]     = *(ushort4*)&v[0];
    *(ushort4*)&dst[base + 4] = *(ushort4*)&v[4];
}

__device__ __forceinline__ void pack_split_one(const float* __restrict__ W, int K, int N,
                                               unsigned short* __restrict__ hi,
                                               unsigned short* __restrict__ lo,
                                               int b, int lane) {
    const int KT = K >> 5;
    const int kt = b % KT, ct = b / KT;
    const int m = lane & 15, qd = lane >> 4;
    size_t base = ((size_t)(ct * KT + kt) * 64 + lane) * 8;
    #pragma unroll
    for (int j = 0; j < 8; j++) {
        int k = kt * 32 + qd * 8 + j;
        float v = W[(size_t)k * N + ct * 16 + m];
        unsigned short h = f2b(v);
        hi[base + j] = h;
        lo[base + j] = f2b(v - b2f(h));
    }
}

__global__ __launch_bounds__(64) void pack_all_kernel(
    const float* __restrict__ Wf2, const float* __restrict__ Wi1,
    const float* __restrict__ Wi2, const float* __restrict__ Wf1,
    const float* __restrict__ Wv, const float* __restrict__ Wm1,
    const float* __restrict__ Wm2,
    unsigned short* __restrict__ Bp, unsigned short* __restrict__ Bp1,
    unsigned short* __restrict__ Bp2, unsigned short* __restrict__ Bf1p,
    unsigned short* __restrict__ Bv_hi, unsigned short* __restrict__ Bv_lo,
    unsigned short* __restrict__ B1_hi, unsigned short* __restrict__ B1_lo,
    unsigned short* __restrict__ B2_hi, unsigned short* __restrict__ B2_lo) {
    const int b = blockIdx.x;
    const int lane = threadIdx.x;
    if (b < 96)        pack_hi_one(Wf2, H, H3, Bp, b, lane);
    else if (b < 192)  pack_hi_one(Wi1, H, H3, Bp1, b - 96, lane);
    else if (b < 480)  pack_hi_one(Wi2, H3, H3, Bp2, b - 192, lane);
    else if (b < 488) {                               // Wf1: K=20 zero-padded to 32
        const int ct = b - 480;
        const int m = lane & 15, qd = lane >> 4;
        size_t base = ((size_t)ct * 64 + lane) * 8;
        unsigned short v[8];
        #pragma unroll
        for (int j = 0; j < 8; j++) {
            int k = qd * 8 + j;
            v[j] = (k < NRBF) ? f2b(Wf1[(size_t)k * H + ct * 16 + m]) : (unsigned short)0;
        }
        *(ushort4*)&Bf1p[base]     = *(ushort4*)&v[0];
        *(ushort4*)&Bf1p[base + 4] = *(ushort4*)&v[4];
    }
    else if (b < 552)  pack_split_one(Wv,  H,  H2, Bv_hi, Bv_lo, b - 488, lane);
    else if (b < 744)  pack_split_one(Wm1, H2, H3, B1_hi, B1_lo, b - 552, lane);
    else if (b < 1032) pack_split_one(Wm2, H3, H3, B2_hi, B2_lo, b - 744, lane);
}

// mu fp32 -> bf16 copy
__global__ __launch_bounds__(256) void mu2b_kernel(const float* __restrict__ mu,
                                                   unsigned short* __restrict__ mu_b) {
    int i = blockIdx.x * 256 + threadIdx.x;
    float4 v = ((const float4*)mu)[i];
    ushort4 o;
    o.x = f2b(v.x); o.y = f2b(v.y); o.z = f2b(v.z); o.w = f2b(v.w);
    ((ushort4*)mu_b)[i] = o;
}

// ---------------------------------------------------------------------------
// node_x (MFMA): x_b = bf16(silu(q@W1+b1) @ W2 + b2). 32 nodes per block.
// ---------------------------------------------------------------------------
__global__ __launch_bounds__(256) void node_x_kernel(
    const float* __restrict__ q,
    const unsigned short* __restrict__ Bp1, const float* __restrict__ b1,
    const unsigned short* __restrict__ Bp2, const float* __restrict__ b2,
    unsigned short* __restrict__ x_b) {
    __shared__ __align__(16) unsigned short qa_s[32 * 136];
    __shared__ __align__(16) unsigned short h1_s[32 * 392];
    const int t = threadIdx.x;
    const int wv = t >> 6, lane = t & 63;
    const int m = lane & 15, qd = lane >> 4;
    const int st = wv >> 1, ch = wv & 1;
    const int n0 = blockIdx.x * 32;

    for (int i = t; i < 32 * 32; i += 256) {
        int r = i >> 5, c4 = (i & 31) * 4;
        int node = n0 + r;
        ushort4 o;
        if (node < NN) {
            float4 v = *(const float4*)&q[(size_t)node * H + c4];
            o.x = f2b(v.x); o.y = f2b(v.y); o.z = f2b(v.z); o.w = f2b(v.w);
        } else { o.x = o.y = o.z = o.w = 0; }
        *(ushort4*)&qa_s[r * 136 + c4] = o;
    }
    __syncthreads();

    {
        const unsigned short* arow = &qa_s[(st * 16 + m) * 136 + qd * 8];
        #pragma unroll 1
        for (int jc = 0; jc < 12; jc++) {
            int ct = ch * 12 + jc;
            f32x4 acc = {0.f, 0.f, 0.f, 0.f};
            #pragma unroll
            for (int kt = 0; kt < 4; kt++) {
                bf16x8 af = *(const bf16x8*)(arow + kt * 32);
                bf16x8 bfr = *(const bf16x8*)(Bp1 + ((size_t)(ct * 4 + kt) * 64 + lane) * 8);
                acc = __builtin_amdgcn_mfma_f32_16x16x32_bf16(af, bfr, acc, 0, 0, 0);
            }
            int col = ct * 16 + m;
            float bb = b1[col];
            #pragma unroll
            for (int r = 0; r < 4; r++) {
                int row = st * 16 + qd * 4 + r;
                h1_s[row * 392 + col] = f2b(silu_f(acc[r] + bb));
            }
        }
    }
    __syncthreads();

    {
        const unsigned short* arow = &h1_s[(st * 16 + m) * 392 + qd * 8];
        #pragma unroll 1
        for (int jc = 0; jc < 12; jc++) {
            int ct = ch * 12 + jc;
            f32x4 acc = {0.f, 0.f, 0.f, 0.f};
            #pragma unroll
            for (int kt = 0; kt < 12; kt++) {
                bf16x8 af = *(const bf16x8*)(arow + kt * 32);
                bf16x8 bfr = *(const bf16x8*)(Bp2 + ((size_t)(ct * 12 + kt) * 64 + lane) * 8);
                acc = __builtin_amdgcn_mfma_f32_16x16x32_bf16(af, bfr, acc, 0, 0, 0);
            }
            int col = ct * 16 + m;
            float bb = b2[col];
            #pragma unroll
            for (int r = 0; r < 4; r++) {
                int row = n0 + st * 16 + qd * 4 + r;
                if (row < NN) x_b[(size_t)row * H3 + col] = f2b(acc[r] + bb);
            }
        }
    }
}

// ---------------------------------------------------------------------------
// Filter MLP v3: ORIGINAL edge order (coalesced rbf/cutoff), both layers MFMA.
// 64 edges per 256-thread block. Layer1: K=20 padded to 32, 1 kt, 8 ct/wave.
// ---------------------------------------------------------------------------
__global__ __launch_bounds__(256) void filter_kernel(
    const float* __restrict__ rbf, const float* __restrict__ cutoff,
    const unsigned short* __restrict__ Bf1p, const float* __restrict__ bf1,
    const unsigned short* __restrict__ Bp, const float* __restrict__ bf2,
    unsigned short* __restrict__ filt) {
    __shared__ __align__(16) float rbf_s[64][21];
    __shared__ __align__(16) unsigned short h1_s[64][136];
    __shared__ float cut_s[64];
    const int t = threadIdx.x;
    const int wv = t >> 6, lane = t & 63;
    const int m = lane & 15, qd = lane >> 4;
    const size_t e0 = (size_t)blockIdx.x * 64;

    if (t < 64) cut_s[t] = cutoff[e0 + t];
    for (int i = t; i < 64 * NRBF; i += 256) {          // coalesced
        rbf_s[i / NRBF][i % NRBF] = rbf[e0 * NRBF + i];
    }
    __syncthreads();

    // layer 1 MFMA: wave wv owns slot-tile wv
    {
        bf16x8 af;
        #pragma unroll
        for (int j = 0; j < 8; j++) {
            int k = qd * 8 + j;
            af[j] = (short)((k < NRBF) ? f2b(rbf_s[wv * 16 + m][k]) : (unsigned short)0);
        }
        #pragma unroll
        for (int ct = 0; ct < 8; ct++) {
            f32x4 acc = {0.f, 0.f, 0.f, 0.f};
            bf16x8 bfr = *(const bf16x8*)(Bf1p + ((size_t)ct * 64 + lane) * 8);
            acc = __builtin_amdgcn_mfma_f32_16x16x32_bf16(af, bfr, acc, 0, 0, 0);
            int col = ct * 16 + m;
            float bb = bf1[col];
            #pragma unroll
            for (int r = 0; r < 4; r++) {
                h1_s[wv * 16 + qd * 4 + r][col] = f2b(silu_f(acc[r] + bb));
            }
        }
    }
    __syncthreads();

    // layer 2 MFMA
    {
        const unsigned short* arow = &h1_s[wv * 16 + m][qd * 8];
        #pragma unroll 1
        for (int c = 0; c < 24; c++) {
            f32x4 acc = {0.f, 0.f, 0.f, 0.f};
            #pragma unroll
            for (int kt = 0; kt < 4; kt++) {
                bf16x8 af = *(const bf16x8*)(arow + kt * 32);
                bf16x8 bfr = *(const bf16x8*)(Bp + ((size_t)(c * 4 + kt) * 64 + lane) * 8);
                acc = __builtin_amdgcn_mfma_f32_16x16x32_bf16(af, bfr, acc, 0, 0, 0);
            }
            const int col = c * 16 + m;
            const float bb = bf2[col];
            #pragma unroll
            for (int r = 0; r < 4; r++) {
                int slot = wv * 16 + qd * 4 + r;
                float v = (acc[r] + bb) * cut_s[slot];
                filt[(e0 + slot) * H3 + col] = f2b(v);
            }
        }
    }
}

// ---------------------------------------------------------------------------
// Gather: filt indexed through sorted_eid (filter runs in original order).
// ---------------------------------------------------------------------------
__global__ __launch_bounds__(256) void gather_kernel(
    const int* __restrict__ off, const int* __restrict__ sorted_eid,
    const int* __restrict__ sorted_src, const float* __restrict__ sorted_unit,
    const unsigned short* __restrict__ filt,
    const unsigned short* __restrict__ x_b, const unsigned short* __restrict__ mu_b,
    float* __restrict__ acc_q, float* __restrict__ acc_mu) {
    __shared__ float red_s[16][128];
    const int t = threadIdx.x;
    const int n = blockIdx.x;
    const int g = t >> 6, lane = t & 63;
    const int c2 = lane * 2;
    const int j0 = off[n], j1 = off[n + 1];

    float aq0 = 0.f, aq1 = 0.f, a00 = 0.f, a01 = 0.f;
    float a10 = 0.f, a11 = 0.f, a20 = 0.f, a21 = 0.f;
    for (int j = j0 + g; j < j1; j += 4) {
        int e = sorted_eid[j];
        int src = sorted_src[j];
        float u0 = sorted_unit[j * 3 + 0];
        float u1 = sorted_unit[j * 3 + 1];
        float u2 = sorted_unit[j * 3 + 2];
        const unsigned short* frow = filt + (size_t)e * H3 + c2;
        const unsigned short* xrow = x_b + (size_t)src * H3 + c2;
        const unsigned short* murow = mu_b + (size_t)src * H3 + c2;
        ushort2 fq = *(const ushort2*)(frow);
        ushort2 fr = *(const ushort2*)(frow + H);
        ushort2 fm = *(const ushort2*)(frow + 2 * H);
        ushort2 xq = *(const ushort2*)(xrow);
        ushort2 xr = *(const ushort2*)(xrow + H);
        ushort2 xm = *(const ushort2*)(xrow + 2 * H);
        ushort2 m0 = *(const ushort2*)(murow);
        ushort2 m1 = *(const ushort2*)(murow + H);
        ushort2 m2 = *(const ushort2*)(murow + 2 * H);
        float xrs0 = b2f(xr.x) * b2f(fr.x), xrs1 = b2f(xr.y) * b2f(fr.y);
        float xms0 = b2f(xm.x) * b2f(fm.x), xms1 = b2f(xm.y) * b2f(fm.y);
        aq0 = fmaf(b2f(xq.x), b2f(fq.x), aq0);
        aq1 = fmaf(b2f(xq.y), b2f(fq.y), aq1);
        a00 = fmaf(u0, xrs0, a00); a00 = fmaf(b2f(m0.x), xms0, a00);
        a01 = fmaf(u0, xrs1, a01); a01 = fmaf(b2f(m0.y), xms1, a01);
        a10 = fmaf(u1, xrs0, a10); a10 = fmaf(b2f(m1.x), xms0, a10);
        a11 = fmaf(u1, xrs1, a11); a11 = fmaf(b2f(m1.y), xms1, a11);
        a20 = fmaf(u2, xrs0, a20); a20 = fmaf(b2f(m2.x), xms0, a20);
        a21 = fmaf(u2, xrs1, a21); a21 = fmaf(b2f(m2.y), xms1, a21);
    }
    red_s[g * 4 + 0][c2] = aq0; red_s[g * 4 + 0][c2 + 1] = aq1;
    red_s[g * 4 + 1][c2] = a00; red_s[g * 4 + 1][c2 + 1] = a01;
    red_s[g * 4 + 2][c2] = a10; red_s[g * 4 + 2][c2 + 1] = a11;
    red_s[g * 4 + 3][c2] = a20; red_s[g * 4 + 3][c2 + 1] = a21;
    __syncthreads();
    if (t < 128) {
        float vq = red_s[0][t] + red_s[4][t] + red_s[8][t] + red_s[12][t];
        float v0 = red_s[1][t] + red_s[5][t] + red_s[9][t] + red_s[13][t];
        float v1 = red_s[2][t] + red_s[6][t] + red_s[10][t] + red_s[14][t];
        float v2 = red_s[3][t] + red_s[7][t] + red_s[11][t] + red_s[15][t];
        acc_q[(size_t)n * H + t] = vq;
        acc_mu[(size_t)n * H3 + t] = v0;
        acc_mu[(size_t)n * H3 + H + t] = v1;
        acc_mu[(size_t)n * H3 + 2 * H + t] = v2;
    }
}

// ---------------------------------------------------------------------------
// Mixing v3 (unchanged from R8).
// ---------------------------------------------------------------------------
__global__ __launch_bounds__(512, 4) void mix_kernel(
    const float* __restrict__ q, const float* __restrict__ mu,
    const float* __restrict__ acc_q, const float* __restrict__ acc_mu,
    const unsigned short* __restrict__ Bv_hi, const unsigned short* __restrict__ Bv_lo,
    const unsigned short* __restrict__ B1_hi, const unsigned short* __restrict__ B1_lo,
    const unsigned short* __restrict__ B2_hi, const unsigned short* __restrict__ B2_lo,
    const float* __restrict__ b_mix1, const float* __restrict__ b_mix2,
    float* __restrict__ q_out, float* __restrict__ mu_out) {

    __shared__ __align__(16) float A_f32[64 * 132];
    __shared__ __align__(16) float qn_s[16][128];
    __shared__ __align__(16) float inner_s[16][128];
    __shared__ __align__(16) unsigned short muw_s[48][136];

    const int t = threadIdx.x;
    const int wv = t >> 6, lane = t & 63;
    const int m = lane & 15, qd = lane >> 4;
    const int n0 = blockIdx.x * 16;

    {
        int r = t >> 5, c4 = (t & 31) * 4;
        float4 a = *(const float4*)&q[(size_t)(n0 + r) * H + c4];
        float4 b = *(const float4*)&acc_q[(size_t)(n0 + r) * H + c4];
        a.x += b.x; a.y += b.y; a.z += b.z; a.w += b.w;
        *(float4*)&qn_s[r][c4] = a;
    }
    for (int i = t; i < 64 * 32; i += 512) {
        int r = i >> 5, c4 = (i & 31) * 4;
        int n = r >> 2, d = r & 3;
        float4 v;
        if (d < 3) {
            float4 a = *(const float4*)&mu[((size_t)(n0 + n) * 3 + d) * H + c4];
            float4 b = *(const float4*)&acc_mu[(size_t)(n0 + n) * H3 + d * H + c4];
            v.x = a.x + b.x; v.y = a.y + b.y; v.z = a.z + b.z; v.w = a.w + b.w;
        } else { v.x = v.y = v.z = v.w = 0.f; }
        *(float4*)&A_f32[r * 132 + c4] = v;
    }
    __syncthreads();

    {
        const int rt = wv >> 1, pp = wv & 1;
        const int node = rt * 4 + qd;
        bf16x8 ah[4], al[4];
        {
            const float* arow = &A_f32[(rt * 16 + m) * 132 + qd * 8];
            #pragma unroll
            for (int kt = 0; kt < 4; kt++) {
                float v[8];
                *(float4*)&v[0] = *(const float4*)(arow + kt * 32);
                *(float4*)&v[4] = *(const float4*)(arow + kt * 32 + 4);
                #pragma unroll
                for (int j = 0; j < 8; j++) {
                    unsigned short h = f2b(v[j]);
                    ah[kt][j] = (short)h;
                    al[kt][j] = (short)f2b(v[j] - b2f(h));
                }
            }
        }
        __syncthreads();

        {
            int r = t >> 5, c4 = (t & 31) * 4;
            *(float4*)&A_f32[r * 260 + c4] = *(const float4*)&qn_s[r][c4];
        }

        #pragma unroll 1
        for (int jj = 0; jj < 4; jj++) {
            int ctv = 2 * jj + pp;
            f32x4 av = {0.f, 0.f, 0.f, 0.f};
            f32x4 aw = {0.f, 0.f, 0.f, 0.f};
            #pragma unroll
            for (int kt = 0; kt < 4; kt++) {
                size_t bov = ((size_t)(ctv * 4 + kt) * 64 + lane) * 8;
                size_t bow = ((size_t)((ctv + 8) * 4 + kt) * 64 + lane) * 8;
                bf16x8 bvh = *(const bf16x8*)(Bv_hi + bov);
                bf16x8 bvl = *(const bf16x8*)(Bv_lo + bov);
                bf16x8 bwh = *(const bf16x8*)(Bv_hi + bow);
                bf16x8 bwl = *(const bf16x8*)(Bv_lo + bow);
                av = __builtin_amdgcn_mfma_f32_16x16x32_bf16(al[kt], bvh, av, 0, 0, 0);
                av = __builtin_amdgcn_mfma_f32_16x16x32_bf16(ah[kt], bvl, av, 0, 0, 0);
                av = __builtin_amdgcn_mfma_f32_16x16x32_bf16(ah[kt], bvh, av, 0, 0, 0);
                aw = __builtin_amdgcn_mfma_f32_16x16x32_bf16(al[kt], bwh, aw, 0, 0, 0);
                aw = __builtin_amdgcn_mfma_f32_16x16x32_bf16(ah[kt], bwl, aw, 0, 0, 0);
                aw = __builtin_amdgcn_mfma_f32_16x16x32_bf16(ah[kt], bwh, aw, 0, 0, 0);
            }
            int cw = ctv * 16 + m;
            float v0 = av[0], v1 = av[1], v2 = av[2];
            float w0 = aw[0], w1 = aw[1], w2 = aw[2];
            A_f32[node * 260 + 128 + cw] = sqrtf(v0 * v0 + v1 * v1 + v2 * v2 + 1e-8f);
            inner_s[node][cw] = v0 * w0 + v1 * w1 + v2 * w2;
            muw_s[node * 3 + 0][cw] = f2b(w0);
            muw_s[node * 3 + 1][cw] = f2b(w1);
            muw_s[node * 3 + 2][cw] = f2b(w2);
        }
    }
    __syncthreads();

    f32x4 hacc[3] = {{0.f,0.f,0.f,0.f},{0.f,0.f,0.f,0.f},{0.f,0.f,0.f,0.f}};
    #pragma unroll 1
    for (int half = 0; half < 2; half++) {
        bf16x8 ah[4], al[4];
        const float* arow = &A_f32[m * 260 + half * 128 + qd * 8];
        #pragma unroll
        for (int u = 0; u < 4; u++) {
            float v[8];
            *(float4*)&v[0] = *(const float4*)(arow + u * 32);
            *(float4*)&v[4] = *(const float4*)(arow + u * 32 + 4);
            #pragma unroll
            for (int j = 0; j < 8; j++) {
                unsigned short h = f2b(v[j]);
                ah[u][j] = (short)h;
                al[u][j] = (short)f2b(v[j] - b2f(h));
            }
        }
        #pragma unroll
        for (int jj = 0; jj < 3; jj++) {
            int ct = jj * 8 + wv;
            #pragma unroll
            for (int u = 0; u < 4; u++) {
                int kt = half * 4 + u;
                size_t bo = ((size_t)(ct * 8 + kt) * 64 + lane) * 8;
                bf16x8 bh = *(const bf16x8*)(B1_hi + bo);
                bf16x8 bl = *(const bf16x8*)(B1_lo + bo);
                hacc[jj] = __builtin_amdgcn_mfma_f32_16x16x32_bf16(al[u], bh, hacc[jj], 0, 0, 0);
                hacc[jj] = __builtin_amdgcn_mfma_f32_16x16x32_bf16(ah[u], bl, hacc[jj], 0, 0, 0);
                hacc[jj] = __builtin_amdgcn_mfma_f32_16x16x32_bf16(ah[u], bh, hacc[jj], 0, 0, 0);
            }
        }
    }
    __syncthreads();

    #pragma unroll
    for (int jj = 0; jj < 3; jj++) {
        int ct = jj * 8 + wv;
        int c = ct * 16 + m;
        float bb = b_mix1[c];
        #pragma unroll
        for (int r = 0; r < 4; r++) {
            int node = qd * 4 + r;
            A_f32[node * 388 + c] = silu_f(hacc[jj][r] + bb);
        }
    }
    __syncthreads();

    {
        f32x4 dacc[3] = {{0.f,0.f,0.f,0.f},{0.f,0.f,0.f,0.f},{0.f,0.f,0.f,0.f}};
        #pragma unroll 1
        for (int half = 0; half < 2; half++) {
            bf16x8 ah[6], al[6];
            const float* arow = &A_f32[m * 388 + half * 192 + qd * 8];
            #pragma unroll
            for (int u = 0; u < 6; u++) {
                float v[8];
                *(float4*)&v[0] = *(const float4*)(arow + u * 32);
                *(float4*)&v[4] = *(const float4*)(arow + u * 32 + 4);
                #pragma unroll
                for (int j = 0; j < 8; j++) {
                    unsigned short h = f2b(v[j]);
                    ah[u][j] = (short)h;
                    al[u][j] = (short)f2b(v[j] - b2f(h));
                }
            }
            #pragma unroll
            for (int jj = 0; jj < 3; jj++) {
                int ct = jj * 8 + wv;
                #pragma unroll
                for (int u = 0; u < 6; u++) {
                    int kt = half * 6 + u;
                    size_t bo = ((size_t)(ct * 12 + kt) * 64 + lane) * 8;
                    bf16x8 bh = *(const bf16x8*)(B2_hi + bo);
                    bf16x8 bl = *(const bf16x8*)(B2_lo + bo);
                    dacc[jj] = __builtin_amdgcn_mfma_f32_16x16x32_bf16(al[u], bh, dacc[jj], 0, 0, 0);
                    dacc[jj] = __builtin_amdgcn_mfma_f32_16x16x32_bf16(ah[u], bl, dacc[jj], 0, 0, 0);
                    dacc[jj] = __builtin_amdgcn_mfma_f32_16x16x32_bf16(ah[u], bh, dacc[jj], 0, 0, 0);
                }
            }
        }
        const int c = wv * 16 + m;
        float bq = b_mix2[c], bs = b_mix2[128 + c], bu = b_mix2[256 + c];
        #pragma unroll
        for (int r = 0; r < 4; r++) {
            int node = qd * 4 + r;
            float dq   = dacc[0][r] + bq;
            float dms  = dacc[1][r] + bs;
            float dqmu = dacc[2][r] + bu;
            q_out[(size_t)(n0 + node) * H + c] =
                qn_s[node][c] + dq + dqmu * inner_s[node][c];
            #pragma unroll
            for (int d = 0; d < 3; d++) {
                size_t gi = ((size_t)(n0 + node) * 3 + d) * H + c;
                float mun = mu[gi] + acc_mu[(size_t)(n0 + node) * H3 + d * H + c];
                mu_out[gi] = mun + b2f(muw_s[node * 3 + d][c]) * dms;
            }
        }
    }
}

extern "C" void kernel_launch(void* const* d_in, const int* in_sizes, int n_in,
                              void* d_out, int out_size, void* d_ws, size_t ws_size,
                              hipStream_t stream) {
    const float* q        = (const float*)d_in[0];
    const float* mu       = (const float*)d_in[1];
    const int*   eidx     = (const int*)d_in[2];
    const float* rbf      = (const float*)d_in[3];
    const float* unitv    = (const float*)d_in[4];
    const float* cutoff   = (const float*)d_in[5];
    const float* W_inter1 = (const float*)d_in[6];
    const float* b_inter1 = (const float*)d_in[7];
    const float* W_inter2 = (const float*)d_in[8];
    const float* b_inter2 = (const float*)d_in[9];
    const float* W_filt1  = (const float*)d_in[10];
    const float* b_filt1  = (const float*)d_in[11];
    const float* W_filt2  = (const float*)d_in[12];
    const float* b_filt2  = (const float*)d_in[13];
    const float* W_vec    = (const float*)d_in[14];
    const float* W_mix1   = (const float*)d_in[15];
    const float* b_mix1   = (const float*)d_in[16];
    const float* W_mix2   = (const float*)d_in[17];
    const float* b_mix2   = (const float*)d_in[18];

    // workspace layout
    char* p = (char*)d_ws;
    float* acc_q       = (float*)p;            p += (size_t)NN * H * 4;
    float* acc_mu      = (float*)p;            p += (size_t)NN * H3 * 4;
    float* sorted_unit = (float*)p;            p += (size_t)NE * 3 * 4;
    int*   counts      = (int*)p;              p += (size_t)NN * 4;
    int*   off         = (int*)p;              p += (size_t)(NN + 1) * 4;
    p = (char*)(((size_t)p + 255) & ~(size_t)255);
    int*   cursor      = (int*)p;              p += (size_t)NN * 4;
    p = (char*)(((size_t)p + 255) & ~(size_t)255);
    int*   sorted_eid  = (int*)p;              p += (size_t)NE * 4;
    int*   sorted_src  = (int*)p;              p += (size_t)NE * 4;
    p = (char*)(((size_t)p + 255) & ~(size_t)255);
    unsigned short* Bp    = (unsigned short*)p; p += (size_t)H * H3 * 2;
    unsigned short* Bp1   = (unsigned short*)p; p += (size_t)H * H3 * 2;
    unsigned short* Bp2   = (unsigned short*)p; p += (size_t)H3 * H3 * 2;
    unsigned short* Bf1p  = (unsigned short*)p; p += (size_t)8 * 64 * 8 * 2;
    unsigned short* Bv_hi = (unsigned short*)p; p += (size_t)H * H2 * 2;
    unsigned short* Bv_lo = (unsigned short*)p; p += (size_t)H * H2 * 2;
    unsigned short* B1_hi = (unsigned short*)p; p += (size_t)H2 * H3 * 2;
    unsigned short* B1_lo = (unsigned short*)p; p += (size_t)H2 * H3 * 2;
    unsigned short* B2_hi = (unsigned short*)p; p += (size_t)H3 * H3 * 2;
    unsigned short* B2_lo = (unsigned short*)p; p += (size_t)H3 * H3 * 2;
    p = (char*)(((size_t)p + 255) & ~(size_t)255);
    unsigned short* x_b  = (unsigned short*)p;  p += (size_t)NN * H3 * 2;
    unsigned short* mu_b = (unsigned short*)p;  p += (size_t)NN * H3 * 2;
    p = (char*)(((size_t)p + 255) & ~(size_t)255);
    unsigned short* filt = (unsigned short*)p;  p += (size_t)NE * H3 * 2;

    float* q_out  = (float*)d_out;
    float* mu_out = q_out + (size_t)NN * H;

    hipMemsetAsync(counts, 0, (size_t)NN * 4, stream);

    hist_kernel    <<<NE / 256, 256, 0, stream>>>(eidx, counts);
    pack_all_kernel<<<1032, 64, 0, stream>>>(W_filt2, W_inter1, W_inter2, W_filt1,
                                             W_vec, W_mix1, W_mix2,
                                             Bp, Bp1, Bp2, Bf1p,
                                             Bv_hi, Bv_lo, B1_hi, B1_lo, B2_hi, B2_lo);
    scan_kernel    <<<1, 1024, 0, stream>>>(counts, off, cursor);
    place_kernel   <<<NE / 256, 256, 0, stream>>>(eidx, unitv, cursor,
                                                  sorted_eid, sorted_src, sorted_unit);
    node_x_kernel  <<<(NN + 31) / 32, 256, 0, stream>>>(q, Bp1, b_inter1, Bp2, b_inter2, x_b);
    mu2b_kernel    <<<NN * H3 / (4 * 256), 256, 0, stream>>>(mu, mu_b);
    filter_kernel  <<<NE / 64, 256, 0, stream>>>(rbf, cutoff, Bf1p, b_filt1,
                                                 Bp, b_filt2, filt);
    gather_kernel  <<<NN, 256, 0, stream>>>(off, sorted_eid, sorted_src, sorted_unit,
                                            filt, x_b, mu_b, acc_q, acc_mu);
    mix_kernel     <<<NN / 16, 512, 0, stream>>>(q, mu, acc_q, acc_mu,
                                                 Bv_hi, Bv_lo, B1_hi, B1_lo, B2_hi, B2_lo,
                                                 b_mix1, b_mix2, q_out, mu_out);
}